// Round 15
// baseline (434.653 us; speedup 1.0000x reference)
//
#include <hip/hip_runtime.h>
#include <hip/hip_bf16.h>
#include <stdint.h>

typedef __bf16 bf16_t;
typedef __bf16 bf16x8 __attribute__((ext_vector_type(8)));
typedef float f32x4 __attribute__((ext_vector_type(4)));
typedef float f32x2 __attribute__((ext_vector_type(2)));
typedef float floatv4 __attribute__((ext_vector_type(4)));

static __device__ __forceinline__ float bflo(unsigned int p){ return __uint_as_float(p << 16); }
static __device__ __forceinline__ float bfhi(unsigned int p){ return __uint_as_float(p & 0xffff0000u); }
static __device__ __forceinline__ unsigned int pack2(float lo, float hi){
  union { bf16_t h[2]; unsigned int u; } o;
  o.h[0] = (bf16_t)lo; o.h[1] = (bf16_t)hi;
  return o.u;
}
// async 16B global->LDS DMA
static __device__ __forceinline__ void gload16(const void* g, void* l){
  __builtin_amdgcn_global_load_lds((const __attribute__((address_space(1))) void*)g,
                                   (__attribute__((address_space(3))) void*)l, 16, 0, 0);
}
// fp8 e4m3 (OCP) HW conversions
static __device__ __forceinline__ void acc4_fp8(float* a, unsigned w, float wt){
  f32x2 lo, hi;
  unsigned wh = w >> 16;
  asm("v_cvt_pk_f32_fp8 %0, %1" : "=v"(lo) : "v"(w));
  asm("v_cvt_pk_f32_fp8 %0, %1" : "=v"(hi) : "v"(wh));
  a[0] += wt*lo[0]; a[1] += wt*lo[1]; a[2] += wt*hi[0]; a[3] += wt*hi[1];
}
static __device__ __forceinline__ unsigned cvt2fp8(float a, float b){
  unsigned r;
  asm("v_cvt_pk_fp8_f32 %0, %1, %2" : "=v"(r) : "v"(a), "v"(b));
  return r & 0xffffu;
}
static __device__ __forceinline__ uint8_t cvt1fp8(float a){
  unsigned r;
  asm("v_cvt_pk_fp8_f32 %0, %1, %1" : "=v"(r) : "v"(a));
  return (uint8_t)r;
}
// packed edge: bits[16:0]=col, bits[31:17]=weight f32 bits[30:16] (sign implicit)
static __device__ __forceinline__ unsigned packEdge(int col, float w_pos){
  unsigned b = __float_as_uint(w_pos) + 0x8000u;
  return ((b >> 16) << 17) | (unsigned)col;
}
static __device__ __forceinline__ float edgeWpos(unsigned u){
  return __uint_as_float((u >> 17) << 16);
}
static __device__ __forceinline__ float edgeWneg(unsigned u){
  return __uint_as_float(0x80000000u | ((u >> 17) << 16));
}

constexpr int NN = 100000;
constexpr int NE = 1600000;
constexpr int NB_G  = (NN + 127)/128;    // 782 (conv gemms, BM=128)
constexpr int NB_G64 = (NN + 63)/64;     // 1563 (gemm1, BM=64, wave-per-16-rows)
constexpr int NBIN = (NN + 127)/128;     // 782
constexpr int EPB  = 4096;
constexpr int NBB  = (NE + EPB - 1)/EPB; // 391
constexpr int MAXBE = 3072;

// ---------------- binned CSR build ----------------
__global__ __launch_bounds__(256) void k_binA(const int* __restrict__ row,
                                              int* __restrict__ bincnt,
                                              int* __restrict__ blockbase){
  __shared__ int h[NBIN];
  for (int b = threadIdx.x; b < NBIN; b += 256) h[b] = 0;
  __syncthreads();
  int base = blockIdx.x * EPB;
  for (int k = 0; k < EPB; k += 256){
    int i = base + k + threadIdx.x;
    if (i < NE) atomicAdd(&h[row[i] >> 7], 1);
  }
  __syncthreads();
  for (int b = threadIdx.x; b < NBIN; b += 256){
    int c = h[b];
    blockbase[blockIdx.x * NBIN + b] = c ? atomicAdd(&bincnt[b], c) : 0;
  }
}

__global__ __launch_bounds__(256) void k_scanbins(const int* __restrict__ bincnt,
                                                  int* __restrict__ binptr,
                                                  int* __restrict__ rowptr){
  __shared__ int s[256];
  int t = threadIdx.x;
  int b0 = t*4;
  int c[4]; int tot = 0;
  #pragma unroll
  for (int j = 0; j < 4; ++j){
    int b = b0 + j;
    c[j] = (b < NBIN) ? bincnt[b] : 0;
    tot += c[j];
  }
  s[t] = tot;
  __syncthreads();
  for (int off = 1; off < 256; off <<= 1){
    int v = (t >= off) ? s[t - off] : 0;
    __syncthreads();
    s[t] += v;
    __syncthreads();
  }
  int ex = s[t] - tot;
  #pragma unroll
  for (int j = 0; j < 4; ++j){
    int b = b0 + j;
    if (b < NBIN) binptr[b] = ex;
    ex += c[j];
  }
  if (t == 255){ binptr[NBIN] = ex; rowptr[NN] = ex; }
}

__global__ __launch_bounds__(256) void k_binB(const int* __restrict__ row,
                                              const int* __restrict__ col,
                                              const float* __restrict__ w,
                                              const int* __restrict__ binptr,
                                              const int* __restrict__ blockbase,
                                              int2* __restrict__ temp){
  __shared__ int h[NBIN];
  for (int b = threadIdx.x; b < NBIN; b += 256) h[b] = 0;
  __syncthreads();
  int base = blockIdx.x * EPB;
  for (int k = 0; k < EPB; k += 256){
    int i = base + k + threadIdx.x;
    if (i < NE){
      int r = row[i];
      int b = r >> 7;
      int rank = atomicAdd(&h[b], 1);
      int pos = binptr[b] + blockbase[blockIdx.x * NBIN + b] + rank;
      temp[pos] = make_int2(col[i] | ((r & 127) << 17), __float_as_int(w[i]));
    }
  }
}

__global__ __launch_bounds__(256) void k_binC(const int2* __restrict__ temp,
                                              const int* __restrict__ binptr,
                                              unsigned* __restrict__ ec,
                                              int* __restrict__ rowptr,
                                              float* __restrict__ dinv, int n){
  __shared__ int2 sbuf[MAXBE];
  __shared__ int cnt[128];
  __shared__ int scan[128];
  __shared__ int estart[128];
  const int b = blockIdx.x;
  const int e0 = binptr[b];
  int nb = binptr[b+1] - e0; if (nb > MAXBE) nb = MAXBE;
  const int t = threadIdx.x;
  if (t < 128) cnt[t] = 0;
  __syncthreads();
  for (int k = t; k < nb; k += 256)
    atomicAdd(&cnt[(temp[e0+k].x >> 17) & 127], 1);
  __syncthreads();
  if (t < 128) scan[t] = cnt[t];
  __syncthreads();
  for (int off = 1; off < 128; off <<= 1){
    int v = (t < 128 && t >= off) ? scan[t - off] : 0;
    __syncthreads();
    if (t < 128) scan[t] += v;
    __syncthreads();
  }
  if (t < 128){ estart[t] = scan[t] - cnt[t]; cnt[t] = 0; }
  __syncthreads();
  for (int k = t; k < nb; k += 256){
    int2 q = temp[e0+k];
    int rl = (q.x >> 17) & 127;
    int rank = atomicAdd(&cnt[rl], 1);
    sbuf[estart[rl] + rank] = q;
  }
  __syncthreads();
  for (int k = t; k < nb; k += 256){
    int2 q = sbuf[k];
    ec[e0 + k] = packEdge(q.x & 0x1FFFF, __int_as_float(q.y));
  }
  if (t < 128){
    int gid = b*128 + t;
    if (gid < n){
      rowptr[gid] = e0 + estart[t];
      float s = 0.f;
      int s0 = estart[t], c = cnt[t];
      for (int j = 0; j < c; ++j) s += __int_as_float(sbuf[s0+j].y);
      dinv[gid] = (s > 0.f) ? rsqrtf(s) : 0.f;
    }
  }
}

__global__ __launch_bounds__(256) void k_norm(unsigned* __restrict__ ec,
                                              const int* __restrict__ rowptr,
                                              const float* __restrict__ dinv, int n){
  int node = blockIdx.x*4 + (threadIdx.x >> 6);
  if (node >= n) return;
  int lane = threadIdx.x & 63;
  int e0 = rowptr[node], e1 = rowptr[node+1];
  float dr = dinv[node];
  for (int e = e0 + lane; e < e1; e += 64){
    unsigned u = ec[e];
    int c = u & 0x1FFFF;
    float wn = dr * edgeWpos(u) * dinv[c];
    ec[e] = packEdge(c, wn);
  }
}

__global__ void k_transw_all(const float* __restrict__ W1, const float* __restrict__ c1W,
                             const float* __restrict__ c2W, bf16_t* __restrict__ Wt1,
                             bf16_t* __restrict__ Wtc1, bf16_t* __restrict__ Wtc2){
  int idx = blockIdx.x*256 + threadIdx.x;   // 8*16384 total
  const float* src; bf16_t* dst; int local;
  if (idx < 2*16384)      { src = W1;  dst = Wt1;  local = idx; }
  else if (idx < 5*16384) { src = c1W; dst = Wtc1; local = idx - 2*16384; }
  else                    { src = c2W; dst = Wtc2; local = idx - 5*16384; }
  int c = local >> 14, r = (local >> 7) & 127, j = local & 127;
  dst[(c << 14) + (j << 7) + r] = (bf16_t)src[local];
}

// ---------------- GEMM1 v7: wave-autonomous, LDS-free, forced 16-deep load burst --
// Each wave owns a 16x128 output stripe. Each lane burst-loads its A-row's entire
// K=256 (16 x float4, statically indexed; sched_barrier(0) pins the issue block so
// the compiler cannot fold it). 8 MFMA steps then consume with compiler-counted
// vmcnt waits (14,12,...). Zero barriers, zero LDS — spmm-style issue depth.
__global__ __launch_bounds__(256) void k_gemm1(
    const float* __restrict__ x, const bf16_t* __restrict__ Wt, const float* __restrict__ bias,
    bf16_t* __restrict__ out, uint8_t* __restrict__ out8, int M)
{
  const int tid = threadIdx.x;
  const int wave = tid >> 6, lane = tid & 63;
  const int l15 = lane & 15, lq = lane >> 4;
  const int blockRow = blockIdx.x * 64;

  int gr = blockRow + wave*16 + l15;
  if (gr > M-1) gr = M-1;                     // clamp: x is an input buffer
  const float* px = x + (size_t)gr*256 + lq*8;

  floatv4 xr[16];
  #pragma unroll
  for (int s = 0; s < 8; ++s){
    xr[s*2]   = *(const floatv4*)(px + s*32);
    xr[s*2+1] = *(const floatv4*)(px + s*32 + 4);
  }
  __builtin_amdgcn_sched_barrier(0);          // all 16 loads issued before any consume

  f32x4 acc[8];
  #pragma unroll
  for (int b = 0; b < 8; ++b) acc[b] = f32x4{0.f,0.f,0.f,0.f};

  #pragma unroll
  for (int s = 0; s < 8; ++s){
    bf16x8 a;
    #pragma unroll
    for (int j = 0; j < 4; ++j){
      a[j]   = (bf16_t)xr[s*2][j];
      a[4+j] = (bf16_t)xr[s*2+1][j];
    }
    #pragma unroll
    for (int fn = 0; fn < 8; ++fn){
      bf16x8 b = *(const bf16x8*)(Wt + ((size_t)(((s>>2) << 7) + fn*16 + l15) << 7) + (s&3)*32 + lq*8);
      acc[fn] = __builtin_amdgcn_mfma_f32_16x16x32_bf16(a, b, acc[fn], 0, 0, 0);
    }
  }
  #pragma unroll
  for (int j = 0; j < 4; ++j){
    int growo = blockRow + wave*16 + lq*4 + j;
    if (growo < M){
      #pragma unroll
      for (int fn = 0; fn < 8; ++fn){
        int c = fn*16 + l15;
        float v = fmaxf(acc[fn][j] + bias[c], 0.f);
        out[((size_t)growo << 7) + c] = (bf16_t)v;
        out8[((size_t)growo << 7) + c] = cvt1fp8(v);
      }
    }
  }
}

// ---------------- conv GEMM (r11-proven): BM=128, async dbuf, 6 steps BK=64 -------
__global__ __launch_bounds__(256) void k_gemm_nb(
    const bf16_t* __restrict__ a0, const bf16_t* __restrict__ a1, const bf16_t* __restrict__ a2,
    const bf16_t* __restrict__ Wt, const float* __restrict__ bias,
    bf16_t* __restrict__ out, uint8_t* __restrict__ out8, int M)
{
  __shared__ uint8_t lds[2][16384];
  const int tid = threadIdx.x;
  const int wave = tid >> 6, lane = tid & 63;
  const int wm = wave >> 1, wn = wave & 1;
  const int l15 = lane & 15, lq = lane >> 4;
  const int blockRow = blockIdx.x * 128;
  const int strow = tid >> 3;
  const int scell = tid & 7;

  f32x4 acc[4][4];
  #pragma unroll
  for (int a = 0; a < 4; ++a)
    #pragma unroll
    for (int b = 0; b < 4; ++b) acc[a][b] = f32x4{0.f,0.f,0.f,0.f};

  #pragma unroll
  for (int j = 0; j < 4; ++j){
    int r = j*32 + strow;
    int gr = blockRow + r; if (gr > M-1) gr = M-1;
    gload16((const char*)a0 + (size_t)gr*256 + ((scell ^ (r&7)) << 4),
            &lds[0][j*4096 + tid*16]);
  }

  #pragma unroll
  for (int s = 0; s < 6; ++s){
    if (s < 5){
      const int sn = s + 1;
      const bf16_t* srcn = (sn>>1) == 0 ? a0 : ((sn>>1) == 1 ? a1 : a2);
      #pragma unroll
      for (int j = 0; j < 4; ++j){
        int r = j*32 + strow;
        int gr = blockRow + r; if (gr > M-1) gr = M-1;
        gload16((const char*)srcn + (size_t)gr*256 + (sn&1)*128 + ((scell ^ (r&7)) << 4),
                &lds[sn&1][j*4096 + tid*16]);
      }
    }
    __syncthreads();
    const uint8_t* buf = lds[s&1];
    #pragma unroll
    for (int kk32 = 0; kk32 < 2; ++kk32){
      bf16x8 af[4], bfr[4];
      #pragma unroll
      for (int fm = 0; fm < 4; ++fm){
        int r = wm*64 + fm*16 + l15;
        af[fm] = *(const bf16x8*)(buf + r*128 + (((kk32*4 + lq) ^ (r&7)) << 4));
      }
      #pragma unroll
      for (int fn = 0; fn < 4; ++fn)
        bfr[fn] = *(const bf16x8*)(Wt + ((size_t)(((s>>1) << 7) + wn*64 + fn*16 + l15) << 7)
                                   + (s&1)*64 + kk32*32 + lq*8);
      #pragma unroll
      for (int fm = 0; fm < 4; ++fm)
        #pragma unroll
        for (int fn = 0; fn < 4; ++fn)
          acc[fm][fn] = __builtin_amdgcn_mfma_f32_16x16x32_bf16(af[fm], bfr[fn], acc[fm][fn], 0, 0, 0);
    }
    __syncthreads();
  }
  #pragma unroll
  for (int fm = 0; fm < 4; ++fm){
    #pragma unroll
    for (int j = 0; j < 4; ++j){
      int growo = blockRow + wm*64 + fm*16 + lq*4 + j;
      if (growo < M){
        #pragma unroll
        for (int fn = 0; fn < 4; ++fn){
          int c = wn*64 + fn*16 + l15;
          float v = fmaxf(acc[fm][fn][j] + bias[c], 0.f);
          out[((size_t)growo << 7) + c] = (bf16_t)v;
          if (out8) out8[((size_t)growo << 7) + c] = cvt1fp8(v);
        }
      }
    }
  }
}

// ---------------- SpMM fp8 (r11-proven): 4 nodes/wave, 16 lanes/node, 8B/lane -----
__global__ __launch_bounds__(256) void k_spmm8(
    const int* __restrict__ rowptr, const unsigned* __restrict__ ec,
    const uint8_t* __restrict__ V8, const bf16_t* __restrict__ sub, float alpha,
    bf16_t* __restrict__ out, uint8_t* __restrict__ out8, int n)
{
  const int lane = threadIdx.x & 63;
  const int wave = threadIdx.x >> 6;
  const int g = lane >> 4;
  const int s = lane & 15;
  const int node = blockIdx.x*16 + wave*4 + g;
  if (node >= n) return;

  int e = rowptr[node];
  const int e1 = rowptr[node+1];
  const int fb = s << 3;

  float acc[8] = {0.f,0.f,0.f,0.f,0.f,0.f,0.f,0.f};

  for (; e + 4 <= e1; e += 4){
    unsigned u0 = ec[e], u1 = ec[e+1], u2 = ec[e+2], u3 = ec[e+3];
    uint2 p0 = *(const uint2*)(V8 + (((size_t)(u0 & 0x1FFFF)) << 7) + fb);
    uint2 p1 = *(const uint2*)(V8 + (((size_t)(u1 & 0x1FFFF)) << 7) + fb);
    uint2 p2 = *(const uint2*)(V8 + (((size_t)(u2 & 0x1FFFF)) << 7) + fb);
    uint2 p3 = *(const uint2*)(V8 + (((size_t)(u3 & 0x1FFFF)) << 7) + fb);
    float w0 = edgeWneg(u0), w1 = edgeWneg(u1), w2 = edgeWneg(u2), w3 = edgeWneg(u3);
    acc4_fp8(acc,   p0.x, w0); acc4_fp8(acc+4, p0.y, w0);
    acc4_fp8(acc,   p1.x, w1); acc4_fp8(acc+4, p1.y, w1);
    acc4_fp8(acc,   p2.x, w2); acc4_fp8(acc+4, p2.y, w2);
    acc4_fp8(acc,   p3.x, w3); acc4_fp8(acc+4, p3.y, w3);
  }
  for (; e < e1; ++e){
    unsigned u = ec[e];
    uint2 p = *(const uint2*)(V8 + (((size_t)(u & 0x1FFFF)) << 7) + fb);
    float w = edgeWneg(u);
    acc4_fp8(acc, p.x, w); acc4_fp8(acc+4, p.y, w);
  }

  float r[8];
  #pragma unroll
  for (int i = 0; i < 8; ++i) r[i] = alpha*acc[i];
  if (sub){
    uint4 sv = *(const uint4*)((const char*)sub + (((size_t)node) << 8) + fb*2);
    r[0] -= bflo(sv.x); r[1] -= bfhi(sv.x);
    r[2] -= bflo(sv.y); r[3] -= bfhi(sv.y);
    r[4] -= bflo(sv.z); r[5] -= bfhi(sv.z);
    r[6] -= bflo(sv.w); r[7] -= bfhi(sv.w);
  }
  uint4 o;
  o.x = pack2(r[0], r[1]);
  o.y = pack2(r[2], r[3]);
  o.z = pack2(r[4], r[5]);
  o.w = pack2(r[6], r[7]);
  *(uint4*)((char*)out + (((size_t)node) << 8) + fb*2) = o;
  if (out8){
    uint2 o8;
    o8.x = cvt2fp8(r[0], r[1]) | (cvt2fp8(r[2], r[3]) << 16);
    o8.y = cvt2fp8(r[4], r[5]) | (cvt2fp8(r[6], r[7]) << 16);
    *(uint2*)(out8 + (((size_t)node) << 7) + fb) = o8;
  }
}

// ---------------- head ----------------
__global__ __launch_bounds__(256) void k_head(
    const bf16_t* __restrict__ h, const float* __restrict__ W2, const float* __restrict__ b2,
    float* __restrict__ out, int n)
{
  int node = blockIdx.x*4 + (threadIdx.x >> 6);
  if (node >= n) return;
  int lane = threadIdx.x & 63;
  unsigned int p = *(const unsigned int*)(h + ((size_t)node << 7) + lane*2);
  float h0 = bflo(p), h1 = bfhi(p);
  floatv4 w = *(const floatv4*)(W2 + lane*4);
  float p0 = h0*w[0] + h1*w[2];
  float p1 = h0*w[1] + h1*w[3];
  #pragma unroll
  for (int s = 32; s > 0; s >>= 1){
    p0 += __shfl_xor(p0, s, 64);
    p1 += __shfl_xor(p1, s, 64);
  }
  if (lane == 0){
    float l0 = p0 + b2[0], l1 = p1 + b2[1];
    float m = fmaxf(l0, l1);
    float e0 = __expf(l0 - m), e1 = __expf(l1 - m);
    float inv = 1.f / (e0 + e1);
    out[(size_t)node*2]     = e0 * inv;
    out[(size_t)node*2 + 1] = e1 * inv;
  }
}

// ---------------- launch ----------------

extern "C" void kernel_launch(void* const* d_in, const int* in_sizes, int n_in,
                              void* d_out, int out_size, void* d_ws, size_t ws_size,
                              hipStream_t stream)
{
  const float* x   = (const float*)d_in[0];
  const int*   ei  = (const int*)d_in[1];
  const float* ew  = (const float*)d_in[2];
  const float* W1  = (const float*)d_in[3];
  const float* b1  = (const float*)d_in[4];
  const float* c1W = (const float*)d_in[5];
  const float* c1b = (const float*)d_in[6];
  const float* c2W = (const float*)d_in[7];
  const float* c2b = (const float*)d_in[8];
  const float* W2  = (const float*)d_in[9];
  const float* b2  = (const float*)d_in[10];
  float* out = (float*)d_out;

  const int n = NN, e = NE;
  const int* row = ei;
  const int* col = ei + e;

  char* ws = (char*)d_ws;
  size_t off = 0;
  auto carve = [&](size_t bytes)->void*{
    void* p = ws + off;
    off += (bytes + 255) & ~(size_t)255;
    return p;
  };
  bf16_t* A    = (bf16_t*)carve((size_t)n*128*2);    // h0 -> h1 -> h2
  bf16_t* B    = (bf16_t*)carve((size_t)n*128*2);    // Tx1
  bf16_t* C    = (bf16_t*)carve((size_t)n*128*2);    // Tx2
  uint8_t* q8a = (uint8_t*)carve((size_t)n*128);     // temp(12.8MB) -> A8 -> D8
  uint8_t* B8  = (uint8_t*)carve((size_t)n*128);     // fp8 copy of B
  float*  dinv = (float*)carve((size_t)n*4);
  int*    rowptr = (int*)carve((size_t)(n+1)*4);
  unsigned* ec = (unsigned*)carve((size_t)e*4);
  int*    bincnt = (int*)carve((size_t)NBIN*4);
  int*    binptr = (int*)carve((size_t)(NBIN+1)*4);
  int*    blockbase = (int*)carve((size_t)NBB*NBIN*4);   // 1.22MB
  bf16_t* Wt1  = (bf16_t*)carve(2*128*128*2);
  bf16_t* Wtc1 = (bf16_t*)carve(3*128*128*2);
  bf16_t* Wtc2 = (bf16_t*)carve(3*128*128*2);
  int2* temp = (int2*)q8a;   // disjoint lifetime windows (r11 notes)
  (void)ws_size; (void)in_sizes; (void)n_in; (void)out_size;

  const int NB_W = (n + 3)/4;       // 25000
  const int NB_S = (n + 15)/16;     // 6250

  hipMemsetAsync(bincnt, 0, (size_t)NBIN*4, stream);
  k_binA<<<NBB,256,0,stream>>>(row, bincnt, blockbase);
  k_scanbins<<<1,256,0,stream>>>(bincnt, binptr, rowptr);
  k_binB<<<NBB,256,0,stream>>>(row, col, ew, binptr, blockbase, temp);
  k_binC<<<NBIN,256,0,stream>>>(temp, binptr, ec, rowptr, dinv, n);
  k_norm<<<NB_W,256,0,stream>>>(ec, rowptr, dinv, n);
  k_transw_all<<<(8*16384+255)/256,256,0,stream>>>(W1, c1W, c2W, Wt1, Wtc1, Wtc2);

  // h0 = relu(x @ W1 + b1) -> A (bf16) + q8a (fp8)
  k_gemm1<<<NB_G64,256,0,stream>>>(x, Wt1, b1, A, q8a, n);
  // conv1: Tx1 = Lx(h0) -> B + B8 ; Tx2 = 2*Lx(Tx1) - h0 -> C
  k_spmm8<<<NB_S,256,0,stream>>>(rowptr, ec, q8a, nullptr, 1.f, B, B8, n);
  k_spmm8<<<NB_S,256,0,stream>>>(rowptr, ec, B8, A, 2.f, C, nullptr, n);
  // h1 = relu([h0|Tx1|Tx2] @ Wc1 + b) -> A (in-place safe) + q8a (fp8, now D8)
  k_gemm_nb<<<NB_G,256,0,stream>>>(A, B, C, Wtc1, c1b, A, q8a, n);
  // conv2
  k_spmm8<<<NB_S,256,0,stream>>>(rowptr, ec, q8a, nullptr, 1.f, B, B8, n);
  k_spmm8<<<NB_S,256,0,stream>>>(rowptr, ec, B8, A, 2.f, C, nullptr, n);
  // h2 = relu([h1|Tx1|Tx2] @ Wc2 + b) -> A
  k_gemm_nb<<<NB_G,256,0,stream>>>(A, B, C, Wtc2, c2b, A, nullptr, n);
  // head
  k_head<<<NB_W,256,0,stream>>>(A, W2, b2, out, n);
}

// Round 16
// 379.771 us; speedup vs baseline: 1.1445x; 1.1445x over previous
//
#include <hip/hip_runtime.h>
#include <hip/hip_bf16.h>
#include <stdint.h>

typedef __bf16 bf16_t;
typedef __bf16 bf16x8 __attribute__((ext_vector_type(8)));
typedef float f32x4 __attribute__((ext_vector_type(4)));
typedef float f32x2 __attribute__((ext_vector_type(2)));
typedef float floatv4 __attribute__((ext_vector_type(4)));

static __device__ __forceinline__ float bflo(unsigned int p){ return __uint_as_float(p << 16); }
static __device__ __forceinline__ float bfhi(unsigned int p){ return __uint_as_float(p & 0xffff0000u); }
static __device__ __forceinline__ unsigned int pack2(float lo, float hi){
  union { bf16_t h[2]; unsigned int u; } o;
  o.h[0] = (bf16_t)lo; o.h[1] = (bf16_t)hi;
  return o.u;
}
// async 16B global->LDS DMA
static __device__ __forceinline__ void gload16(const void* g, void* l){
  __builtin_amdgcn_global_load_lds((const __attribute__((address_space(1))) void*)g,
                                   (__attribute__((address_space(3))) void*)l, 16, 0, 0);
}
// fp8 e4m3 (OCP) HW conversions
static __device__ __forceinline__ void acc4_fp8(float* a, unsigned w, float wt){
  f32x2 lo, hi;
  unsigned wh = w >> 16;
  asm("v_cvt_pk_f32_fp8 %0, %1" : "=v"(lo) : "v"(w));
  asm("v_cvt_pk_f32_fp8 %0, %1" : "=v"(hi) : "v"(wh));
  a[0] += wt*lo[0]; a[1] += wt*lo[1]; a[2] += wt*hi[0]; a[3] += wt*hi[1];
}
static __device__ __forceinline__ unsigned cvt2fp8(float a, float b){
  unsigned r;
  asm("v_cvt_pk_fp8_f32 %0, %1, %2" : "=v"(r) : "v"(a), "v"(b));
  return r & 0xffffu;
}
static __device__ __forceinline__ uint8_t cvt1fp8(float a){
  unsigned r;
  asm("v_cvt_pk_fp8_f32 %0, %1, %1" : "=v"(r) : "v"(a));
  return (uint8_t)r;
}
// packed edge: bits[16:0]=col, bits[31:17]=weight f32 bits[30:16] (sign implicit)
static __device__ __forceinline__ unsigned packEdge(int col, float w_pos){
  unsigned b = __float_as_uint(w_pos) + 0x8000u;
  return ((b >> 16) << 17) | (unsigned)col;
}
static __device__ __forceinline__ float edgeWpos(unsigned u){
  return __uint_as_float((u >> 17) << 16);
}
static __device__ __forceinline__ float edgeWneg(unsigned u){
  return __uint_as_float(0x80000000u | ((u >> 17) << 16));
}

constexpr int NN = 100000;
constexpr int NE = 1600000;
constexpr int NB_G  = (NN + 127)/128;    // 782
constexpr int NBIN = (NN + 127)/128;     // 782
constexpr int EPB  = 4096;
constexpr int NBB  = (NE + EPB - 1)/EPB; // 391
constexpr int MAXBE = 3072;

// ---------------- binned CSR build ----------------
__global__ __launch_bounds__(256) void k_binA(const int* __restrict__ row,
                                              int* __restrict__ bincnt,
                                              int* __restrict__ blockbase){
  __shared__ int h[NBIN];
  for (int b = threadIdx.x; b < NBIN; b += 256) h[b] = 0;
  __syncthreads();
  int base = blockIdx.x * EPB;
  for (int k = 0; k < EPB; k += 256){
    int i = base + k + threadIdx.x;
    if (i < NE) atomicAdd(&h[row[i] >> 7], 1);
  }
  __syncthreads();
  for (int b = threadIdx.x; b < NBIN; b += 256){
    int c = h[b];
    blockbase[blockIdx.x * NBIN + b] = c ? atomicAdd(&bincnt[b], c) : 0;
  }
}

__global__ __launch_bounds__(256) void k_scanbins(const int* __restrict__ bincnt,
                                                  int* __restrict__ binptr,
                                                  int* __restrict__ rowptr){
  __shared__ int s[256];
  int t = threadIdx.x;
  int b0 = t*4;
  int c[4]; int tot = 0;
  #pragma unroll
  for (int j = 0; j < 4; ++j){
    int b = b0 + j;
    c[j] = (b < NBIN) ? bincnt[b] : 0;
    tot += c[j];
  }
  s[t] = tot;
  __syncthreads();
  for (int off = 1; off < 256; off <<= 1){
    int v = (t >= off) ? s[t - off] : 0;
    __syncthreads();
    s[t] += v;
    __syncthreads();
  }
  int ex = s[t] - tot;
  #pragma unroll
  for (int j = 0; j < 4; ++j){
    int b = b0 + j;
    if (b < NBIN) binptr[b] = ex;
    ex += c[j];
  }
  if (t == 255){ binptr[NBIN] = ex; rowptr[NN] = ex; }
}

__global__ __launch_bounds__(256) void k_binB(const int* __restrict__ row,
                                              const int* __restrict__ col,
                                              const float* __restrict__ w,
                                              const int* __restrict__ binptr,
                                              const int* __restrict__ blockbase,
                                              int2* __restrict__ temp){
  __shared__ int h[NBIN];
  for (int b = threadIdx.x; b < NBIN; b += 256) h[b] = 0;
  __syncthreads();
  int base = blockIdx.x * EPB;
  for (int k = 0; k < EPB; k += 256){
    int i = base + k + threadIdx.x;
    if (i < NE){
      int r = row[i];
      int b = r >> 7;
      int rank = atomicAdd(&h[b], 1);
      int pos = binptr[b] + blockbase[blockIdx.x * NBIN + b] + rank;
      temp[pos] = make_int2(col[i] | ((r & 127) << 17), __float_as_int(w[i]));
    }
  }
}

__global__ __launch_bounds__(256) void k_binC(const int2* __restrict__ temp,
                                              const int* __restrict__ binptr,
                                              unsigned* __restrict__ ec,
                                              int* __restrict__ rowptr,
                                              float* __restrict__ dinv, int n){
  __shared__ int2 sbuf[MAXBE];
  __shared__ int cnt[128];
  __shared__ int scan[128];
  __shared__ int estart[128];
  const int b = blockIdx.x;
  const int e0 = binptr[b];
  int nb = binptr[b+1] - e0; if (nb > MAXBE) nb = MAXBE;
  const int t = threadIdx.x;
  if (t < 128) cnt[t] = 0;
  __syncthreads();
  for (int k = t; k < nb; k += 256)
    atomicAdd(&cnt[(temp[e0+k].x >> 17) & 127], 1);
  __syncthreads();
  if (t < 128) scan[t] = cnt[t];
  __syncthreads();
  for (int off = 1; off < 128; off <<= 1){
    int v = (t < 128 && t >= off) ? scan[t - off] : 0;
    __syncthreads();
    if (t < 128) scan[t] += v;
    __syncthreads();
  }
  if (t < 128){ estart[t] = scan[t] - cnt[t]; cnt[t] = 0; }
  __syncthreads();
  for (int k = t; k < nb; k += 256){
    int2 q = temp[e0+k];
    int rl = (q.x >> 17) & 127;
    int rank = atomicAdd(&cnt[rl], 1);
    sbuf[estart[rl] + rank] = q;
  }
  __syncthreads();
  for (int k = t; k < nb; k += 256){
    int2 q = sbuf[k];
    ec[e0 + k] = packEdge(q.x & 0x1FFFF, __int_as_float(q.y));
  }
  if (t < 128){
    int gid = b*128 + t;
    if (gid < n){
      rowptr[gid] = e0 + estart[t];
      float s = 0.f;
      int s0 = estart[t], c = cnt[t];
      for (int j = 0; j < c; ++j) s += __int_as_float(sbuf[s0+j].y);
      dinv[gid] = (s > 0.f) ? rsqrtf(s) : 0.f;
    }
  }
}

__global__ __launch_bounds__(256) void k_norm(unsigned* __restrict__ ec,
                                              const int* __restrict__ rowptr,
                                              const float* __restrict__ dinv, int n){
  int node = blockIdx.x*4 + (threadIdx.x >> 6);
  if (node >= n) return;
  int lane = threadIdx.x & 63;
  int e0 = rowptr[node], e1 = rowptr[node+1];
  float dr = dinv[node];
  for (int e = e0 + lane; e < e1; e += 64){
    unsigned u = ec[e];
    int c = u & 0x1FFFF;
    float wn = dr * edgeWpos(u) * dinv[c];
    ec[e] = packEdge(c, wn);
  }
}

__global__ void k_transw_all(const float* __restrict__ W1, const float* __restrict__ c1W,
                             const float* __restrict__ c2W, bf16_t* __restrict__ Wt1,
                             bf16_t* __restrict__ Wtc1, bf16_t* __restrict__ Wtc2){
  int idx = blockIdx.x*256 + threadIdx.x;   // 8*16384 total
  const float* src; bf16_t* dst; int local;
  if (idx < 2*16384)      { src = W1;  dst = Wt1;  local = idx; }
  else if (idx < 5*16384) { src = c1W; dst = Wtc1; local = idx - 2*16384; }
  else                    { src = c2W; dst = Wtc2; local = idx - 5*16384; }
  int c = local >> 14, r = (local >> 7) & 127, j = local & 127;
  dst[(c << 14) + (j << 7) + r] = (bf16_t)src[local];
}

// ---------------- GEMM1 (r11-proven): BM=128, async dbuf LDS staging --------------
__global__ __launch_bounds__(256) void k_gemm1(
    const float* __restrict__ x, const bf16_t* __restrict__ Wt, const float* __restrict__ bias,
    bf16_t* __restrict__ out, uint8_t* __restrict__ out8, int M)
{
  __shared__ uint8_t lds[2][16384];
  const int tid = threadIdx.x;
  const int wave = tid >> 6, lane = tid & 63;
  const int wm = wave >> 1, wn = wave & 1;
  const int l15 = lane & 15, lq = lane >> 4;
  const int blockRow = blockIdx.x * 128;
  const int strow = tid >> 3;
  const int scell = tid & 7;

  f32x4 acc[4][4];
  #pragma unroll
  for (int a = 0; a < 4; ++a)
    #pragma unroll
    for (int b = 0; b < 4; ++b) acc[a][b] = f32x4{0.f,0.f,0.f,0.f};

  #pragma unroll
  for (int j = 0; j < 4; ++j){
    int r = j*32 + strow;
    int gr = blockRow + r; if (gr > M-1) gr = M-1;
    gload16((const char*)x + (size_t)gr*1024 + ((scell ^ (r&7)) << 4),
            &lds[0][j*4096 + tid*16]);
  }

  #pragma unroll
  for (int s = 0; s < 8; ++s){
    if (s < 7){
      #pragma unroll
      for (int j = 0; j < 4; ++j){
        int r = j*32 + strow;
        int gr = blockRow + r; if (gr > M-1) gr = M-1;
        gload16((const char*)x + (size_t)gr*1024 + (s+1)*128 + ((scell ^ (r&7)) << 4),
                &lds[(s+1)&1][j*4096 + tid*16]);
      }
    }
    __syncthreads();
    const uint8_t* buf = lds[s&1];
    bf16x8 af[4], bfr[4];
    #pragma unroll
    for (int fm = 0; fm < 4; ++fm){
      int r = wm*64 + fm*16 + l15;
      floatv4 v0 = *(const floatv4*)(buf + r*128 + (((lq*2    ) ^ (r&7)) << 4));
      floatv4 v1 = *(const floatv4*)(buf + r*128 + (((lq*2 + 1) ^ (r&7)) << 4));
      bf16x8 t;
      t[0]=(bf16_t)v0[0]; t[1]=(bf16_t)v0[1]; t[2]=(bf16_t)v0[2]; t[3]=(bf16_t)v0[3];
      t[4]=(bf16_t)v1[0]; t[5]=(bf16_t)v1[1]; t[6]=(bf16_t)v1[2]; t[7]=(bf16_t)v1[3];
      af[fm] = t;
    }
    #pragma unroll
    for (int fn = 0; fn < 4; ++fn)
      bfr[fn] = *(const bf16x8*)(Wt + ((size_t)(((s>>2) << 7) + wn*64 + fn*16 + l15) << 7) + (s&3)*32 + lq*8);
    #pragma unroll
    for (int fm = 0; fm < 4; ++fm)
      #pragma unroll
      for (int fn = 0; fn < 4; ++fn)
        acc[fm][fn] = __builtin_amdgcn_mfma_f32_16x16x32_bf16(af[fm], bfr[fn], acc[fm][fn], 0, 0, 0);
    __syncthreads();
  }
  #pragma unroll
  for (int fm = 0; fm < 4; ++fm){
    #pragma unroll
    for (int j = 0; j < 4; ++j){
      int growo = blockRow + wm*64 + fm*16 + lq*4 + j;
      if (growo < M){
        #pragma unroll
        for (int fn = 0; fn < 4; ++fn){
          int c = wn*64 + fn*16 + l15;
          float v = fmaxf(acc[fm][fn][j] + bias[c], 0.f);
          out[((size_t)growo << 7) + c] = (bf16_t)v;
          out8[((size_t)growo << 7) + c] = cvt1fp8(v);
        }
      }
    }
  }
}

// ---------------- conv GEMM (r11-proven): BM=128, async dbuf, 6 steps BK=64 -------
__global__ __launch_bounds__(256) void k_gemm_nb(
    const bf16_t* __restrict__ a0, const bf16_t* __restrict__ a1, const bf16_t* __restrict__ a2,
    const bf16_t* __restrict__ Wt, const float* __restrict__ bias,
    bf16_t* __restrict__ out, uint8_t* __restrict__ out8, int M)
{
  __shared__ uint8_t lds[2][16384];
  const int tid = threadIdx.x;
  const int wave = tid >> 6, lane = tid & 63;
  const int wm = wave >> 1, wn = wave & 1;
  const int l15 = lane & 15, lq = lane >> 4;
  const int blockRow = blockIdx.x * 128;
  const int strow = tid >> 3;
  const int scell = tid & 7;

  f32x4 acc[4][4];
  #pragma unroll
  for (int a = 0; a < 4; ++a)
    #pragma unroll
    for (int b = 0; b < 4; ++b) acc[a][b] = f32x4{0.f,0.f,0.f,0.f};

  #pragma unroll
  for (int j = 0; j < 4; ++j){
    int r = j*32 + strow;
    int gr = blockRow + r; if (gr > M-1) gr = M-1;
    gload16((const char*)a0 + (size_t)gr*256 + ((scell ^ (r&7)) << 4),
            &lds[0][j*4096 + tid*16]);
  }

  #pragma unroll
  for (int s = 0; s < 6; ++s){
    if (s < 5){
      const int sn = s + 1;
      const bf16_t* srcn = (sn>>1) == 0 ? a0 : ((sn>>1) == 1 ? a1 : a2);
      #pragma unroll
      for (int j = 0; j < 4; ++j){
        int r = j*32 + strow;
        int gr = blockRow + r; if (gr > M-1) gr = M-1;
        gload16((const char*)srcn + (size_t)gr*256 + (sn&1)*128 + ((scell ^ (r&7)) << 4),
                &lds[sn&1][j*4096 + tid*16]);
      }
    }
    __syncthreads();
    const uint8_t* buf = lds[s&1];
    #pragma unroll
    for (int kk32 = 0; kk32 < 2; ++kk32){
      bf16x8 af[4], bfr[4];
      #pragma unroll
      for (int fm = 0; fm < 4; ++fm){
        int r = wm*64 + fm*16 + l15;
        af[fm] = *(const bf16x8*)(buf + r*128 + (((kk32*4 + lq) ^ (r&7)) << 4));
      }
      #pragma unroll
      for (int fn = 0; fn < 4; ++fn)
        bfr[fn] = *(const bf16x8*)(Wt + ((size_t)(((s>>1) << 7) + wn*64 + fn*16 + l15) << 7)
                                   + (s&1)*64 + kk32*32 + lq*8);
      #pragma unroll
      for (int fm = 0; fm < 4; ++fm)
        #pragma unroll
        for (int fn = 0; fn < 4; ++fn)
          acc[fm][fn] = __builtin_amdgcn_mfma_f32_16x16x32_bf16(af[fm], bfr[fn], acc[fm][fn], 0, 0, 0);
    }
    __syncthreads();
  }
  #pragma unroll
  for (int fm = 0; fm < 4; ++fm){
    #pragma unroll
    for (int j = 0; j < 4; ++j){
      int growo = blockRow + wm*64 + fm*16 + lq*4 + j;
      if (growo < M){
        #pragma unroll
        for (int fn = 0; fn < 4; ++fn){
          int c = wn*64 + fn*16 + l15;
          float v = fmaxf(acc[fm][fn][j] + bias[c], 0.f);
          out[((size_t)growo << 7) + c] = (bf16_t)v;
          if (out8) out8[((size_t)growo << 7) + c] = cvt1fp8(v);
        }
      }
    }
  }
}

// ---------------- SpMM fp8 v2: 8-deep unrolled gather loop (2x in-flight bytes) ----
__global__ __launch_bounds__(256) void k_spmm8(
    const int* __restrict__ rowptr, const unsigned* __restrict__ ec,
    const uint8_t* __restrict__ V8, const bf16_t* __restrict__ sub, float alpha,
    bf16_t* __restrict__ out, uint8_t* __restrict__ out8, int n)
{
  const int lane = threadIdx.x & 63;
  const int wave = threadIdx.x >> 6;
  const int g = lane >> 4;
  const int s = lane & 15;
  const int node = blockIdx.x*16 + wave*4 + g;
  if (node >= n) return;

  int e = rowptr[node];
  const int e1 = rowptr[node+1];
  const int fb = s << 3;

  float acc[8] = {0.f,0.f,0.f,0.f,0.f,0.f,0.f,0.f};

  for (; e + 8 <= e1; e += 8){
    unsigned u0 = ec[e],   u1 = ec[e+1], u2 = ec[e+2], u3 = ec[e+3];
    unsigned u4 = ec[e+4], u5 = ec[e+5], u6 = ec[e+6], u7 = ec[e+7];
    uint2 p0 = *(const uint2*)(V8 + (((size_t)(u0 & 0x1FFFF)) << 7) + fb);
    uint2 p1 = *(const uint2*)(V8 + (((size_t)(u1 & 0x1FFFF)) << 7) + fb);
    uint2 p2 = *(const uint2*)(V8 + (((size_t)(u2 & 0x1FFFF)) << 7) + fb);
    uint2 p3 = *(const uint2*)(V8 + (((size_t)(u3 & 0x1FFFF)) << 7) + fb);
    uint2 p4 = *(const uint2*)(V8 + (((size_t)(u4 & 0x1FFFF)) << 7) + fb);
    uint2 p5 = *(const uint2*)(V8 + (((size_t)(u5 & 0x1FFFF)) << 7) + fb);
    uint2 p6 = *(const uint2*)(V8 + (((size_t)(u6 & 0x1FFFF)) << 7) + fb);
    uint2 p7 = *(const uint2*)(V8 + (((size_t)(u7 & 0x1FFFF)) << 7) + fb);
    float w0 = edgeWneg(u0), w1 = edgeWneg(u1), w2 = edgeWneg(u2), w3 = edgeWneg(u3);
    float w4 = edgeWneg(u4), w5 = edgeWneg(u5), w6 = edgeWneg(u6), w7 = edgeWneg(u7);
    acc4_fp8(acc,   p0.x, w0); acc4_fp8(acc+4, p0.y, w0);
    acc4_fp8(acc,   p1.x, w1); acc4_fp8(acc+4, p1.y, w1);
    acc4_fp8(acc,   p2.x, w2); acc4_fp8(acc+4, p2.y, w2);
    acc4_fp8(acc,   p3.x, w3); acc4_fp8(acc+4, p3.y, w3);
    acc4_fp8(acc,   p4.x, w4); acc4_fp8(acc+4, p4.y, w4);
    acc4_fp8(acc,   p5.x, w5); acc4_fp8(acc+4, p5.y, w5);
    acc4_fp8(acc,   p6.x, w6); acc4_fp8(acc+4, p6.y, w6);
    acc4_fp8(acc,   p7.x, w7); acc4_fp8(acc+4, p7.y, w7);
  }
  for (; e + 4 <= e1; e += 4){
    unsigned u0 = ec[e], u1 = ec[e+1], u2 = ec[e+2], u3 = ec[e+3];
    uint2 p0 = *(const uint2*)(V8 + (((size_t)(u0 & 0x1FFFF)) << 7) + fb);
    uint2 p1 = *(const uint2*)(V8 + (((size_t)(u1 & 0x1FFFF)) << 7) + fb);
    uint2 p2 = *(const uint2*)(V8 + (((size_t)(u2 & 0x1FFFF)) << 7) + fb);
    uint2 p3 = *(const uint2*)(V8 + (((size_t)(u3 & 0x1FFFF)) << 7) + fb);
    float w0 = edgeWneg(u0), w1 = edgeWneg(u1), w2 = edgeWneg(u2), w3 = edgeWneg(u3);
    acc4_fp8(acc,   p0.x, w0); acc4_fp8(acc+4, p0.y, w0);
    acc4_fp8(acc,   p1.x, w1); acc4_fp8(acc+4, p1.y, w1);
    acc4_fp8(acc,   p2.x, w2); acc4_fp8(acc+4, p2.y, w2);
    acc4_fp8(acc,   p3.x, w3); acc4_fp8(acc+4, p3.y, w3);
  }
  for (; e < e1; ++e){
    unsigned u = ec[e];
    uint2 p = *(const uint2*)(V8 + (((size_t)(u & 0x1FFFF)) << 7) + fb);
    float w = edgeWneg(u);
    acc4_fp8(acc, p.x, w); acc4_fp8(acc+4, p.y, w);
  }

  float r[8];
  #pragma unroll
  for (int i = 0; i < 8; ++i) r[i] = alpha*acc[i];
  if (sub){
    uint4 sv = *(const uint4*)((const char*)sub + (((size_t)node) << 8) + fb*2);
    r[0] -= bflo(sv.x); r[1] -= bfhi(sv.x);
    r[2] -= bflo(sv.y); r[3] -= bfhi(sv.y);
    r[4] -= bflo(sv.z); r[5] -= bfhi(sv.z);
    r[6] -= bflo(sv.w); r[7] -= bfhi(sv.w);
  }
  uint4 o;
  o.x = pack2(r[0], r[1]);
  o.y = pack2(r[2], r[3]);
  o.z = pack2(r[4], r[5]);
  o.w = pack2(r[6], r[7]);
  *(uint4*)((char*)out + (((size_t)node) << 8) + fb*2) = o;
  if (out8){
    uint2 o8;
    o8.x = cvt2fp8(r[0], r[1]) | (cvt2fp8(r[2], r[3]) << 16);
    o8.y = cvt2fp8(r[4], r[5]) | (cvt2fp8(r[6], r[7]) << 16);
    *(uint2*)(out8 + (((size_t)node) << 7) + fb) = o8;
  }
}

// ---------------- head ----------------
__global__ __launch_bounds__(256) void k_head(
    const bf16_t* __restrict__ h, const float* __restrict__ W2, const float* __restrict__ b2,
    float* __restrict__ out, int n)
{
  int node = blockIdx.x*4 + (threadIdx.x >> 6);
  if (node >= n) return;
  int lane = threadIdx.x & 63;
  unsigned int p = *(const unsigned int*)(h + ((size_t)node << 7) + lane*2);
  float h0 = bflo(p), h1 = bfhi(p);
  floatv4 w = *(const floatv4*)(W2 + lane*4);
  float p0 = h0*w[0] + h1*w[2];
  float p1 = h0*w[1] + h1*w[3];
  #pragma unroll
  for (int s = 32; s > 0; s >>= 1){
    p0 += __shfl_xor(p0, s, 64);
    p1 += __shfl_xor(p1, s, 64);
  }
  if (lane == 0){
    float l0 = p0 + b2[0], l1 = p1 + b2[1];
    float m = fmaxf(l0, l1);
    float e0 = __expf(l0 - m), e1 = __expf(l1 - m);
    float inv = 1.f / (e0 + e1);
    out[(size_t)node*2]     = e0 * inv;
    out[(size_t)node*2 + 1] = e1 * inv;
  }
}

// ---------------- launch ----------------

extern "C" void kernel_launch(void* const* d_in, const int* in_sizes, int n_in,
                              void* d_out, int out_size, void* d_ws, size_t ws_size,
                              hipStream_t stream)
{
  const float* x   = (const float*)d_in[0];
  const int*   ei  = (const int*)d_in[1];
  const float* ew  = (const float*)d_in[2];
  const float* W1  = (const float*)d_in[3];
  const float* b1  = (const float*)d_in[4];
  const float* c1W = (const float*)d_in[5];
  const float* c1b = (const float*)d_in[6];
  const float* c2W = (const float*)d_in[7];
  const float* c2b = (const float*)d_in[8];
  const float* W2  = (const float*)d_in[9];
  const float* b2  = (const float*)d_in[10];
  float* out = (float*)d_out;

  const int n = NN, e = NE;
  const int* row = ei;
  const int* col = ei + e;

  char* ws = (char*)d_ws;
  size_t off = 0;
  auto carve = [&](size_t bytes)->void*{
    void* p = ws + off;
    off += (bytes + 255) & ~(size_t)255;
    return p;
  };
  bf16_t* A    = (bf16_t*)carve((size_t)n*128*2);    // h0 -> h1 -> h2
  bf16_t* B    = (bf16_t*)carve((size_t)n*128*2);    // Tx1
  bf16_t* C    = (bf16_t*)carve((size_t)n*128*2);    // Tx2
  uint8_t* q8a = (uint8_t*)carve((size_t)n*128);     // temp(12.8MB) -> A8 -> D8
  uint8_t* B8  = (uint8_t*)carve((size_t)n*128);     // fp8 copy of B
  float*  dinv = (float*)carve((size_t)n*4);
  int*    rowptr = (int*)carve((size_t)(n+1)*4);
  unsigned* ec = (unsigned*)carve((size_t)e*4);
  int*    bincnt = (int*)carve((size_t)NBIN*4);
  int*    binptr = (int*)carve((size_t)(NBIN+1)*4);
  int*    blockbase = (int*)carve((size_t)NBB*NBIN*4);   // 1.22MB
  bf16_t* Wt1  = (bf16_t*)carve(2*128*128*2);
  bf16_t* Wtc1 = (bf16_t*)carve(3*128*128*2);
  bf16_t* Wtc2 = (bf16_t*)carve(3*128*128*2);
  int2* temp = (int2*)q8a;   // disjoint lifetime windows (r11 notes)
  (void)ws_size; (void)in_sizes; (void)n_in; (void)out_size;

  const int NB_W = (n + 3)/4;       // 25000
  const int NB_S = (n + 15)/16;     // 6250

  hipMemsetAsync(bincnt, 0, (size_t)NBIN*4, stream);
  k_binA<<<NBB,256,0,stream>>>(row, bincnt, blockbase);
  k_scanbins<<<1,256,0,stream>>>(bincnt, binptr, rowptr);
  k_binB<<<NBB,256,0,stream>>>(row, col, ew, binptr, blockbase, temp);
  k_binC<<<NBIN,256,0,stream>>>(temp, binptr, ec, rowptr, dinv, n);
  k_norm<<<NB_W,256,0,stream>>>(ec, rowptr, dinv, n);
  k_transw_all<<<(8*16384+255)/256,256,0,stream>>>(W1, c1W, c2W, Wt1, Wtc1, Wtc2);

  // h0 = relu(x @ W1 + b1) -> A (bf16) + q8a (fp8)
  k_gemm1<<<NB_G,256,0,stream>>>(x, Wt1, b1, A, q8a, n);
  // conv1: Tx1 = Lx(h0) -> B + B8 ; Tx2 = 2*Lx(Tx1) - h0 -> C
  k_spmm8<<<NB_S,256,0,stream>>>(rowptr, ec, q8a, nullptr, 1.f, B, B8, n);
  k_spmm8<<<NB_S,256,0,stream>>>(rowptr, ec, B8, A, 2.f, C, nullptr, n);
  // h1 = relu([h0|Tx1|Tx2] @ Wc1 + b) -> A (in-place safe) + q8a (fp8, now D8)
  k_gemm_nb<<<NB_G,256,0,stream>>>(A, B, C, Wtc1, c1b, A, q8a, n);
  // conv2
  k_spmm8<<<NB_S,256,0,stream>>>(rowptr, ec, q8a, nullptr, 1.f, B, B8, n);
  k_spmm8<<<NB_S,256,0,stream>>>(rowptr, ec, B8, A, 2.f, C, nullptr, n);
  // h2 = relu([h1|Tx1|Tx2] @ Wc2 + b) -> A
  k_gemm_nb<<<NB_G,256,0,stream>>>(A, B, C, Wtc2, c2b, A, nullptr, n);
  // head
  k_head<<<NB_W,256,0,stream>>>(A, W2, b2, out, n);
}

// Round 17
// 359.697 us; speedup vs baseline: 1.2084x; 1.0558x over previous
//
#include <hip/hip_runtime.h>
#include <hip/hip_bf16.h>
#include <stdint.h>

typedef __bf16 bf16_t;
typedef __bf16 bf16x8 __attribute__((ext_vector_type(8)));
typedef float f32x4 __attribute__((ext_vector_type(4)));
typedef float f32x2 __attribute__((ext_vector_type(2)));
typedef float floatv4 __attribute__((ext_vector_type(4)));

static __device__ __forceinline__ float bflo(unsigned int p){ return __uint_as_float(p << 16); }
static __device__ __forceinline__ float bfhi(unsigned int p){ return __uint_as_float(p & 0xffff0000u); }
static __device__ __forceinline__ unsigned int pack2(float lo, float hi){
  union { bf16_t h[2]; unsigned int u; } o;
  o.h[0] = (bf16_t)lo; o.h[1] = (bf16_t)hi;
  return o.u;
}
// async 16B global->LDS DMA
static __device__ __forceinline__ void gload16(const void* g, void* l){
  __builtin_amdgcn_global_load_lds((const __attribute__((address_space(1))) void*)g,
                                   (__attribute__((address_space(3))) void*)l, 16, 0, 0);
}
// fp8 e4m3 (OCP) HW conversions
static __device__ __forceinline__ void acc4_fp8(float* a, unsigned w, float wt){
  f32x2 lo, hi;
  unsigned wh = w >> 16;
  asm("v_cvt_pk_f32_fp8 %0, %1" : "=v"(lo) : "v"(w));
  asm("v_cvt_pk_f32_fp8 %0, %1" : "=v"(hi) : "v"(wh));
  a[0] += wt*lo[0]; a[1] += wt*lo[1]; a[2] += wt*hi[0]; a[3] += wt*hi[1];
}
static __device__ __forceinline__ void dec4_fp8(float* d, unsigned w){
  f32x2 lo, hi;
  unsigned wh = w >> 16;
  asm("v_cvt_pk_f32_fp8 %0, %1" : "=v"(lo) : "v"(w));
  asm("v_cvt_pk_f32_fp8 %0, %1" : "=v"(hi) : "v"(wh));
  d[0] = lo[0]; d[1] = lo[1]; d[2] = hi[0]; d[3] = hi[1];
}
static __device__ __forceinline__ unsigned cvt2fp8(float a, float b){
  unsigned r;
  asm("v_cvt_pk_fp8_f32 %0, %1, %2" : "=v"(r) : "v"(a), "v"(b));
  return r & 0xffffu;
}
static __device__ __forceinline__ uint8_t cvt1fp8(float a){
  unsigned r;
  asm("v_cvt_pk_fp8_f32 %0, %1, %1" : "=v"(r) : "v"(a));
  return (uint8_t)r;
}
// packed edge: bits[16:0]=col, bits[31:17]=weight f32 bits[30:16] (sign implicit)
static __device__ __forceinline__ unsigned packEdge(int col, float w_pos){
  unsigned b = __float_as_uint(w_pos) + 0x8000u;
  return ((b >> 16) << 17) | (unsigned)col;
}
static __device__ __forceinline__ float edgeWpos(unsigned u){
  return __uint_as_float((u >> 17) << 16);
}
static __device__ __forceinline__ float edgeWneg(unsigned u){
  return __uint_as_float(0x80000000u | ((u >> 17) << 16));
}

constexpr int NN = 100000;
constexpr int NE = 1600000;
constexpr int NB_G  = (NN + 127)/128;    // 782
constexpr int NBIN = (NN + 127)/128;     // 782
constexpr int EPB  = 4096;
constexpr int NBB  = (NE + EPB - 1)/EPB; // 391
constexpr int MAXBE = 3072;

// ---------------- binned CSR build ----------------
__global__ __launch_bounds__(256) void k_binA(const int* __restrict__ row,
                                              int* __restrict__ bincnt,
                                              int* __restrict__ blockbase){
  __shared__ int h[NBIN];
  for (int b = threadIdx.x; b < NBIN; b += 256) h[b] = 0;
  __syncthreads();
  int base = blockIdx.x * EPB;
  for (int k = 0; k < EPB; k += 256){
    int i = base + k + threadIdx.x;
    if (i < NE) atomicAdd(&h[row[i] >> 7], 1);
  }
  __syncthreads();
  for (int b = threadIdx.x; b < NBIN; b += 256){
    int c = h[b];
    blockbase[blockIdx.x * NBIN + b] = c ? atomicAdd(&bincnt[b], c) : 0;
  }
}

__global__ __launch_bounds__(256) void k_scanbins(const int* __restrict__ bincnt,
                                                  int* __restrict__ binptr,
                                                  int* __restrict__ rowptr){
  __shared__ int s[256];
  int t = threadIdx.x;
  int b0 = t*4;
  int c[4]; int tot = 0;
  #pragma unroll
  for (int j = 0; j < 4; ++j){
    int b = b0 + j;
    c[j] = (b < NBIN) ? bincnt[b] : 0;
    tot += c[j];
  }
  s[t] = tot;
  __syncthreads();
  for (int off = 1; off < 256; off <<= 1){
    int v = (t >= off) ? s[t - off] : 0;
    __syncthreads();
    s[t] += v;
    __syncthreads();
  }
  int ex = s[t] - tot;
  #pragma unroll
  for (int j = 0; j < 4; ++j){
    int b = b0 + j;
    if (b < NBIN) binptr[b] = ex;
    ex += c[j];
  }
  if (t == 255){ binptr[NBIN] = ex; rowptr[NN] = ex; }
}

__global__ __launch_bounds__(256) void k_binB(const int* __restrict__ row,
                                              const int* __restrict__ col,
                                              const float* __restrict__ w,
                                              const int* __restrict__ binptr,
                                              const int* __restrict__ blockbase,
                                              int2* __restrict__ temp){
  __shared__ int h[NBIN];
  for (int b = threadIdx.x; b < NBIN; b += 256) h[b] = 0;
  __syncthreads();
  int base = blockIdx.x * EPB;
  for (int k = 0; k < EPB; k += 256){
    int i = base + k + threadIdx.x;
    if (i < NE){
      int r = row[i];
      int b = r >> 7;
      int rank = atomicAdd(&h[b], 1);
      int pos = binptr[b] + blockbase[blockIdx.x * NBIN + b] + rank;
      temp[pos] = make_int2(col[i] | ((r & 127) << 17), __float_as_int(w[i]));
    }
  }
}

__global__ __launch_bounds__(256) void k_binC(const int2* __restrict__ temp,
                                              const int* __restrict__ binptr,
                                              unsigned* __restrict__ ec,
                                              int* __restrict__ rowptr,
                                              float* __restrict__ dinv, int n){
  __shared__ int2 sbuf[MAXBE];
  __shared__ int cnt[128];
  __shared__ int scan[128];
  __shared__ int estart[128];
  const int b = blockIdx.x;
  const int e0 = binptr[b];
  int nb = binptr[b+1] - e0; if (nb > MAXBE) nb = MAXBE;
  const int t = threadIdx.x;
  if (t < 128) cnt[t] = 0;
  __syncthreads();
  for (int k = t; k < nb; k += 256)
    atomicAdd(&cnt[(temp[e0+k].x >> 17) & 127], 1);
  __syncthreads();
  if (t < 128) scan[t] = cnt[t];
  __syncthreads();
  for (int off = 1; off < 128; off <<= 1){
    int v = (t < 128 && t >= off) ? scan[t - off] : 0;
    __syncthreads();
    if (t < 128) scan[t] += v;
    __syncthreads();
  }
  if (t < 128){ estart[t] = scan[t] - cnt[t]; cnt[t] = 0; }
  __syncthreads();
  for (int k = t; k < nb; k += 256){
    int2 q = temp[e0+k];
    int rl = (q.x >> 17) & 127;
    int rank = atomicAdd(&cnt[rl], 1);
    sbuf[estart[rl] + rank] = q;
  }
  __syncthreads();
  for (int k = t; k < nb; k += 256){
    int2 q = sbuf[k];
    ec[e0 + k] = packEdge(q.x & 0x1FFFF, __int_as_float(q.y));
  }
  if (t < 128){
    int gid = b*128 + t;
    if (gid < n){
      rowptr[gid] = e0 + estart[t];
      float s = 0.f;
      int s0 = estart[t], c = cnt[t];
      for (int j = 0; j < c; ++j) s += __int_as_float(sbuf[s0+j].y);
      dinv[gid] = (s > 0.f) ? rsqrtf(s) : 0.f;
    }
  }
}

__global__ __launch_bounds__(256) void k_norm(unsigned* __restrict__ ec,
                                              const int* __restrict__ rowptr,
                                              const float* __restrict__ dinv, int n){
  int node = blockIdx.x*4 + (threadIdx.x >> 6);
  if (node >= n) return;
  int lane = threadIdx.x & 63;
  int e0 = rowptr[node], e1 = rowptr[node+1];
  float dr = dinv[node];
  for (int e = e0 + lane; e < e1; e += 64){
    unsigned u = ec[e];
    int c = u & 0x1FFFF;
    float wn = dr * edgeWpos(u) * dinv[c];
    ec[e] = packEdge(c, wn);
  }
}

// weights: Wt1 bf16 [chunk][col][k] (gemm1) ; W8c1/W8c2 fp8 [chunk][col][k] (conv)
__global__ void k_transw_all(const float* __restrict__ W1, const float* __restrict__ c1W,
                             const float* __restrict__ c2W, bf16_t* __restrict__ Wt1,
                             uint8_t* __restrict__ W8c1, uint8_t* __restrict__ W8c2){
  int idx = blockIdx.x*256 + threadIdx.x;   // 8*16384 total
  if (idx < 2*16384){
    int c = idx >> 14, r = (idx >> 7) & 127, j = idx & 127;
    Wt1[(c << 14) + (j << 7) + r] = (bf16_t)W1[idx];
  } else if (idx < 5*16384){
    int local = idx - 2*16384;
    int c = local >> 14, r = (local >> 7) & 127, j = local & 127;
    W8c1[(c << 14) + (j << 7) + r] = cvt1fp8(c1W[local]);
  } else {
    int local = idx - 5*16384;
    int c = local >> 14, r = (local >> 7) & 127, j = local & 127;
    W8c2[(c << 14) + (j << 7) + r] = cvt1fp8(c2W[local]);
  }
}

// ---------------- GEMM1 (r11 structure): BM=128, async dbuf; fp8-only output ------
__global__ __launch_bounds__(256) void k_gemm1(
    const float* __restrict__ x, const bf16_t* __restrict__ Wt, const float* __restrict__ bias,
    uint8_t* __restrict__ out8, int M)
{
  __shared__ uint8_t lds[2][16384];
  const int tid = threadIdx.x;
  const int wave = tid >> 6, lane = tid & 63;
  const int wm = wave >> 1, wn = wave & 1;
  const int l15 = lane & 15, lq = lane >> 4;
  const int blockRow = blockIdx.x * 128;
  const int strow = tid >> 3;
  const int scell = tid & 7;

  f32x4 acc[4][4];
  #pragma unroll
  for (int a = 0; a < 4; ++a)
    #pragma unroll
    for (int b = 0; b < 4; ++b) acc[a][b] = f32x4{0.f,0.f,0.f,0.f};

  #pragma unroll
  for (int j = 0; j < 4; ++j){
    int r = j*32 + strow;
    int gr = blockRow + r; if (gr > M-1) gr = M-1;
    gload16((const char*)x + (size_t)gr*1024 + ((scell ^ (r&7)) << 4),
            &lds[0][j*4096 + tid*16]);
  }

  #pragma unroll
  for (int s = 0; s < 8; ++s){
    if (s < 7){
      #pragma unroll
      for (int j = 0; j < 4; ++j){
        int r = j*32 + strow;
        int gr = blockRow + r; if (gr > M-1) gr = M-1;
        gload16((const char*)x + (size_t)gr*1024 + (s+1)*128 + ((scell ^ (r&7)) << 4),
                &lds[(s+1)&1][j*4096 + tid*16]);
      }
    }
    __syncthreads();
    const uint8_t* buf = lds[s&1];
    bf16x8 af[4], bfr[4];
    #pragma unroll
    for (int fm = 0; fm < 4; ++fm){
      int r = wm*64 + fm*16 + l15;
      floatv4 v0 = *(const floatv4*)(buf + r*128 + (((lq*2    ) ^ (r&7)) << 4));
      floatv4 v1 = *(const floatv4*)(buf + r*128 + (((lq*2 + 1) ^ (r&7)) << 4));
      bf16x8 t;
      t[0]=(bf16_t)v0[0]; t[1]=(bf16_t)v0[1]; t[2]=(bf16_t)v0[2]; t[3]=(bf16_t)v0[3];
      t[4]=(bf16_t)v1[0]; t[5]=(bf16_t)v1[1]; t[6]=(bf16_t)v1[2]; t[7]=(bf16_t)v1[3];
      af[fm] = t;
    }
    #pragma unroll
    for (int fn = 0; fn < 4; ++fn)
      bfr[fn] = *(const bf16x8*)(Wt + ((size_t)(((s>>2) << 7) + wn*64 + fn*16 + l15) << 7) + (s&3)*32 + lq*8);
    #pragma unroll
    for (int fm = 0; fm < 4; ++fm)
      #pragma unroll
      for (int fn = 0; fn < 4; ++fn)
        acc[fm][fn] = __builtin_amdgcn_mfma_f32_16x16x32_bf16(af[fm], bfr[fn], acc[fm][fn], 0, 0, 0);
    __syncthreads();
  }
  #pragma unroll
  for (int fm = 0; fm < 4; ++fm){
    #pragma unroll
    for (int j = 0; j < 4; ++j){
      int growo = blockRow + wm*64 + fm*16 + lq*4 + j;
      if (growo < M){
        #pragma unroll
        for (int fn = 0; fn < 4; ++fn){
          int c = wn*64 + fn*16 + l15;
          float v = fmaxf(acc[fm][fn][j] + bias[c], 0.f);
          out8[((size_t)growo << 7) + c] = cvt1fp8(v);
        }
      }
    }
  }
}

// ---------------- conv GEMM fp8: BM=128, async dbuf, 6 steps BK=64, fp8 MFMA ------
// A chunks fp8 [node][128] (128B rows); Wt8 fp8 [chunk][col][k]. Per step stage
// 128x64B (8KB) with 16B-cell swizzle cell^((r>>1)&3) (<=2-way banks on b64 reads).
__global__ __launch_bounds__(256) void k_gemm8(
    const uint8_t* __restrict__ a0, const uint8_t* __restrict__ a1, const uint8_t* __restrict__ a2,
    const uint8_t* __restrict__ Wt8, const float* __restrict__ bias,
    bf16_t* __restrict__ out, uint8_t* __restrict__ out8, int M)
{
  __shared__ uint8_t lds[2][8192];
  const int tid = threadIdx.x;
  const int wave = tid >> 6, lane = tid & 63;
  const int wm = wave >> 1, wn = wave & 1;
  const int l15 = lane & 15, lq = lane >> 4;
  const int blockRow = blockIdx.x * 128;

  f32x4 acc[4][4];
  #pragma unroll
  for (int a = 0; a < 4; ++a)
    #pragma unroll
    for (int b = 0; b < 4; ++b) acc[a][b] = f32x4{0.f,0.f,0.f,0.f};

  // prologue: stage step 0 (chunk0, half0): 128 rows x 64B, 2 DMA/thread
  #pragma unroll
  for (int j = 0; j < 2; ++j){
    int flat = j*256 + tid;
    int r = flat >> 2, cell = flat & 3;
    int gr = blockRow + r; if (gr > M-1) gr = M-1;
    gload16(a0 + (size_t)gr*128 + ((cell ^ ((r>>1)&3)) << 4), &lds[0][flat << 4]);
  }

  #pragma unroll
  for (int s = 0; s < 6; ++s){
    if (s < 5){
      const int sn = s + 1;
      const uint8_t* srcn = (sn>>1) == 0 ? a0 : ((sn>>1) == 1 ? a1 : a2);
      #pragma unroll
      for (int j = 0; j < 2; ++j){
        int flat = j*256 + tid;
        int r = flat >> 2, cell = flat & 3;
        int gr = blockRow + r; if (gr > M-1) gr = M-1;
        gload16(srcn + (size_t)gr*128 + (sn&1)*64 + ((cell ^ ((r>>1)&3)) << 4),
                &lds[sn&1][flat << 4]);
      }
    }
    __syncthreads();
    const uint8_t* buf = lds[s&1];
    #pragma unroll
    for (int kk32 = 0; kk32 < 2; ++kk32){
      long af[4], bfr[4];
      #pragma unroll
      for (int fm = 0; fm < 4; ++fm){
        int r = wm*64 + fm*16 + l15;
        int cell = kk32*2 + (lq >> 1);
        af[fm] = *(const long*)(buf + r*64 + ((cell ^ ((r>>1)&3)) << 4) + (lq & 1)*8);
      }
      #pragma unroll
      for (int fn = 0; fn < 4; ++fn)
        bfr[fn] = *(const long*)(Wt8 + ((size_t)(((s>>1) << 7) + wn*64 + fn*16 + l15) << 7)
                                 + (s&1)*64 + kk32*32 + lq*8);
      #pragma unroll
      for (int fm = 0; fm < 4; ++fm)
        #pragma unroll
        for (int fn = 0; fn < 4; ++fn)
          acc[fm][fn] = __builtin_amdgcn_mfma_f32_16x16x32_fp8_fp8(af[fm], bfr[fn], acc[fm][fn], 0, 0, 0);
    }
    __syncthreads();
  }
  #pragma unroll
  for (int fm = 0; fm < 4; ++fm){
    #pragma unroll
    for (int j = 0; j < 4; ++j){
      int growo = blockRow + wm*64 + fm*16 + lq*4 + j;
      if (growo < M){
        #pragma unroll
        for (int fn = 0; fn < 4; ++fn){
          int c = wn*64 + fn*16 + l15;
          float v = fmaxf(acc[fm][fn][j] + bias[c], 0.f);
          if (out)  out[((size_t)growo << 7) + c] = (bf16_t)v;
          if (out8) out8[((size_t)growo << 7) + c] = cvt1fp8(v);
        }
      }
    }
  }
}

// ---------------- SpMM fp8 v3: fp8 in / fp8 out, 8-deep unroll --------------------
// out8 = fp8( alpha * sum_e (-wn)*V8[col]  - sub8 )
__global__ __launch_bounds__(256) void k_spmm8(
    const int* __restrict__ rowptr, const unsigned* __restrict__ ec,
    const uint8_t* __restrict__ V8, const uint8_t* __restrict__ sub8, float alpha,
    uint8_t* __restrict__ out8, int n)
{
  const int lane = threadIdx.x & 63;
  const int wave = threadIdx.x >> 6;
  const int g = lane >> 4;
  const int s = lane & 15;
  const int node = blockIdx.x*16 + wave*4 + g;
  if (node >= n) return;

  int e = rowptr[node];
  const int e1 = rowptr[node+1];
  const int fb = s << 3;

  float acc[8] = {0.f,0.f,0.f,0.f,0.f,0.f,0.f,0.f};

  for (; e + 8 <= e1; e += 8){
    unsigned u0 = ec[e],   u1 = ec[e+1], u2 = ec[e+2], u3 = ec[e+3];
    unsigned u4 = ec[e+4], u5 = ec[e+5], u6 = ec[e+6], u7 = ec[e+7];
    uint2 p0 = *(const uint2*)(V8 + (((size_t)(u0 & 0x1FFFF)) << 7) + fb);
    uint2 p1 = *(const uint2*)(V8 + (((size_t)(u1 & 0x1FFFF)) << 7) + fb);
    uint2 p2 = *(const uint2*)(V8 + (((size_t)(u2 & 0x1FFFF)) << 7) + fb);
    uint2 p3 = *(const uint2*)(V8 + (((size_t)(u3 & 0x1FFFF)) << 7) + fb);
    uint2 p4 = *(const uint2*)(V8 + (((size_t)(u4 & 0x1FFFF)) << 7) + fb);
    uint2 p5 = *(const uint2*)(V8 + (((size_t)(u5 & 0x1FFFF)) << 7) + fb);
    uint2 p6 = *(const uint2*)(V8 + (((size_t)(u6 & 0x1FFFF)) << 7) + fb);
    uint2 p7 = *(const uint2*)(V8 + (((size_t)(u7 & 0x1FFFF)) << 7) + fb);
    float w0 = edgeWneg(u0), w1 = edgeWneg(u1), w2 = edgeWneg(u2), w3 = edgeWneg(u3);
    float w4 = edgeWneg(u4), w5 = edgeWneg(u5), w6 = edgeWneg(u6), w7 = edgeWneg(u7);
    acc4_fp8(acc,   p0.x, w0); acc4_fp8(acc+4, p0.y, w0);
    acc4_fp8(acc,   p1.x, w1); acc4_fp8(acc+4, p1.y, w1);
    acc4_fp8(acc,   p2.x, w2); acc4_fp8(acc+4, p2.y, w2);
    acc4_fp8(acc,   p3.x, w3); acc4_fp8(acc+4, p3.y, w3);
    acc4_fp8(acc,   p4.x, w4); acc4_fp8(acc+4, p4.y, w4);
    acc4_fp8(acc,   p5.x, w5); acc4_fp8(acc+4, p5.y, w5);
    acc4_fp8(acc,   p6.x, w6); acc4_fp8(acc+4, p6.y, w6);
    acc4_fp8(acc,   p7.x, w7); acc4_fp8(acc+4, p7.y, w7);
  }
  for (; e + 4 <= e1; e += 4){
    unsigned u0 = ec[e], u1 = ec[e+1], u2 = ec[e+2], u3 = ec[e+3];
    uint2 p0 = *(const uint2*)(V8 + (((size_t)(u0 & 0x1FFFF)) << 7) + fb);
    uint2 p1 = *(const uint2*)(V8 + (((size_t)(u1 & 0x1FFFF)) << 7) + fb);
    uint2 p2 = *(const uint2*)(V8 + (((size_t)(u2 & 0x1FFFF)) << 7) + fb);
    uint2 p3 = *(const uint2*)(V8 + (((size_t)(u3 & 0x1FFFF)) << 7) + fb);
    float w0 = edgeWneg(u0), w1 = edgeWneg(u1), w2 = edgeWneg(u2), w3 = edgeWneg(u3);
    acc4_fp8(acc,   p0.x, w0); acc4_fp8(acc+4, p0.y, w0);
    acc4_fp8(acc,   p1.x, w1); acc4_fp8(acc+4, p1.y, w1);
    acc4_fp8(acc,   p2.x, w2); acc4_fp8(acc+4, p2.y, w2);
    acc4_fp8(acc,   p3.x, w3); acc4_fp8(acc+4, p3.y, w3);
  }
  for (; e < e1; ++e){
    unsigned u = ec[e];
    uint2 p = *(const uint2*)(V8 + (((size_t)(u & 0x1FFFF)) << 7) + fb);
    float w = edgeWneg(u);
    acc4_fp8(acc, p.x, w); acc4_fp8(acc+4, p.y, w);
  }

  float r[8];
  #pragma unroll
  for (int i = 0; i < 8; ++i) r[i] = alpha*acc[i];
  if (sub8){
    uint2 sv = *(const uint2*)(sub8 + (((size_t)node) << 7) + fb);
    float sd[8];
    dec4_fp8(sd,     sv.x);
    dec4_fp8(sd + 4, sv.y);
    #pragma unroll
    for (int i = 0; i < 8; ++i) r[i] -= sd[i];
  }
  uint2 o8;
  o8.x = cvt2fp8(r[0], r[1]) | (cvt2fp8(r[2], r[3]) << 16);
  o8.y = cvt2fp8(r[4], r[5]) | (cvt2fp8(r[6], r[7]) << 16);
  *(uint2*)(out8 + (((size_t)node) << 7) + fb) = o8;
}

// ---------------- head ----------------
__global__ __launch_bounds__(256) void k_head(
    const bf16_t* __restrict__ h, const float* __restrict__ W2, const float* __restrict__ b2,
    float* __restrict__ out, int n)
{
  int node = blockIdx.x*4 + (threadIdx.x >> 6);
  if (node >= n) return;
  int lane = threadIdx.x & 63;
  unsigned int p = *(const unsigned int*)(h + ((size_t)node << 7) + lane*2);
  float h0 = bflo(p), h1 = bfhi(p);
  floatv4 w = *(const floatv4*)(W2 + lane*4);
  float p0 = h0*w[0] + h1*w[2];
  float p1 = h0*w[1] + h1*w[3];
  #pragma unroll
  for (int s = 32; s > 0; s >>= 1){
    p0 += __shfl_xor(p0, s, 64);
    p1 += __shfl_xor(p1, s, 64);
  }
  if (lane == 0){
    float l0 = p0 + b2[0], l1 = p1 + b2[1];
    float m = fmaxf(l0, l1);
    float e0 = __expf(l0 - m), e1 = __expf(l1 - m);
    float inv = 1.f / (e0 + e1);
    out[(size_t)node*2]     = e0 * inv;
    out[(size_t)node*2 + 1] = e1 * inv;
  }
}

// ---------------- launch ----------------

extern "C" void kernel_launch(void* const* d_in, const int* in_sizes, int n_in,
                              void* d_out, int out_size, void* d_ws, size_t ws_size,
                              hipStream_t stream)
{
  const float* x   = (const float*)d_in[0];
  const int*   ei  = (const int*)d_in[1];
  const float* ew  = (const float*)d_in[2];
  const float* W1  = (const float*)d_in[3];
  const float* b1  = (const float*)d_in[4];
  const float* c1W = (const float*)d_in[5];
  const float* c1b = (const float*)d_in[6];
  const float* c2W = (const float*)d_in[7];
  const float* c2b = (const float*)d_in[8];
  const float* W2  = (const float*)d_in[9];
  const float* b2  = (const float*)d_in[10];
  float* out = (float*)d_out;

  const int n = NN, e = NE;
  const int* row = ei;
  const int* col = ei + e;

  char* ws = (char*)d_ws;
  size_t off = 0;
  auto carve = [&](size_t bytes)->void*{
    void* p = ws + off;
    off += (bytes + 255) & ~(size_t)255;
    return p;
  };
  bf16_t*  A   = (bf16_t*)carve((size_t)n*128*2);    // h2 (bf16, for head)
  uint8_t* q8a = (uint8_t*)carve((size_t)n*128);     // h0 fp8
  uint8_t* B8  = (uint8_t*)carve((size_t)n*128);     // Tx1 fp8
  uint8_t* C8  = (uint8_t*)carve((size_t)n*128);     // Tx2 fp8
  uint8_t* D8  = (uint8_t*)carve((size_t)n*128);     // h1 fp8 (aliases temp)
  float*  dinv = (float*)carve((size_t)n*4);
  int*    rowptr = (int*)carve((size_t)(n+1)*4);
  unsigned* ec = (unsigned*)carve((size_t)e*4);
  int*    bincnt = (int*)carve((size_t)NBIN*4);
  int*    binptr = (int*)carve((size_t)(NBIN+1)*4);
  int*    blockbase = (int*)carve((size_t)NBB*NBIN*4);   // 1.22MB
  bf16_t*  Wt1  = (bf16_t*)carve(2*128*128*2);
  uint8_t* W8c1 = (uint8_t*)carve(3*128*128);
  uint8_t* W8c2 = (uint8_t*)carve(3*128*128);
  // temp edge buffer (12.8MB) aliases D8: temp lives [binB,binC]; D8 first
  // written by conv1's k_gemm8 (after binC).
  int2* temp = (int2*)D8;
  (void)ws_size; (void)in_sizes; (void)n_in; (void)out_size;

  const int NB_W = (n + 3)/4;       // 25000
  const int NB_S = (n + 15)/16;     // 6250

  hipMemsetAsync(bincnt, 0, (size_t)NBIN*4, stream);
  k_binA<<<NBB,256,0,stream>>>(row, bincnt, blockbase);
  k_scanbins<<<1,256,0,stream>>>(bincnt, binptr, rowptr);
  k_binB<<<NBB,256,0,stream>>>(row, col, ew, binptr, blockbase, temp);
  k_binC<<<NBIN,256,0,stream>>>(temp, binptr, ec, rowptr, dinv, n);
  k_norm<<<NB_W,256,0,stream>>>(ec, rowptr, dinv, n);
  k_transw_all<<<(8*16384+255)/256,256,0,stream>>>(W1, c1W, c2W, Wt1, W8c1, W8c2);

  // h0 = relu(x @ W1 + b1) -> q8a (fp8 only)
  k_gemm1<<<NB_G,256,0,stream>>>(x, Wt1, b1, q8a, n);
  // conv1: Tx1 = Lx(h0) -> B8 ; Tx2 = 2*Lx(Tx1) - h0 -> C8
  k_spmm8<<<NB_S,256,0,stream>>>(rowptr, ec, q8a, nullptr, 1.f, B8, n);
  k_spmm8<<<NB_S,256,0,stream>>>(rowptr, ec, B8, q8a, 2.f, C8, n);
  // h1 = relu([h0|Tx1|Tx2] @ Wc1 + b) -> D8 (fp8)
  k_gemm8<<<NB_G,256,0,stream>>>(q8a, B8, C8, W8c1, c1b, nullptr, D8, n);
  // conv2
  k_spmm8<<<NB_S,256,0,stream>>>(rowptr, ec, D8, nullptr, 1.f, B8, n);
  k_spmm8<<<NB_S,256,0,stream>>>(rowptr, ec, B8, D8, 2.f, C8, n);
  // h2 = relu([h1|Tx1|Tx2] @ Wc2 + b) -> A (bf16, for head)
  k_gemm8<<<NB_G,256,0,stream>>>(D8, B8, C8, W8c2, c2b, A, nullptr, n);
  // head
  k_head<<<NB_W,256,0,stream>>>(A, W2, b2, out, n);
}

// Round 18
// 352.103 us; speedup vs baseline: 1.2344x; 1.0216x over previous
//
#include <hip/hip_runtime.h>
#include <hip/hip_bf16.h>
#include <stdint.h>

typedef __bf16 bf16_t;
typedef __bf16 bf16x8 __attribute__((ext_vector_type(8)));
typedef float f32x4 __attribute__((ext_vector_type(4)));
typedef float f32x2 __attribute__((ext_vector_type(2)));
typedef float floatv4 __attribute__((ext_vector_type(4)));

// async 16B global->LDS DMA
static __device__ __forceinline__ void gload16(const void* g, void* l){
  __builtin_amdgcn_global_load_lds((const __attribute__((address_space(1))) void*)g,
                                   (__attribute__((address_space(3))) void*)l, 16, 0, 0);
}
// fp8 e4m3 (OCP) HW conversions
static __device__ __forceinline__ void acc4_fp8(float* a, unsigned w, float wt){
  f32x2 lo, hi;
  unsigned wh = w >> 16;
  asm("v_cvt_pk_f32_fp8 %0, %1" : "=v"(lo) : "v"(w));
  asm("v_cvt_pk_f32_fp8 %0, %1" : "=v"(hi) : "v"(wh));
  a[0] += wt*lo[0]; a[1] += wt*lo[1]; a[2] += wt*hi[0]; a[3] += wt*hi[1];
}
static __device__ __forceinline__ void dec4_fp8(float* d, unsigned w){
  f32x2 lo, hi;
  unsigned wh = w >> 16;
  asm("v_cvt_pk_f32_fp8 %0, %1" : "=v"(lo) : "v"(w));
  asm("v_cvt_pk_f32_fp8 %0, %1" : "=v"(hi) : "v"(wh));
  d[0] = lo[0]; d[1] = lo[1]; d[2] = hi[0]; d[3] = hi[1];
}
static __device__ __forceinline__ unsigned cvt2fp8(float a, float b){
  unsigned r;
  asm("v_cvt_pk_fp8_f32 %0, %1, %2" : "=v"(r) : "v"(a), "v"(b));
  return r & 0xffffu;
}
static __device__ __forceinline__ uint8_t cvt1fp8(float a){
  unsigned r;
  asm("v_cvt_pk_fp8_f32 %0, %1, %1" : "=v"(r) : "v"(a));
  return (uint8_t)r;
}
// packed edge: bits[16:0]=col, bits[31:17]=weight f32 bits[30:16] (sign implicit)
static __device__ __forceinline__ unsigned packEdge(int col, float w_pos){
  unsigned b = __float_as_uint(w_pos) + 0x8000u;
  return ((b >> 16) << 17) | (unsigned)col;
}
static __device__ __forceinline__ float edgeWpos(unsigned u){
  return __uint_as_float((u >> 17) << 16);
}
static __device__ __forceinline__ float edgeWneg(unsigned u){
  return __uint_as_float(0x80000000u | ((u >> 17) << 16));
}

constexpr int NN = 100000;
constexpr int NE = 1600000;
constexpr int NB_G  = (NN + 127)/128;    // 782
constexpr int NBIN = (NN + 127)/128;     // 782
constexpr int EPB  = 4096;
constexpr int NBB  = (NE + EPB - 1)/EPB; // 391
constexpr int MAXBE = 3072;
constexpr int NB_TW8 = (2*3*128*128)/256; // 384 transw8 blocks

// ---------------- CSR build (binA fused into gemm1) ----------------
__global__ __launch_bounds__(256) void k_scanbins(const int* __restrict__ bincnt,
                                                  int* __restrict__ binptr,
                                                  int* __restrict__ rowptr){
  __shared__ int s[256];
  int t = threadIdx.x;
  int b0 = t*4;
  int c[4]; int tot = 0;
  #pragma unroll
  for (int j = 0; j < 4; ++j){
    int b = b0 + j;
    c[j] = (b < NBIN) ? bincnt[b] : 0;
    tot += c[j];
  }
  s[t] = tot;
  __syncthreads();
  for (int off = 1; off < 256; off <<= 1){
    int v = (t >= off) ? s[t - off] : 0;
    __syncthreads();
    s[t] += v;
    __syncthreads();
  }
  int ex = s[t] - tot;
  #pragma unroll
  for (int j = 0; j < 4; ++j){
    int b = b0 + j;
    if (b < NBIN) binptr[b] = ex;
    ex += c[j];
  }
  if (t == 255){ binptr[NBIN] = ex; rowptr[NN] = ex; }
}

__global__ __launch_bounds__(256) void k_binB(const int* __restrict__ row,
                                              const int* __restrict__ col,
                                              const float* __restrict__ w,
                                              const int* __restrict__ binptr,
                                              const int* __restrict__ blockbase,
                                              int2* __restrict__ temp){
  __shared__ int h[NBIN];
  for (int b = threadIdx.x; b < NBIN; b += 256) h[b] = 0;
  __syncthreads();
  int base = blockIdx.x * EPB;
  for (int k = 0; k < EPB; k += 256){
    int i = base + k + threadIdx.x;
    if (i < NE){
      int r = row[i];
      int b = r >> 7;
      int rank = atomicAdd(&h[b], 1);
      int pos = binptr[b] + blockbase[blockIdx.x * NBIN + b] + rank;
      temp[pos] = make_int2(col[i] | ((r & 127) << 17), __float_as_int(w[i]));
    }
  }
}

__global__ __launch_bounds__(256) void k_binC(const int2* __restrict__ temp,
                                              const int* __restrict__ binptr,
                                              unsigned* __restrict__ ec,
                                              int* __restrict__ rowptr,
                                              float* __restrict__ dinv, int n){
  __shared__ int2 sbuf[MAXBE];
  __shared__ int cnt[128];
  __shared__ int scan[128];
  __shared__ int estart[128];
  const int b = blockIdx.x;
  const int e0 = binptr[b];
  int nb = binptr[b+1] - e0; if (nb > MAXBE) nb = MAXBE;
  const int t = threadIdx.x;
  if (t < 128) cnt[t] = 0;
  __syncthreads();
  for (int k = t; k < nb; k += 256)
    atomicAdd(&cnt[(temp[e0+k].x >> 17) & 127], 1);
  __syncthreads();
  if (t < 128) scan[t] = cnt[t];
  __syncthreads();
  for (int off = 1; off < 128; off <<= 1){
    int v = (t < 128 && t >= off) ? scan[t - off] : 0;
    __syncthreads();
    if (t < 128) scan[t] += v;
    __syncthreads();
  }
  if (t < 128){ estart[t] = scan[t] - cnt[t]; cnt[t] = 0; }
  __syncthreads();
  for (int k = t; k < nb; k += 256){
    int2 q = temp[e0+k];
    int rl = (q.x >> 17) & 127;
    int rank = atomicAdd(&cnt[rl], 1);
    sbuf[estart[rl] + rank] = q;
  }
  __syncthreads();
  for (int k = t; k < nb; k += 256){
    int2 q = sbuf[k];
    ec[e0 + k] = packEdge(q.x & 0x1FFFF, __int_as_float(q.y));
  }
  if (t < 128){
    int gid = b*128 + t;
    if (gid < n){
      rowptr[gid] = e0 + estart[t];
      float s = 0.f;
      int s0 = estart[t], c = cnt[t];
      for (int j = 0; j < c; ++j) s += __int_as_float(sbuf[s0+j].y);
      dinv[gid] = (s > 0.f) ? rsqrtf(s) : 0.f;
    }
  }
}

__global__ __launch_bounds__(256) void k_norm(unsigned* __restrict__ ec,
                                              const int* __restrict__ rowptr,
                                              const float* __restrict__ dinv, int n){
  int node = blockIdx.x*4 + (threadIdx.x >> 6);
  if (node >= n) return;
  int lane = threadIdx.x & 63;
  int e0 = rowptr[node], e1 = rowptr[node+1];
  float dr = dinv[node];
  for (int e = e0 + lane; e < e1; e += 64){
    unsigned u = ec[e];
    int c = u & 0x1FFFF;
    float wn = dr * edgeWpos(u) * dinv[c];
    ec[e] = packEdge(c, wn);
  }
}

// Wt1 bf16 [chunk][col][k] — needed by gemm1, so built in a small pre-kernel
__global__ void k_transw1(const float* __restrict__ W1, bf16_t* __restrict__ Wt1){
  int idx = blockIdx.x*256 + threadIdx.x;   // 32768
  int c = idx >> 14, r = (idx >> 7) & 127, j = idx & 127;
  Wt1[(c << 14) + (j << 7) + r] = (bf16_t)W1[idx];
}

// ---------------- FUSED: gemm1 (782) + binA (391) + conv-weight fp8 pack (384) ----
// gemm1 is latency-stalled (VALUBusy 6%) — binA's histogram and the W8 packs ride
// its idle pipes instead of costing serial dispatches.
__global__ __launch_bounds__(256) void k_gemm1_fused(
    const float* __restrict__ x, const bf16_t* __restrict__ Wt, const float* __restrict__ bias,
    uint8_t* __restrict__ out8, int M,
    const int* __restrict__ row, int* __restrict__ bincnt, int* __restrict__ blockbase,
    const float* __restrict__ c1W, const float* __restrict__ c2W,
    uint8_t* __restrict__ W8c1, uint8_t* __restrict__ W8c2)
{
  __shared__ uint8_t lds[2][16384];
  __shared__ int hA[NBIN];
  const int tid = threadIdx.x;

  if (blockIdx.x >= NB_G + NBB){                 // --- conv-weight fp8 pack ---
    int base = (blockIdx.x - NB_G - NBB)*256 + tid;   // 0..98303
    int m = base / 49152;
    int local = base - m*49152;
    const float* src = m ? c2W : c1W;
    uint8_t* dst = m ? W8c2 : W8c1;
    int c = local >> 14, r = (local >> 7) & 127, j = local & 127;
    dst[(c << 14) + (j << 7) + r] = cvt1fp8(src[local]);
    return;
  }
  if (blockIdx.x >= NB_G){                       // --- binA histogram ---
    int bb = blockIdx.x - NB_G;
    for (int b = tid; b < NBIN; b += 256) hA[b] = 0;
    __syncthreads();
    int base = bb * EPB;
    for (int k = 0; k < EPB; k += 256){
      int i = base + k + tid;
      if (i < NE) atomicAdd(&hA[row[i] >> 7], 1);
    }
    __syncthreads();
    for (int b = tid; b < NBIN; b += 256){
      int c = hA[b];
      blockbase[bb * NBIN + b] = c ? atomicAdd(&bincnt[b], c) : 0;
    }
    return;
  }

  // --- gemm1: BM=128, async dbuf, fp8-only output (r17-proven) ---
  const int wave = tid >> 6, lane = tid & 63;
  const int wm = wave >> 1, wn = wave & 1;
  const int l15 = lane & 15, lq = lane >> 4;
  const int blockRow = blockIdx.x * 128;
  const int strow = tid >> 3;
  const int scell = tid & 7;

  f32x4 acc[4][4];
  #pragma unroll
  for (int a = 0; a < 4; ++a)
    #pragma unroll
    for (int b = 0; b < 4; ++b) acc[a][b] = f32x4{0.f,0.f,0.f,0.f};

  #pragma unroll
  for (int j = 0; j < 4; ++j){
    int r = j*32 + strow;
    int gr = blockRow + r; if (gr > M-1) gr = M-1;
    gload16((const char*)x + (size_t)gr*1024 + ((scell ^ (r&7)) << 4),
            &lds[0][j*4096 + tid*16]);
  }

  #pragma unroll
  for (int s = 0; s < 8; ++s){
    if (s < 7){
      #pragma unroll
      for (int j = 0; j < 4; ++j){
        int r = j*32 + strow;
        int gr = blockRow + r; if (gr > M-1) gr = M-1;
        gload16((const char*)x + (size_t)gr*1024 + (s+1)*128 + ((scell ^ (r&7)) << 4),
                &lds[(s+1)&1][j*4096 + tid*16]);
      }
    }
    __syncthreads();
    const uint8_t* buf = lds[s&1];
    bf16x8 af[4], bfr[4];
    #pragma unroll
    for (int fm = 0; fm < 4; ++fm){
      int r = wm*64 + fm*16 + l15;
      floatv4 v0 = *(const floatv4*)(buf + r*128 + (((lq*2    ) ^ (r&7)) << 4));
      floatv4 v1 = *(const floatv4*)(buf + r*128 + (((lq*2 + 1) ^ (r&7)) << 4));
      bf16x8 t;
      t[0]=(bf16_t)v0[0]; t[1]=(bf16_t)v0[1]; t[2]=(bf16_t)v0[2]; t[3]=(bf16_t)v0[3];
      t[4]=(bf16_t)v1[0]; t[5]=(bf16_t)v1[1]; t[6]=(bf16_t)v1[2]; t[7]=(bf16_t)v1[3];
      af[fm] = t;
    }
    #pragma unroll
    for (int fn = 0; fn < 4; ++fn)
      bfr[fn] = *(const bf16x8*)(Wt + ((size_t)(((s>>2) << 7) + wn*64 + fn*16 + l15) << 7) + (s&3)*32 + lq*8);
    #pragma unroll
    for (int fm = 0; fm < 4; ++fm)
      #pragma unroll
      for (int fn = 0; fn < 4; ++fn)
        acc[fm][fn] = __builtin_amdgcn_mfma_f32_16x16x32_bf16(af[fm], bfr[fn], acc[fm][fn], 0, 0, 0);
    __syncthreads();
  }
  #pragma unroll
  for (int fm = 0; fm < 4; ++fm){
    #pragma unroll
    for (int j = 0; j < 4; ++j){
      int growo = blockRow + wm*64 + fm*16 + lq*4 + j;
      if (growo < M){
        #pragma unroll
        for (int fn = 0; fn < 4; ++fn){
          int c = wn*64 + fn*16 + l15;
          float v = fmaxf(acc[fm][fn][j] + bias[c], 0.f);
          out8[((size_t)growo << 7) + c] = cvt1fp8(v);
        }
      }
    }
  }
}

// ---------------- conv GEMM fp8 (+ optional fused head) ----------------
// If outh != null: per-thread partial dot with W2, LDS-atomic reduce to
// logits[128][2], softmax + float2 store (replaces h2 write + k_head).
__global__ __launch_bounds__(256) void k_gemm8(
    const uint8_t* __restrict__ a0, const uint8_t* __restrict__ a1, const uint8_t* __restrict__ a2,
    const uint8_t* __restrict__ Wt8, const float* __restrict__ bias,
    uint8_t* __restrict__ out8,
    const float* __restrict__ W2h, const float* __restrict__ b2h, float* __restrict__ outh,
    int M)
{
  __shared__ uint8_t lds[2][8192];
  __shared__ float logits[128][2];
  const int tid = threadIdx.x;
  const int wave = tid >> 6, lane = tid & 63;
  const int wm = wave >> 1, wn = wave & 1;
  const int l15 = lane & 15, lq = lane >> 4;
  const int blockRow = blockIdx.x * 128;

  f32x4 acc[4][4];
  #pragma unroll
  for (int a = 0; a < 4; ++a)
    #pragma unroll
    for (int b = 0; b < 4; ++b) acc[a][b] = f32x4{0.f,0.f,0.f,0.f};

  #pragma unroll
  for (int j = 0; j < 2; ++j){
    int flat = j*256 + tid;
    int r = flat >> 2, cell = flat & 3;
    int gr = blockRow + r; if (gr > M-1) gr = M-1;
    gload16(a0 + (size_t)gr*128 + ((cell ^ ((r>>1)&3)) << 4), &lds[0][flat << 4]);
  }

  #pragma unroll
  for (int s = 0; s < 6; ++s){
    if (s < 5){
      const int sn = s + 1;
      const uint8_t* srcn = (sn>>1) == 0 ? a0 : ((sn>>1) == 1 ? a1 : a2);
      #pragma unroll
      for (int j = 0; j < 2; ++j){
        int flat = j*256 + tid;
        int r = flat >> 2, cell = flat & 3;
        int gr = blockRow + r; if (gr > M-1) gr = M-1;
        gload16(srcn + (size_t)gr*128 + (sn&1)*64 + ((cell ^ ((r>>1)&3)) << 4),
                &lds[sn&1][flat << 4]);
      }
    }
    __syncthreads();
    const uint8_t* buf = lds[s&1];
    #pragma unroll
    for (int kk32 = 0; kk32 < 2; ++kk32){
      long af[4], bfr[4];
      #pragma unroll
      for (int fm = 0; fm < 4; ++fm){
        int r = wm*64 + fm*16 + l15;
        int cell = kk32*2 + (lq >> 1);
        af[fm] = *(const long*)(buf + r*64 + ((cell ^ ((r>>1)&3)) << 4) + (lq & 1)*8);
      }
      #pragma unroll
      for (int fn = 0; fn < 4; ++fn)
        bfr[fn] = *(const long*)(Wt8 + ((size_t)(((s>>1) << 7) + wn*64 + fn*16 + l15) << 7)
                                 + (s&1)*64 + kk32*32 + lq*8);
      #pragma unroll
      for (int fm = 0; fm < 4; ++fm)
        #pragma unroll
        for (int fn = 0; fn < 4; ++fn)
          acc[fm][fn] = __builtin_amdgcn_mfma_f32_16x16x32_fp8_fp8(af[fm], bfr[fn], acc[fm][fn], 0, 0, 0);
    }
    __syncthreads();
  }

  if (outh){
    // fused head: logits = relu(acc+bias) @ W2 ; softmax ; write float2
    ((float*)logits)[tid] = 0.f;     // 256 = 128*2
    __syncthreads();
    float w2l[8];
    #pragma unroll
    for (int fn = 0; fn < 4; ++fn){
      int c = wn*64 + fn*16 + l15;
      w2l[fn*2]   = W2h[c*2];
      w2l[fn*2+1] = W2h[c*2+1];
    }
    #pragma unroll
    for (int fm = 0; fm < 4; ++fm){
      #pragma unroll
      for (int j = 0; j < 4; ++j){
        int r = wm*64 + fm*16 + lq*4 + j;
        int growo = blockRow + r;
        float p0 = 0.f, p1 = 0.f;
        #pragma unroll
        for (int fn = 0; fn < 4; ++fn){
          float v = fmaxf(acc[fm][fn][j] + bias[wn*64 + fn*16 + l15], 0.f);
          p0 += v*w2l[fn*2];
          p1 += v*w2l[fn*2+1];
        }
        if (growo < M){
          atomicAdd(&logits[r][0], p0);
          atomicAdd(&logits[r][1], p1);
        }
      }
    }
    __syncthreads();
    if (tid < 128){
      int node = blockRow + tid;
      if (node < M){
        float l0 = logits[tid][0] + b2h[0];
        float l1 = logits[tid][1] + b2h[1];
        float mx = fmaxf(l0, l1);
        float e0 = __expf(l0 - mx), e1 = __expf(l1 - mx);
        float inv = 1.f / (e0 + e1);
        *(float2*)(outh + (size_t)node*2) = make_float2(e0*inv, e1*inv);
      }
    }
  } else {
    #pragma unroll
    for (int fm = 0; fm < 4; ++fm){
      #pragma unroll
      for (int j = 0; j < 4; ++j){
        int growo = blockRow + wm*64 + fm*16 + lq*4 + j;
        if (growo < M){
          #pragma unroll
          for (int fn = 0; fn < 4; ++fn){
            int c = wn*64 + fn*16 + l15;
            float v = fmaxf(acc[fm][fn][j] + bias[c], 0.f);
            out8[((size_t)growo << 7) + c] = cvt1fp8(v);
          }
        }
      }
    }
  }
}

// ---------------- SpMM fp8: fp8 in / fp8 out, 8-deep unroll (r17-proven) ----------
__global__ __launch_bounds__(256) void k_spmm8(
    const int* __restrict__ rowptr, const unsigned* __restrict__ ec,
    const uint8_t* __restrict__ V8, const uint8_t* __restrict__ sub8, float alpha,
    uint8_t* __restrict__ out8, int n)
{
  const int lane = threadIdx.x & 63;
  const int wave = threadIdx.x >> 6;
  const int g = lane >> 4;
  const int s = lane & 15;
  const int node = blockIdx.x*16 + wave*4 + g;
  if (node >= n) return;

  int e = rowptr[node];
  const int e1 = rowptr[node+1];
  const int fb = s << 3;

  float acc[8] = {0.f,0.f,0.f,0.f,0.f,0.f,0.f,0.f};

  for (; e + 8 <= e1; e += 8){
    unsigned u0 = ec[e],   u1 = ec[e+1], u2 = ec[e+2], u3 = ec[e+3];
    unsigned u4 = ec[e+4], u5 = ec[e+5], u6 = ec[e+6], u7 = ec[e+7];
    uint2 p0 = *(const uint2*)(V8 + (((size_t)(u0 & 0x1FFFF)) << 7) + fb);
    uint2 p1 = *(const uint2*)(V8 + (((size_t)(u1 & 0x1FFFF)) << 7) + fb);
    uint2 p2 = *(const uint2*)(V8 + (((size_t)(u2 & 0x1FFFF)) << 7) + fb);
    uint2 p3 = *(const uint2*)(V8 + (((size_t)(u3 & 0x1FFFF)) << 7) + fb);
    uint2 p4 = *(const uint2*)(V8 + (((size_t)(u4 & 0x1FFFF)) << 7) + fb);
    uint2 p5 = *(const uint2*)(V8 + (((size_t)(u5 & 0x1FFFF)) << 7) + fb);
    uint2 p6 = *(const uint2*)(V8 + (((size_t)(u6 & 0x1FFFF)) << 7) + fb);
    uint2 p7 = *(const uint2*)(V8 + (((size_t)(u7 & 0x1FFFF)) << 7) + fb);
    float w0 = edgeWneg(u0), w1 = edgeWneg(u1), w2 = edgeWneg(u2), w3 = edgeWneg(u3);
    float w4 = edgeWneg(u4), w5 = edgeWneg(u5), w6 = edgeWneg(u6), w7 = edgeWneg(u7);
    acc4_fp8(acc,   p0.x, w0); acc4_fp8(acc+4, p0.y, w0);
    acc4_fp8(acc,   p1.x, w1); acc4_fp8(acc+4, p1.y, w1);
    acc4_fp8(acc,   p2.x, w2); acc4_fp8(acc+4, p2.y, w2);
    acc4_fp8(acc,   p3.x, w3); acc4_fp8(acc+4, p3.y, w3);
    acc4_fp8(acc,   p4.x, w4); acc4_fp8(acc+4, p4.y, w4);
    acc4_fp8(acc,   p5.x, w5); acc4_fp8(acc+4, p5.y, w5);
    acc4_fp8(acc,   p6.x, w6); acc4_fp8(acc+4, p6.y, w6);
    acc4_fp8(acc,   p7.x, w7); acc4_fp8(acc+4, p7.y, w7);
  }
  for (; e + 4 <= e1; e += 4){
    unsigned u0 = ec[e], u1 = ec[e+1], u2 = ec[e+2], u3 = ec[e+3];
    uint2 p0 = *(const uint2*)(V8 + (((size_t)(u0 & 0x1FFFF)) << 7) + fb);
    uint2 p1 = *(const uint2*)(V8 + (((size_t)(u1 & 0x1FFFF)) << 7) + fb);
    uint2 p2 = *(const uint2*)(V8 + (((size_t)(u2 & 0x1FFFF)) << 7) + fb);
    uint2 p3 = *(const uint2*)(V8 + (((size_t)(u3 & 0x1FFFF)) << 7) + fb);
    float w0 = edgeWneg(u0), w1 = edgeWneg(u1), w2 = edgeWneg(u2), w3 = edgeWneg(u3);
    acc4_fp8(acc,   p0.x, w0); acc4_fp8(acc+4, p0.y, w0);
    acc4_fp8(acc,   p1.x, w1); acc4_fp8(acc+4, p1.y, w1);
    acc4_fp8(acc,   p2.x, w2); acc4_fp8(acc+4, p2.y, w2);
    acc4_fp8(acc,   p3.x, w3); acc4_fp8(acc+4, p3.y, w3);
  }
  for (; e < e1; ++e){
    unsigned u = ec[e];
    uint2 p = *(const uint2*)(V8 + (((size_t)(u & 0x1FFFF)) << 7) + fb);
    float w = edgeWneg(u);
    acc4_fp8(acc, p.x, w); acc4_fp8(acc+4, p.y, w);
  }

  float r[8];
  #pragma unroll
  for (int i = 0; i < 8; ++i) r[i] = alpha*acc[i];
  if (sub8){
    uint2 sv = *(const uint2*)(sub8 + (((size_t)node) << 7) + fb);
    float sd[8];
    dec4_fp8(sd,     sv.x);
    dec4_fp8(sd + 4, sv.y);
    #pragma unroll
    for (int i = 0; i < 8; ++i) r[i] -= sd[i];
  }
  uint2 o8;
  o8.x = cvt2fp8(r[0], r[1]) | (cvt2fp8(r[2], r[3]) << 16);
  o8.y = cvt2fp8(r[4], r[5]) | (cvt2fp8(r[6], r[7]) << 16);
  *(uint2*)(out8 + (((size_t)node) << 7) + fb) = o8;
}

// ---------------- launch ----------------

extern "C" void kernel_launch(void* const* d_in, const int* in_sizes, int n_in,
                              void* d_out, int out_size, void* d_ws, size_t ws_size,
                              hipStream_t stream)
{
  const float* x   = (const float*)d_in[0];
  const int*   ei  = (const int*)d_in[1];
  const float* ew  = (const float*)d_in[2];
  const float* W1  = (const float*)d_in[3];
  const float* b1  = (const float*)d_in[4];
  const float* c1W = (const float*)d_in[5];
  const float* c1b = (const float*)d_in[6];
  const float* c2W = (const float*)d_in[7];
  const float* c2b = (const float*)d_in[8];
  const float* W2  = (const float*)d_in[9];
  const float* b2  = (const float*)d_in[10];
  float* out = (float*)d_out;

  const int n = NN, e = NE;
  const int* row = ei;
  const int* col = ei + e;

  char* ws = (char*)d_ws;
  size_t off = 0;
  auto carve = [&](size_t bytes)->void*{
    void* p = ws + off;
    off += (bytes + 255) & ~(size_t)255;
    return p;
  };
  uint8_t* q8a = (uint8_t*)carve((size_t)n*128);     // h0 fp8
  uint8_t* B8  = (uint8_t*)carve((size_t)n*128);     // Tx1 fp8
  uint8_t* C8  = (uint8_t*)carve((size_t)n*128);     // Tx2 fp8
  uint8_t* D8  = (uint8_t*)carve((size_t)n*128);     // h1 fp8 (aliases temp)
  float*  dinv = (float*)carve((size_t)n*4);
  int*    rowptr = (int*)carve((size_t)(n+1)*4);
  unsigned* ec = (unsigned*)carve((size_t)e*4);
  int*    bincnt = (int*)carve((size_t)NBIN*4);
  int*    binptr = (int*)carve((size_t)(NBIN+1)*4);
  int*    blockbase = (int*)carve((size_t)NBB*NBIN*4);   // 1.22MB
  bf16_t*  Wt1  = (bf16_t*)carve(2*128*128*2);
  uint8_t* W8c1 = (uint8_t*)carve(3*128*128);
  uint8_t* W8c2 = (uint8_t*)carve(3*128*128);
  // temp edge buffer (12.8MB) aliases D8: temp lives [binB,binC]; D8 first
  // written by conv1's k_gemm8 (after binC).
  int2* temp = (int2*)D8;
  (void)ws_size; (void)in_sizes; (void)n_in; (void)out_size;

  const int NB_W = (n + 3)/4;       // 25000
  const int NB_S = (n + 15)/16;     // 6250

  hipMemsetAsync(bincnt, 0, (size_t)NBIN*4, stream);
  k_transw1<<<128,256,0,stream>>>(W1, Wt1);
  // fused: h0 = relu(x@W1+b1) -> q8a  AND  binA histogram  AND  conv-weight fp8 pack
  k_gemm1_fused<<<NB_G + NBB + NB_TW8,256,0,stream>>>(
      x, Wt1, b1, q8a, n, row, bincnt, blockbase, c1W, c2W, W8c1, W8c2);
  k_scanbins<<<1,256,0,stream>>>(bincnt, binptr, rowptr);
  k_binB<<<NBB,256,0,stream>>>(row, col, ew, binptr, blockbase, temp);
  k_binC<<<NBIN,256,0,stream>>>(temp, binptr, ec, rowptr, dinv, n);
  k_norm<<<NB_W,256,0,stream>>>(ec, rowptr, dinv, n);

  // conv1: Tx1 = Lx(h0) -> B8 ; Tx2 = 2*Lx(Tx1) - h0 -> C8
  k_spmm8<<<NB_S,256,0,stream>>>(rowptr, ec, q8a, nullptr, 1.f, B8, n);
  k_spmm8<<<NB_S,256,0,stream>>>(rowptr, ec, B8, q8a, 2.f, C8, n);
  // h1 = relu([h0|Tx1|Tx2] @ Wc1 + b) -> D8 (fp8)
  k_gemm8<<<NB_G,256,0,stream>>>(q8a, B8, C8, W8c1, c1b, D8, nullptr, nullptr, nullptr, n);
  // conv2
  k_spmm8<<<NB_S,256,0,stream>>>(rowptr, ec, D8, nullptr, 1.f, B8, n);
  k_spmm8<<<NB_S,256,0,stream>>>(rowptr, ec, B8, D8, 2.f, C8, n);
  // h2 GEMM + fused head -> out (softmax probabilities)
  k_gemm8<<<NB_G,256,0,stream>>>(D8, B8, C8, W8c2, c2b, nullptr, W2, b2, out, n);
}

// Round 19
// 305.561 us; speedup vs baseline: 1.4225x; 1.1523x over previous
//
#include <hip/hip_runtime.h>
#include <hip/hip_bf16.h>
#include <stdint.h>

typedef __bf16 bf16_t;
typedef __bf16 bf16x8 __attribute__((ext_vector_type(8)));
typedef float f32x4 __attribute__((ext_vector_type(4)));
typedef float f32x2 __attribute__((ext_vector_type(2)));
typedef float floatv4 __attribute__((ext_vector_type(4)));

// async 16B global->LDS DMA
static __device__ __forceinline__ void gload16(const void* g, void* l){
  __builtin_amdgcn_global_load_lds((const __attribute__((address_space(1))) void*)g,
                                   (__attribute__((address_space(3))) void*)l, 16, 0, 0);
}
// fp8 e4m3 (OCP) HW conversions
static __device__ __forceinline__ void acc4_fp8(float* a, unsigned w, float wt){
  f32x2 lo, hi;
  unsigned wh = w >> 16;
  asm("v_cvt_pk_f32_fp8 %0, %1" : "=v"(lo) : "v"(w));
  asm("v_cvt_pk_f32_fp8 %0, %1" : "=v"(hi) : "v"(wh));
  a[0] += wt*lo[0]; a[1] += wt*lo[1]; a[2] += wt*hi[0]; a[3] += wt*hi[1];
}
static __device__ __forceinline__ void dec4_fp8(float* d, unsigned w){
  f32x2 lo, hi;
  unsigned wh = w >> 16;
  asm("v_cvt_pk_f32_fp8 %0, %1" : "=v"(lo) : "v"(w));
  asm("v_cvt_pk_f32_fp8 %0, %1" : "=v"(hi) : "v"(wh));
  d[0] = lo[0]; d[1] = lo[1]; d[2] = hi[0]; d[3] = hi[1];
}
static __device__ __forceinline__ unsigned cvt2fp8(float a, float b){
  unsigned r;
  asm("v_cvt_pk_fp8_f32 %0, %1, %2" : "=v"(r) : "v"(a), "v"(b));
  return r & 0xffffu;
}
static __device__ __forceinline__ uint8_t cvt1fp8(float a){
  unsigned r;
  asm("v_cvt_pk_fp8_f32 %0, %1, %1" : "=v"(r) : "v"(a));
  return (uint8_t)r;
}
// packed edge: bits[16:0]=col, bits[31:17]=weight f32 bits[30:16] (sign implicit)
static __device__ __forceinline__ unsigned packEdge(int col, float w_pos){
  unsigned b = __float_as_uint(w_pos) + 0x8000u;
  return ((b >> 16) << 17) | (unsigned)col;
}
static __device__ __forceinline__ float edgeWpos(unsigned u){
  return __uint_as_float((u >> 17) << 16);
}
static __device__ __forceinline__ float edgeWneg(unsigned u){
  return __uint_as_float(0x80000000u | ((u >> 17) << 16));
}

constexpr int NN = 100000;
constexpr int NE = 1600000;
constexpr int NB_G  = (NN + 127)/128;    // 782
constexpr int NBIN = (NN + 127)/128;     // 782
constexpr int EPB  = 4096;
constexpr int NBB  = (NE + EPB - 1)/EPB; // 391
constexpr int MAXBE = 3072;
constexpr int NB_TW8 = (2*3*128*128)/256; // 384 transw8 blocks

// ---------------- CSR build (binA fused into gemm1) ----------------
__global__ __launch_bounds__(256) void k_scanbins(const int* __restrict__ bincnt,
                                                  int* __restrict__ binptr,
                                                  int* __restrict__ rowptr){
  __shared__ int s[256];
  int t = threadIdx.x;
  int b0 = t*4;
  int c[4]; int tot = 0;
  #pragma unroll
  for (int j = 0; j < 4; ++j){
    int b = b0 + j;
    c[j] = (b < NBIN) ? bincnt[b] : 0;
    tot += c[j];
  }
  s[t] = tot;
  __syncthreads();
  for (int off = 1; off < 256; off <<= 1){
    int v = (t >= off) ? s[t - off] : 0;
    __syncthreads();
    s[t] += v;
    __syncthreads();
  }
  int ex = s[t] - tot;
  #pragma unroll
  for (int j = 0; j < 4; ++j){
    int b = b0 + j;
    if (b < NBIN) binptr[b] = ex;
    ex += c[j];
  }
  if (t == 255){ binptr[NBIN] = ex; rowptr[NN] = ex; }
}

__global__ __launch_bounds__(256) void k_binB(const int* __restrict__ row,
                                              const int* __restrict__ col,
                                              const float* __restrict__ w,
                                              const int* __restrict__ binptr,
                                              const int* __restrict__ blockbase,
                                              int2* __restrict__ temp){
  __shared__ int h[NBIN];
  for (int b = threadIdx.x; b < NBIN; b += 256) h[b] = 0;
  __syncthreads();
  int base = blockIdx.x * EPB;
  for (int k = 0; k < EPB; k += 256){
    int i = base + k + threadIdx.x;
    if (i < NE){
      int r = row[i];
      int b = r >> 7;
      int rank = atomicAdd(&h[b], 1);
      int pos = binptr[b] + blockbase[blockIdx.x * NBIN + b] + rank;
      temp[pos] = make_int2(col[i] | ((r & 127) << 17), __float_as_int(w[i]));
    }
  }
}

__global__ __launch_bounds__(256) void k_binC(const int2* __restrict__ temp,
                                              const int* __restrict__ binptr,
                                              unsigned* __restrict__ ec,
                                              int* __restrict__ rowptr,
                                              float* __restrict__ dinv, int n){
  __shared__ int2 sbuf[MAXBE];
  __shared__ int cnt[128];
  __shared__ int scan[128];
  __shared__ int estart[128];
  const int b = blockIdx.x;
  const int e0 = binptr[b];
  int nb = binptr[b+1] - e0; if (nb > MAXBE) nb = MAXBE;
  const int t = threadIdx.x;
  if (t < 128) cnt[t] = 0;
  __syncthreads();
  for (int k = t; k < nb; k += 256)
    atomicAdd(&cnt[(temp[e0+k].x >> 17) & 127], 1);
  __syncthreads();
  if (t < 128) scan[t] = cnt[t];
  __syncthreads();
  for (int off = 1; off < 128; off <<= 1){
    int v = (t < 128 && t >= off) ? scan[t - off] : 0;
    __syncthreads();
    if (t < 128) scan[t] += v;
    __syncthreads();
  }
  if (t < 128){ estart[t] = scan[t] - cnt[t]; cnt[t] = 0; }
  __syncthreads();
  for (int k = t; k < nb; k += 256){
    int2 q = temp[e0+k];
    int rl = (q.x >> 17) & 127;
    int rank = atomicAdd(&cnt[rl], 1);
    sbuf[estart[rl] + rank] = q;
  }
  __syncthreads();
  for (int k = t; k < nb; k += 256){
    int2 q = sbuf[k];
    ec[e0 + k] = packEdge(q.x & 0x1FFFF, __int_as_float(q.y));
  }
  if (t < 128){
    int gid = b*128 + t;
    if (gid < n){
      rowptr[gid] = e0 + estart[t];
      float s = 0.f;
      int s0 = estart[t], c = cnt[t];
      for (int j = 0; j < c; ++j) s += __int_as_float(sbuf[s0+j].y);
      dinv[gid] = (s > 0.f) ? rsqrtf(s) : 0.f;
    }
  }
}

__global__ __launch_bounds__(256) void k_norm(unsigned* __restrict__ ec,
                                              const int* __restrict__ rowptr,
                                              const float* __restrict__ dinv, int n){
  int node = blockIdx.x*4 + (threadIdx.x >> 6);
  if (node >= n) return;
  int lane = threadIdx.x & 63;
  int e0 = rowptr[node], e1 = rowptr[node+1];
  float dr = dinv[node];
  for (int e = e0 + lane; e < e1; e += 64){
    unsigned u = ec[e];
    int c = u & 0x1FFFF;
    float wn = dr * edgeWpos(u) * dinv[c];
    ec[e] = packEdge(c, wn);
  }
}

// Wt1 bf16 [chunk][col][k]
__global__ void k_transw1(const float* __restrict__ W1, bf16_t* __restrict__ Wt1){
  int idx = blockIdx.x*256 + threadIdx.x;   // 32768
  int c = idx >> 14, r = (idx >> 7) & 127, j = idx & 127;
  Wt1[(c << 14) + (j << 7) + r] = (bf16_t)W1[idx];
}

// ---------------- FUSED: gemm1 (782) + binA (391) + conv-weight fp8 pack (384) ----
__global__ __launch_bounds__(256) void k_gemm1_fused(
    const float* __restrict__ x, const bf16_t* __restrict__ Wt, const float* __restrict__ bias,
    uint8_t* __restrict__ out8, int M,
    const int* __restrict__ row, int* __restrict__ bincnt, int* __restrict__ blockbase,
    const float* __restrict__ c1W, const float* __restrict__ c2W,
    uint8_t* __restrict__ W8c1, uint8_t* __restrict__ W8c2)
{
  __shared__ uint8_t lds[2][16384];
  __shared__ int hA[NBIN];
  const int tid = threadIdx.x;

  if (blockIdx.x >= NB_G + NBB){                 // --- conv-weight fp8 pack ---
    int base = (blockIdx.x - NB_G - NBB)*256 + tid;   // 0..98303
    int m = base / 49152;
    int local = base - m*49152;
    const float* src = m ? c2W : c1W;
    uint8_t* dst = m ? W8c2 : W8c1;
    int c = local >> 14, r = (local >> 7) & 127, j = local & 127;
    dst[(c << 14) + (j << 7) + r] = cvt1fp8(src[local]);
    return;
  }
  if (blockIdx.x >= NB_G){                       // --- binA histogram ---
    int bb = blockIdx.x - NB_G;
    for (int b = tid; b < NBIN; b += 256) hA[b] = 0;
    __syncthreads();
    int base = bb * EPB;
    for (int k = 0; k < EPB; k += 256){
      int i = base + k + tid;
      if (i < NE) atomicAdd(&hA[row[i] >> 7], 1);
    }
    __syncthreads();
    for (int b = tid; b < NBIN; b += 256){
      int c = hA[b];
      blockbase[bb * NBIN + b] = c ? atomicAdd(&bincnt[b], c) : 0;
    }
    return;
  }

  // --- gemm1: BM=128, async dbuf, fp8-only output (r17-proven) ---
  const int wave = tid >> 6, lane = tid & 63;
  const int wm = wave >> 1, wn = wave & 1;
  const int l15 = lane & 15, lq = lane >> 4;
  const int blockRow = blockIdx.x * 128;
  const int strow = tid >> 3;
  const int scell = tid & 7;

  f32x4 acc[4][4];
  #pragma unroll
  for (int a = 0; a < 4; ++a)
    #pragma unroll
    for (int b = 0; b < 4; ++b) acc[a][b] = f32x4{0.f,0.f,0.f,0.f};

  #pragma unroll
  for (int j = 0; j < 4; ++j){
    int r = j*32 + strow;
    int gr = blockRow + r; if (gr > M-1) gr = M-1;
    gload16((const char*)x + (size_t)gr*1024 + ((scell ^ (r&7)) << 4),
            &lds[0][j*4096 + tid*16]);
  }

  #pragma unroll
  for (int s = 0; s < 8; ++s){
    if (s < 7){
      #pragma unroll
      for (int j = 0; j < 4; ++j){
        int r = j*32 + strow;
        int gr = blockRow + r; if (gr > M-1) gr = M-1;
        gload16((const char*)x + (size_t)gr*1024 + (s+1)*128 + ((scell ^ (r&7)) << 4),
                &lds[(s+1)&1][j*4096 + tid*16]);
      }
    }
    __syncthreads();
    const uint8_t* buf = lds[s&1];
    bf16x8 af[4], bfr[4];
    #pragma unroll
    for (int fm = 0; fm < 4; ++fm){
      int r = wm*64 + fm*16 + l15;
      floatv4 v0 = *(const floatv4*)(buf + r*128 + (((lq*2    ) ^ (r&7)) << 4));
      floatv4 v1 = *(const floatv4*)(buf + r*128 + (((lq*2 + 1) ^ (r&7)) << 4));
      bf16x8 t;
      t[0]=(bf16_t)v0[0]; t[1]=(bf16_t)v0[1]; t[2]=(bf16_t)v0[2]; t[3]=(bf16_t)v0[3];
      t[4]=(bf16_t)v1[0]; t[5]=(bf16_t)v1[1]; t[6]=(bf16_t)v1[2]; t[7]=(bf16_t)v1[3];
      af[fm] = t;
    }
    #pragma unroll
    for (int fn = 0; fn < 4; ++fn)
      bfr[fn] = *(const bf16x8*)(Wt + ((size_t)(((s>>2) << 7) + wn*64 + fn*16 + l15) << 7) + (s&3)*32 + lq*8);
    #pragma unroll
    for (int fm = 0; fm < 4; ++fm)
      #pragma unroll
      for (int fn = 0; fn < 4; ++fn)
        acc[fm][fn] = __builtin_amdgcn_mfma_f32_16x16x32_bf16(af[fm], bfr[fn], acc[fm][fn], 0, 0, 0);
    __syncthreads();
  }
  #pragma unroll
  for (int fm = 0; fm < 4; ++fm){
    #pragma unroll
    for (int j = 0; j < 4; ++j){
      int growo = blockRow + wm*64 + fm*16 + lq*4 + j;
      if (growo < M){
        #pragma unroll
        for (int fn = 0; fn < 4; ++fn){
          int c = wn*64 + fn*16 + l15;
          float v = fmaxf(acc[fm][fn][j] + bias[c], 0.f);
          out8[((size_t)growo << 7) + c] = cvt1fp8(v);
        }
      }
    }
  }
}

// ---------------- conv GEMM fp8 (+ optional fused head, atomic-free reduce) --------
__global__ __launch_bounds__(256) void k_gemm8(
    const uint8_t* __restrict__ a0, const uint8_t* __restrict__ a1, const uint8_t* __restrict__ a2,
    const uint8_t* __restrict__ Wt8, const float* __restrict__ bias,
    uint8_t* __restrict__ out8,
    const float* __restrict__ W2h, const float* __restrict__ b2h, float* __restrict__ outh,
    int M)
{
  __shared__ uint8_t lds[2][8192];
  __shared__ float logits[128][2][2];   // [row][wn][cls], written lane-exclusive
  const int tid = threadIdx.x;
  const int wave = tid >> 6, lane = tid & 63;
  const int wm = wave >> 1, wn = wave & 1;
  const int l15 = lane & 15, lq = lane >> 4;
  const int blockRow = blockIdx.x * 128;

  f32x4 acc[4][4];
  #pragma unroll
  for (int a = 0; a < 4; ++a)
    #pragma unroll
    for (int b = 0; b < 4; ++b) acc[a][b] = f32x4{0.f,0.f,0.f,0.f};

  #pragma unroll
  for (int j = 0; j < 2; ++j){
    int flat = j*256 + tid;
    int r = flat >> 2, cell = flat & 3;
    int gr = blockRow + r; if (gr > M-1) gr = M-1;
    gload16(a0 + (size_t)gr*128 + ((cell ^ ((r>>1)&3)) << 4), &lds[0][flat << 4]);
  }

  #pragma unroll
  for (int s = 0; s < 6; ++s){
    if (s < 5){
      const int sn = s + 1;
      const uint8_t* srcn = (sn>>1) == 0 ? a0 : ((sn>>1) == 1 ? a1 : a2);
      #pragma unroll
      for (int j = 0; j < 2; ++j){
        int flat = j*256 + tid;
        int r = flat >> 2, cell = flat & 3;
        int gr = blockRow + r; if (gr > M-1) gr = M-1;
        gload16(srcn + (size_t)gr*128 + (sn&1)*64 + ((cell ^ ((r>>1)&3)) << 4),
                &lds[sn&1][flat << 4]);
      }
    }
    __syncthreads();
    const uint8_t* buf = lds[s&1];
    #pragma unroll
    for (int kk32 = 0; kk32 < 2; ++kk32){
      long af[4], bfr[4];
      #pragma unroll
      for (int fm = 0; fm < 4; ++fm){
        int r = wm*64 + fm*16 + l15;
        int cell = kk32*2 + (lq >> 1);
        af[fm] = *(const long*)(buf + r*64 + ((cell ^ ((r>>1)&3)) << 4) + (lq & 1)*8);
      }
      #pragma unroll
      for (int fn = 0; fn < 4; ++fn)
        bfr[fn] = *(const long*)(Wt8 + ((size_t)(((s>>1) << 7) + wn*64 + fn*16 + l15) << 7)
                                 + (s&1)*64 + kk32*32 + lq*8);
      #pragma unroll
      for (int fm = 0; fm < 4; ++fm)
        #pragma unroll
        for (int fn = 0; fn < 4; ++fn)
          acc[fm][fn] = __builtin_amdgcn_mfma_f32_16x16x32_fp8_fp8(af[fm], bfr[fn], acc[fm][fn], 0, 0, 0);
    }
    __syncthreads();
  }

  if (outh){
    // fused head: per-thread partial dot, shfl-reduce over the 16 l15 lanes,
    // lane-exclusive LDS write (no atomics), then softmax by 128 threads.
    float w2l[8];
    #pragma unroll
    for (int fn = 0; fn < 4; ++fn){
      int c = wn*64 + fn*16 + l15;
      w2l[fn*2]   = W2h[c*2];
      w2l[fn*2+1] = W2h[c*2+1];
    }
    #pragma unroll
    for (int fm = 0; fm < 4; ++fm){
      #pragma unroll
      for (int j = 0; j < 4; ++j){
        int r = wm*64 + fm*16 + lq*4 + j;
        float p0 = 0.f, p1 = 0.f;
        #pragma unroll
        for (int fn = 0; fn < 4; ++fn){
          float v = fmaxf(acc[fm][fn][j] + bias[wn*64 + fn*16 + l15], 0.f);
          p0 += v*w2l[fn*2];
          p1 += v*w2l[fn*2+1];
        }
        // reduce across the 16 l15 lanes (masks stay inside the lq group)
        #pragma unroll
        for (int m = 1; m < 16; m <<= 1){
          p0 += __shfl_xor(p0, m, 64);
          p1 += __shfl_xor(p1, m, 64);
        }
        if (l15 == 0){
          logits[r][wn][0] = p0;
          logits[r][wn][1] = p1;
        }
      }
    }
    __syncthreads();
    if (tid < 128){
      int node = blockRow + tid;
      if (node < M){
        float l0 = logits[tid][0][0] + logits[tid][1][0] + b2h[0];
        float l1 = logits[tid][0][1] + logits[tid][1][1] + b2h[1];
        float mx = fmaxf(l0, l1);
        float e0 = __expf(l0 - mx), e1 = __expf(l1 - mx);
        float inv = 1.f / (e0 + e1);
        *(float2*)(outh + (size_t)node*2) = make_float2(e0*inv, e1*inv);
      }
    }
  } else {
    #pragma unroll
    for (int fm = 0; fm < 4; ++fm){
      #pragma unroll
      for (int j = 0; j < 4; ++j){
        int growo = blockRow + wm*64 + fm*16 + lq*4 + j;
        if (growo < M){
          #pragma unroll
          for (int fn = 0; fn < 4; ++fn){
            int c = wn*64 + fn*16 + l15;
            float v = fmaxf(acc[fm][fn][j] + bias[c], 0.f);
            out8[((size_t)growo << 7) + c] = cvt1fp8(v);
          }
        }
      }
    }
  }
}

// ---------------- SpMM fp8: fp8 in / fp8 out, 8-deep unroll (r17-proven) ----------
__global__ __launch_bounds__(256) void k_spmm8(
    const int* __restrict__ rowptr, const unsigned* __restrict__ ec,
    const uint8_t* __restrict__ V8, const uint8_t* __restrict__ sub8, float alpha,
    uint8_t* __restrict__ out8, int n)
{
  const int lane = threadIdx.x & 63;
  const int wave = threadIdx.x >> 6;
  const int g = lane >> 4;
  const int s = lane & 15;
  const int node = blockIdx.x*16 + wave*4 + g;
  if (node >= n) return;

  int e = rowptr[node];
  const int e1 = rowptr[node+1];
  const int fb = s << 3;

  float acc[8] = {0.f,0.f,0.f,0.f,0.f,0.f,0.f,0.f};

  for (; e + 8 <= e1; e += 8){
    unsigned u0 = ec[e],   u1 = ec[e+1], u2 = ec[e+2], u3 = ec[e+3];
    unsigned u4 = ec[e+4], u5 = ec[e+5], u6 = ec[e+6], u7 = ec[e+7];
    uint2 p0 = *(const uint2*)(V8 + (((size_t)(u0 & 0x1FFFF)) << 7) + fb);
    uint2 p1 = *(const uint2*)(V8 + (((size_t)(u1 & 0x1FFFF)) << 7) + fb);
    uint2 p2 = *(const uint2*)(V8 + (((size_t)(u2 & 0x1FFFF)) << 7) + fb);
    uint2 p3 = *(const uint2*)(V8 + (((size_t)(u3 & 0x1FFFF)) << 7) + fb);
    uint2 p4 = *(const uint2*)(V8 + (((size_t)(u4 & 0x1FFFF)) << 7) + fb);
    uint2 p5 = *(const uint2*)(V8 + (((size_t)(u5 & 0x1FFFF)) << 7) + fb);
    uint2 p6 = *(const uint2*)(V8 + (((size_t)(u6 & 0x1FFFF)) << 7) + fb);
    uint2 p7 = *(const uint2*)(V8 + (((size_t)(u7 & 0x1FFFF)) << 7) + fb);
    float w0 = edgeWneg(u0), w1 = edgeWneg(u1), w2 = edgeWneg(u2), w3 = edgeWneg(u3);
    float w4 = edgeWneg(u4), w5 = edgeWneg(u5), w6 = edgeWneg(u6), w7 = edgeWneg(u7);
    acc4_fp8(acc,   p0.x, w0); acc4_fp8(acc+4, p0.y, w0);
    acc4_fp8(acc,   p1.x, w1); acc4_fp8(acc+4, p1.y, w1);
    acc4_fp8(acc,   p2.x, w2); acc4_fp8(acc+4, p2.y, w2);
    acc4_fp8(acc,   p3.x, w3); acc4_fp8(acc+4, p3.y, w3);
    acc4_fp8(acc,   p4.x, w4); acc4_fp8(acc+4, p4.y, w4);
    acc4_fp8(acc,   p5.x, w5); acc4_fp8(acc+4, p5.y, w5);
    acc4_fp8(acc,   p6.x, w6); acc4_fp8(acc+4, p6.y, w6);
    acc4_fp8(acc,   p7.x, w7); acc4_fp8(acc+4, p7.y, w7);
  }
  for (; e + 4 <= e1; e += 4){
    unsigned u0 = ec[e], u1 = ec[e+1], u2 = ec[e+2], u3 = ec[e+3];
    uint2 p0 = *(const uint2*)(V8 + (((size_t)(u0 & 0x1FFFF)) << 7) + fb);
    uint2 p1 = *(const uint2*)(V8 + (((size_t)(u1 & 0x1FFFF)) << 7) + fb);
    uint2 p2 = *(const uint2*)(V8 + (((size_t)(u2 & 0x1FFFF)) << 7) + fb);
    uint2 p3 = *(const uint2*)(V8 + (((size_t)(u3 & 0x1FFFF)) << 7) + fb);
    float w0 = edgeWneg(u0), w1 = edgeWneg(u1), w2 = edgeWneg(u2), w3 = edgeWneg(u3);
    acc4_fp8(acc,   p0.x, w0); acc4_fp8(acc+4, p0.y, w0);
    acc4_fp8(acc,   p1.x, w1); acc4_fp8(acc+4, p1.y, w1);
    acc4_fp8(acc,   p2.x, w2); acc4_fp8(acc+4, p2.y, w2);
    acc4_fp8(acc,   p3.x, w3); acc4_fp8(acc+4, p3.y, w3);
  }
  for (; e < e1; ++e){
    unsigned u = ec[e];
    uint2 p = *(const uint2*)(V8 + (((size_t)(u & 0x1FFFF)) << 7) + fb);
    float w = edgeWneg(u);
    acc4_fp8(acc, p.x, w); acc4_fp8(acc+4, p.y, w);
  }

  float r[8];
  #pragma unroll
  for (int i = 0; i < 8; ++i) r[i] = alpha*acc[i];
  if (sub8){
    uint2 sv = *(const uint2*)(sub8 + (((size_t)node) << 7) + fb);
    float sd[8];
    dec4_fp8(sd,     sv.x);
    dec4_fp8(sd + 4, sv.y);
    #pragma unroll
    for (int i = 0; i < 8; ++i) r[i] -= sd[i];
  }
  uint2 o8;
  o8.x = cvt2fp8(r[0], r[1]) | (cvt2fp8(r[2], r[3]) << 16);
  o8.y = cvt2fp8(r[4], r[5]) | (cvt2fp8(r[6], r[7]) << 16);
  *(uint2*)(out8 + (((size_t)node) << 7) + fb) = o8;
}

// ---------------- launch ----------------

extern "C" void kernel_launch(void* const* d_in, const int* in_sizes, int n_in,
                              void* d_out, int out_size, void* d_ws, size_t ws_size,
                              hipStream_t stream)
{
  const float* x   = (const float*)d_in[0];
  const int*   ei  = (const int*)d_in[1];
  const float* ew  = (const float*)d_in[2];
  const float* W1  = (const float*)d_in[3];
  const float* b1  = (const float*)d_in[4];
  const float* c1W = (const float*)d_in[5];
  const float* c1b = (const float*)d_in[6];
  const float* c2W = (const float*)d_in[7];
  const float* c2b = (const float*)d_in[8];
  const float* W2  = (const float*)d_in[9];
  const float* b2  = (const float*)d_in[10];
  float* out = (float*)d_out;

  const int n = NN, e = NE;
  const int* row = ei;
  const int* col = ei + e;

  char* ws = (char*)d_ws;
  size_t off = 0;
  auto carve = [&](size_t bytes)->void*{
    void* p = ws + off;
    off += (bytes + 255) & ~(size_t)255;
    return p;
  };
  uint8_t* q8a = (uint8_t*)carve((size_t)n*128);     // h0 fp8
  uint8_t* B8  = (uint8_t*)carve((size_t)n*128);     // Tx1 fp8
  uint8_t* C8  = (uint8_t*)carve((size_t)n*128);     // Tx2 fp8
  uint8_t* D8  = (uint8_t*)carve((size_t)n*128);     // h1 fp8 (aliases temp)
  float*  dinv = (float*)carve((size_t)n*4);
  int*    rowptr = (int*)carve((size_t)(n+1)*4);
  unsigned* ec = (unsigned*)carve((size_t)e*4);
  int*    bincnt = (int*)carve((size_t)NBIN*4);
  int*    binptr = (int*)carve((size_t)(NBIN+1)*4);
  int*    blockbase = (int*)carve((size_t)NBB*NBIN*4);   // 1.22MB
  bf16_t*  Wt1  = (bf16_t*)carve(2*128*128*2);
  uint8_t* W8c1 = (uint8_t*)carve(3*128*128);
  uint8_t* W8c2 = (uint8_t*)carve(3*128*128);
  // temp edge buffer (12.8MB) aliases D8: temp lives [binB,binC]; D8 first
  // written by conv1's k_gemm8 (after binC).
  int2* temp = (int2*)D8;
  (void)ws_size; (void)in_sizes; (void)n_in; (void)out_size;

  const int NB_W = (n + 3)/4;       // 25000
  const int NB_S = (n + 15)/16;     // 6250

  hipMemsetAsync(bincnt, 0, (size_t)NBIN*4, stream);
  k_transw1<<<128,256,0,stream>>>(W1, Wt1);
  // fused: h0 = relu(x@W1+b1) -> q8a  AND  binA histogram  AND  conv-weight fp8 pack
  k_gemm1_fused<<<NB_G + NBB + NB_TW8,256,0,stream>>>(
      x, Wt1, b1, q8a, n, row, bincnt, blockbase, c1W, c2W, W8c1, W8c2);
  k_scanbins<<<1,256,0,stream>>>(bincnt, binptr, rowptr);
  k_binB<<<NBB,256,0,stream>>>(row, col, ew, binptr, blockbase, temp);
  k_binC<<<NBIN,256,0,stream>>>(temp, binptr, ec, rowptr, dinv, n);
  k_norm<<<NB_W,256,0,stream>>>(ec, rowptr, dinv, n);

  // conv1: Tx1 = Lx(h0) -> B8 ; Tx2 = 2*Lx(Tx1) - h0 -> C8
  k_spmm8<<<NB_S,256,0,stream>>>(rowptr, ec, q8a, nullptr, 1.f, B8, n);
  k_spmm8<<<NB_S,256,0,stream>>>(rowptr, ec, B8, q8a, 2.f, C8, n);
  // h1 = relu([h0|Tx1|Tx2] @ Wc1 + b) -> D8 (fp8)
  k_gemm8<<<NB_G,256,0,stream>>>(q8a, B8, C8, W8c1, c1b, D8, nullptr, nullptr, nullptr, n);
  // conv2
  k_spmm8<<<NB_S,256,0,stream>>>(rowptr, ec, D8, nullptr, 1.f, B8, n);
  k_spmm8<<<NB_S,256,0,stream>>>(rowptr, ec, B8, D8, 2.f, C8, n);
  // h2 GEMM + fused head -> out (softmax probabilities)
  k_gemm8<<<NB_G,256,0,stream>>>(D8, B8, C8, W8c2, c2b, nullptr, W2, b2, out, n);
}

// Round 20
// 295.212 us; speedup vs baseline: 1.4723x; 1.0351x over previous
//
#include <hip/hip_runtime.h>
#include <hip/hip_bf16.h>
#include <stdint.h>

typedef __bf16 bf16_t;
typedef __bf16 bf16x8 __attribute__((ext_vector_type(8)));
typedef float f32x4 __attribute__((ext_vector_type(4)));
typedef float f32x2 __attribute__((ext_vector_type(2)));
typedef float floatv4 __attribute__((ext_vector_type(4)));

// async 16B global->LDS DMA
static __device__ __forceinline__ void gload16(const void* g, void* l){
  __builtin_amdgcn_global_load_lds((const __attribute__((address_space(1))) void*)g,
                                   (__attribute__((address_space(3))) void*)l, 16, 0, 0);
}
// fp8 e4m3 (OCP) HW conversions
static __device__ __forceinline__ void acc4_fp8(float* a, unsigned w, float wt){
  f32x2 lo, hi;
  unsigned wh = w >> 16;
  asm("v_cvt_pk_f32_fp8 %0, %1" : "=v"(lo) : "v"(w));
  asm("v_cvt_pk_f32_fp8 %0, %1" : "=v"(hi) : "v"(wh));
  a[0] += wt*lo[0]; a[1] += wt*lo[1]; a[2] += wt*hi[0]; a[3] += wt*hi[1];
}
static __device__ __forceinline__ void dec4_fp8(float* d, unsigned w){
  f32x2 lo, hi;
  unsigned wh = w >> 16;
  asm("v_cvt_pk_f32_fp8 %0, %1" : "=v"(lo) : "v"(w));
  asm("v_cvt_pk_f32_fp8 %0, %1" : "=v"(hi) : "v"(wh));
  d[0] = lo[0]; d[1] = lo[1]; d[2] = hi[0]; d[3] = hi[1];
}
static __device__ __forceinline__ unsigned cvt2fp8(float a, float b){
  unsigned r;
  asm("v_cvt_pk_fp8_f32 %0, %1, %2" : "=v"(r) : "v"(a), "v"(b));
  return r & 0xffffu;
}
static __device__ __forceinline__ uint8_t cvt1fp8(float a){
  unsigned r;
  asm("v_cvt_pk_fp8_f32 %0, %1, %1" : "=v"(r) : "v"(a));
  return (uint8_t)r;
}
// packed edge: bits[16:0]=col, bits[31:17]=weight f32 bits[30:16] (sign implicit)
static __device__ __forceinline__ unsigned packEdge(int col, float w_pos){
  unsigned b = __float_as_uint(w_pos) + 0x8000u;
  return ((b >> 16) << 17) | (unsigned)col;
}
static __device__ __forceinline__ float edgeWpos(unsigned u){
  return __uint_as_float((u >> 17) << 16);
}
static __device__ __forceinline__ float edgeWneg(unsigned u){
  return __uint_as_float(0x80000000u | ((u >> 17) << 16));
}

constexpr int NN = 100000;
constexpr int NE = 1600000;
constexpr int NB_G  = (NN + 127)/128;    // 782
constexpr int NBIN = (NN + 127)/128;     // 782
constexpr int EPB  = 4096;
constexpr int NBB  = (NE + EPB - 1)/EPB; // 391
constexpr int MAXBE = 3072;
constexpr int NB_TW8 = (2*3*128*128)/256; // 384 conv-weight pack blocks
constexpr int NB_TW1 = (2*128*128)/256;   // 128 Wt1 pack blocks

// ---------------- binA + Wt1 pack (fused) ----------------
__global__ __launch_bounds__(256) void k_binA_tw(const int* __restrict__ row,
                                                 int* __restrict__ bincnt,
                                                 int* __restrict__ blockbase,
                                                 const float* __restrict__ W1,
                                                 bf16_t* __restrict__ Wt1){
  __shared__ int h[NBIN];
  const int tid = threadIdx.x;
  if (blockIdx.x >= NBB){             // --- Wt1 bf16 [chunk][col][k] pack ---
    int idx = (blockIdx.x - NBB)*256 + tid;   // 0..32767
    int c = idx >> 14, r = (idx >> 7) & 127, j = idx & 127;
    Wt1[(c << 14) + (j << 7) + r] = (bf16_t)W1[idx];
    return;
  }
  for (int b = tid; b < NBIN; b += 256) h[b] = 0;
  __syncthreads();
  int base = blockIdx.x * EPB;
  for (int k = 0; k < EPB; k += 256){
    int i = base + k + tid;
    if (i < NE) atomicAdd(&h[row[i] >> 7], 1);
  }
  __syncthreads();
  for (int b = tid; b < NBIN; b += 256){
    int c = h[b];
    blockbase[blockIdx.x * NBIN + b] = c ? atomicAdd(&bincnt[b], c) : 0;
  }
}

__global__ __launch_bounds__(256) void k_scanbins(const int* __restrict__ bincnt,
                                                  int* __restrict__ binptr,
                                                  int* __restrict__ rowptr){
  __shared__ int s[256];
  int t = threadIdx.x;
  int b0 = t*4;
  int c[4]; int tot = 0;
  #pragma unroll
  for (int j = 0; j < 4; ++j){
    int b = b0 + j;
    c[j] = (b < NBIN) ? bincnt[b] : 0;
    tot += c[j];
  }
  s[t] = tot;
  __syncthreads();
  for (int off = 1; off < 256; off <<= 1){
    int v = (t >= off) ? s[t - off] : 0;
    __syncthreads();
    s[t] += v;
    __syncthreads();
  }
  int ex = s[t] - tot;
  #pragma unroll
  for (int j = 0; j < 4; ++j){
    int b = b0 + j;
    if (b < NBIN) binptr[b] = ex;
    ex += c[j];
  }
  if (t == 255){ binptr[NBIN] = ex; rowptr[NN] = ex; }
}

__global__ __launch_bounds__(256) void k_binC(const int2* __restrict__ temp,
                                              const int* __restrict__ binptr,
                                              unsigned* __restrict__ ec,
                                              int* __restrict__ rowptr,
                                              float* __restrict__ dinv, int n){
  __shared__ int2 sbuf[MAXBE];
  __shared__ int cnt[128];
  __shared__ int scan[128];
  __shared__ int estart[128];
  const int b = blockIdx.x;
  const int e0 = binptr[b];
  int nb = binptr[b+1] - e0; if (nb > MAXBE) nb = MAXBE;
  const int t = threadIdx.x;
  if (t < 128) cnt[t] = 0;
  __syncthreads();
  for (int k = t; k < nb; k += 256)
    atomicAdd(&cnt[(temp[e0+k].x >> 17) & 127], 1);
  __syncthreads();
  if (t < 128) scan[t] = cnt[t];
  __syncthreads();
  for (int off = 1; off < 128; off <<= 1){
    int v = (t < 128 && t >= off) ? scan[t - off] : 0;
    __syncthreads();
    if (t < 128) scan[t] += v;
    __syncthreads();
  }
  if (t < 128){ estart[t] = scan[t] - cnt[t]; cnt[t] = 0; }
  __syncthreads();
  for (int k = t; k < nb; k += 256){
    int2 q = temp[e0+k];
    int rl = (q.x >> 17) & 127;
    int rank = atomicAdd(&cnt[rl], 1);
    sbuf[estart[rl] + rank] = q;
  }
  __syncthreads();
  for (int k = t; k < nb; k += 256){
    int2 q = sbuf[k];
    ec[e0 + k] = packEdge(q.x & 0x1FFFF, __int_as_float(q.y));
  }
  if (t < 128){
    int gid = b*128 + t;
    if (gid < n){
      rowptr[gid] = e0 + estart[t];
      float s = 0.f;
      int s0 = estart[t], c = cnt[t];
      for (int j = 0; j < c; ++j) s += __int_as_float(sbuf[s0+j].y);
      dinv[gid] = (s > 0.f) ? rsqrtf(s) : 0.f;
    }
  }
}

// ---------------- FUSED: gemm1 (782) + binB (391) + conv-weight fp8 pack (384) ----
__global__ __launch_bounds__(256) void k_gemm1_fused(
    const float* __restrict__ x, const bf16_t* __restrict__ Wt, const float* __restrict__ bias,
    uint8_t* __restrict__ out8, int M,
    const int* __restrict__ row, const int* __restrict__ col, const float* __restrict__ w,
    const int* __restrict__ binptr, const int* __restrict__ blockbase, int2* __restrict__ temp,
    const float* __restrict__ c1W, const float* __restrict__ c2W,
    uint8_t* __restrict__ W8c1, uint8_t* __restrict__ W8c2)
{
  __shared__ uint8_t lds[2][16384];
  __shared__ int hB[NBIN];
  const int tid = threadIdx.x;

  if (blockIdx.x >= NB_G + NBB){                 // --- conv-weight fp8 pack ---
    int base = (blockIdx.x - NB_G - NBB)*256 + tid;   // 0..98303
    int m = base / 49152;
    int local = base - m*49152;
    const float* src = m ? c2W : c1W;
    uint8_t* dst = m ? W8c2 : W8c1;
    int c = local >> 14, r = (local >> 7) & 127, j = local & 127;
    dst[(c << 14) + (j << 7) + r] = cvt1fp8(src[local]);
    return;
  }
  if (blockIdx.x >= NB_G){                       // --- binB scatter ---
    int bb = blockIdx.x - NB_G;
    for (int b = tid; b < NBIN; b += 256) hB[b] = 0;
    __syncthreads();
    int base = bb * EPB;
    for (int k = 0; k < EPB; k += 256){
      int i = base + k + tid;
      if (i < NE){
        int r = row[i];
        int b = r >> 7;
        int rank = atomicAdd(&hB[b], 1);
        int pos = binptr[b] + blockbase[bb * NBIN + b] + rank;
        temp[pos] = make_int2(col[i] | ((r & 127) << 17), __float_as_int(w[i]));
      }
    }
    return;
  }

  // --- gemm1: BM=128, async dbuf, fp8-only output ---
  const int wave = tid >> 6, lane = tid & 63;
  const int wm = wave >> 1, wn = wave & 1;
  const int l15 = lane & 15, lq = lane >> 4;
  const int blockRow = blockIdx.x * 128;
  const int strow = tid >> 3;
  const int scell = tid & 7;

  f32x4 acc[4][4];
  #pragma unroll
  for (int a = 0; a < 4; ++a)
    #pragma unroll
    for (int b = 0; b < 4; ++b) acc[a][b] = f32x4{0.f,0.f,0.f,0.f};

  #pragma unroll
  for (int j = 0; j < 4; ++j){
    int r = j*32 + strow;
    int gr = blockRow + r; if (gr > M-1) gr = M-1;
    gload16((const char*)x + (size_t)gr*1024 + ((scell ^ (r&7)) << 4),
            &lds[0][j*4096 + tid*16]);
  }

  #pragma unroll
  for (int s = 0; s < 8; ++s){
    if (s < 7){
      #pragma unroll
      for (int j = 0; j < 4; ++j){
        int r = j*32 + strow;
        int gr = blockRow + r; if (gr > M-1) gr = M-1;
        gload16((const char*)x + (size_t)gr*1024 + (s+1)*128 + ((scell ^ (r&7)) << 4),
                &lds[(s+1)&1][j*4096 + tid*16]);
      }
    }
    __syncthreads();
    const uint8_t* buf = lds[s&1];
    bf16x8 af[4], bfr[4];
    #pragma unroll
    for (int fm = 0; fm < 4; ++fm){
      int r = wm*64 + fm*16 + l15;
      floatv4 v0 = *(const floatv4*)(buf + r*128 + (((lq*2    ) ^ (r&7)) << 4));
      floatv4 v1 = *(const floatv4*)(buf + r*128 + (((lq*2 + 1) ^ (r&7)) << 4));
      bf16x8 t;
      t[0]=(bf16_t)v0[0]; t[1]=(bf16_t)v0[1]; t[2]=(bf16_t)v0[2]; t[3]=(bf16_t)v0[3];
      t[4]=(bf16_t)v1[0]; t[5]=(bf16_t)v1[1]; t[6]=(bf16_t)v1[2]; t[7]=(bf16_t)v1[3];
      af[fm] = t;
    }
    #pragma unroll
    for (int fn = 0; fn < 4; ++fn)
      bfr[fn] = *(const bf16x8*)(Wt + ((size_t)(((s>>2) << 7) + wn*64 + fn*16 + l15) << 7) + (s&3)*32 + lq*8);
    #pragma unroll
    for (int fm = 0; fm < 4; ++fm)
      #pragma unroll
      for (int fn = 0; fn < 4; ++fn)
        acc[fm][fn] = __builtin_amdgcn_mfma_f32_16x16x32_bf16(af[fm], bfr[fn], acc[fm][fn], 0, 0, 0);
    __syncthreads();
  }
  #pragma unroll
  for (int fm = 0; fm < 4; ++fm){
    #pragma unroll
    for (int j = 0; j < 4; ++j){
      int growo = blockRow + wm*64 + fm*16 + lq*4 + j;
      if (growo < M){
        #pragma unroll
        for (int fn = 0; fn < 4; ++fn){
          int c = wn*64 + fn*16 + l15;
          float v = fmaxf(acc[fm][fn][j] + bias[c], 0.f);
          out8[((size_t)growo << 7) + c] = cvt1fp8(v);
        }
      }
    }
  }
}

// ---------------- conv GEMM fp8 (+ optional fused head, shfl reduce) --------------
__global__ __launch_bounds__(256) void k_gemm8(
    const uint8_t* __restrict__ a0, const uint8_t* __restrict__ a1, const uint8_t* __restrict__ a2,
    const uint8_t* __restrict__ Wt8, const float* __restrict__ bias,
    uint8_t* __restrict__ out8,
    const float* __restrict__ W2h, const float* __restrict__ b2h, float* __restrict__ outh,
    int M)
{
  __shared__ uint8_t lds[2][8192];
  __shared__ float logits[128][2][2];
  const int tid = threadIdx.x;
  const int wave = tid >> 6, lane = tid & 63;
  const int wm = wave >> 1, wn = wave & 1;
  const int l15 = lane & 15, lq = lane >> 4;
  const int blockRow = blockIdx.x * 128;

  f32x4 acc[4][4];
  #pragma unroll
  for (int a = 0; a < 4; ++a)
    #pragma unroll
    for (int b = 0; b < 4; ++b) acc[a][b] = f32x4{0.f,0.f,0.f,0.f};

  #pragma unroll
  for (int j = 0; j < 2; ++j){
    int flat = j*256 + tid;
    int r = flat >> 2, cell = flat & 3;
    int gr = blockRow + r; if (gr > M-1) gr = M-1;
    gload16(a0 + (size_t)gr*128 + ((cell ^ ((r>>1)&3)) << 4), &lds[0][flat << 4]);
  }

  #pragma unroll
  for (int s = 0; s < 6; ++s){
    if (s < 5){
      const int sn = s + 1;
      const uint8_t* srcn = (sn>>1) == 0 ? a0 : ((sn>>1) == 1 ? a1 : a2);
      #pragma unroll
      for (int j = 0; j < 2; ++j){
        int flat = j*256 + tid;
        int r = flat >> 2, cell = flat & 3;
        int gr = blockRow + r; if (gr > M-1) gr = M-1;
        gload16(srcn + (size_t)gr*128 + (sn&1)*64 + ((cell ^ ((r>>1)&3)) << 4),
                &lds[sn&1][flat << 4]);
      }
    }
    __syncthreads();
    const uint8_t* buf = lds[s&1];
    #pragma unroll
    for (int kk32 = 0; kk32 < 2; ++kk32){
      long af[4], bfr[4];
      #pragma unroll
      for (int fm = 0; fm < 4; ++fm){
        int r = wm*64 + fm*16 + l15;
        int cell = kk32*2 + (lq >> 1);
        af[fm] = *(const long*)(buf + r*64 + ((cell ^ ((r>>1)&3)) << 4) + (lq & 1)*8);
      }
      #pragma unroll
      for (int fn = 0; fn < 4; ++fn)
        bfr[fn] = *(const long*)(Wt8 + ((size_t)(((s>>1) << 7) + wn*64 + fn*16 + l15) << 7)
                                 + (s&1)*64 + kk32*32 + lq*8);
      #pragma unroll
      for (int fm = 0; fm < 4; ++fm)
        #pragma unroll
        for (int fn = 0; fn < 4; ++fn)
          acc[fm][fn] = __builtin_amdgcn_mfma_f32_16x16x32_fp8_fp8(af[fm], bfr[fn], acc[fm][fn], 0, 0, 0);
    }
    __syncthreads();
  }

  if (outh){
    float w2l[8];
    #pragma unroll
    for (int fn = 0; fn < 4; ++fn){
      int c = wn*64 + fn*16 + l15;
      w2l[fn*2]   = W2h[c*2];
      w2l[fn*2+1] = W2h[c*2+1];
    }
    #pragma unroll
    for (int fm = 0; fm < 4; ++fm){
      #pragma unroll
      for (int j = 0; j < 4; ++j){
        int r = wm*64 + fm*16 + lq*4 + j;
        float p0 = 0.f, p1 = 0.f;
        #pragma unroll
        for (int fn = 0; fn < 4; ++fn){
          float v = fmaxf(acc[fm][fn][j] + bias[wn*64 + fn*16 + l15], 0.f);
          p0 += v*w2l[fn*2];
          p1 += v*w2l[fn*2+1];
        }
        #pragma unroll
        for (int m = 1; m < 16; m <<= 1){
          p0 += __shfl_xor(p0, m, 64);
          p1 += __shfl_xor(p1, m, 64);
        }
        if (l15 == 0){
          logits[r][wn][0] = p0;
          logits[r][wn][1] = p1;
        }
      }
    }
    __syncthreads();
    if (tid < 128){
      int node = blockRow + tid;
      if (node < M){
        float l0 = logits[tid][0][0] + logits[tid][1][0] + b2h[0];
        float l1 = logits[tid][0][1] + logits[tid][1][1] + b2h[1];
        float mx = fmaxf(l0, l1);
        float e0 = __expf(l0 - mx), e1 = __expf(l1 - mx);
        float inv = 1.f / (e0 + e1);
        *(float2*)(outh + (size_t)node*2) = make_float2(e0*inv, e1*inv);
      }
    }
  } else {
    #pragma unroll
    for (int fm = 0; fm < 4; ++fm){
      #pragma unroll
      for (int j = 0; j < 4; ++j){
        int growo = blockRow + wm*64 + fm*16 + lq*4 + j;
        if (growo < M){
          #pragma unroll
          for (int fn = 0; fn < 4; ++fn){
            int c = wn*64 + fn*16 + l15;
            float v = fmaxf(acc[fm][fn][j] + bias[c], 0.f);
            out8[((size_t)growo << 7) + c] = cvt1fp8(v);
          }
        }
      }
    }
  }
}

// ---------------- SpMM fp8 + on-the-fly normalization (conv1 pass 1) --------------
// Reads RAW edges; wn = dinv[node]*w*dinv[col]; gathers with -wn; lane 0 of each
// 16-lane group writes the normalized packed edge back for the 3 later passes.
__global__ __launch_bounds__(256) void k_spmm8n(
    const int* __restrict__ rowptr, unsigned* __restrict__ ec,
    const float* __restrict__ dinv,
    const uint8_t* __restrict__ V8, uint8_t* __restrict__ out8, int n)
{
  const int lane = threadIdx.x & 63;
  const int wave = threadIdx.x >> 6;
  const int g = lane >> 4;
  const int s = lane & 15;
  const int node = blockIdx.x*16 + wave*4 + g;
  if (node >= n) return;

  int e = rowptr[node];
  const int e1 = rowptr[node+1];
  const int fb = s << 3;
  const float dr = dinv[node];

  float acc[8] = {0.f,0.f,0.f,0.f,0.f,0.f,0.f,0.f};

  for (; e + 4 <= e1; e += 4){
    unsigned u0 = ec[e], u1 = ec[e+1], u2 = ec[e+2], u3 = ec[e+3];
    int c0 = u0 & 0x1FFFF, c1 = u1 & 0x1FFFF, c2 = u2 & 0x1FFFF, c3 = u3 & 0x1FFFF;
    uint2 p0 = *(const uint2*)(V8 + (((size_t)c0) << 7) + fb);
    uint2 p1 = *(const uint2*)(V8 + (((size_t)c1) << 7) + fb);
    uint2 p2 = *(const uint2*)(V8 + (((size_t)c2) << 7) + fb);
    uint2 p3 = *(const uint2*)(V8 + (((size_t)c3) << 7) + fb);
    float wn0 = dr * edgeWpos(u0) * dinv[c0];
    float wn1 = dr * edgeWpos(u1) * dinv[c1];
    float wn2 = dr * edgeWpos(u2) * dinv[c2];
    float wn3 = dr * edgeWpos(u3) * dinv[c3];
    if (s == 0){
      ec[e]   = packEdge(c0, wn0);
      ec[e+1] = packEdge(c1, wn1);
      ec[e+2] = packEdge(c2, wn2);
      ec[e+3] = packEdge(c3, wn3);
    }
    acc4_fp8(acc, p0.x, -wn0); acc4_fp8(acc+4, p0.y, -wn0);
    acc4_fp8(acc, p1.x, -wn1); acc4_fp8(acc+4, p1.y, -wn1);
    acc4_fp8(acc, p2.x, -wn2); acc4_fp8(acc+4, p2.y, -wn2);
    acc4_fp8(acc, p3.x, -wn3); acc4_fp8(acc+4, p3.y, -wn3);
  }
  for (; e < e1; ++e){
    unsigned u = ec[e];
    int c = u & 0x1FFFF;
    uint2 p = *(const uint2*)(V8 + (((size_t)c) << 7) + fb);
    float wn = dr * edgeWpos(u) * dinv[c];
    if (s == 0) ec[e] = packEdge(c, wn);
    acc4_fp8(acc, p.x, -wn); acc4_fp8(acc+4, p.y, -wn);
  }

  uint2 o8;
  o8.x = cvt2fp8(acc[0], acc[1]) | (cvt2fp8(acc[2], acc[3]) << 16);
  o8.y = cvt2fp8(acc[4], acc[5]) | (cvt2fp8(acc[6], acc[7]) << 16);
  *(uint2*)(out8 + (((size_t)node) << 7) + fb) = o8;
}

// ---------------- SpMM fp8: fp8 in / fp8 out, 8-deep unroll (r17-proven) ----------
__global__ __launch_bounds__(256) void k_spmm8(
    const int* __restrict__ rowptr, const unsigned* __restrict__ ec,
    const uint8_t* __restrict__ V8, const uint8_t* __restrict__ sub8, float alpha,
    uint8_t* __restrict__ out8, int n)
{
  const int lane = threadIdx.x & 63;
  const int wave = threadIdx.x >> 6;
  const int g = lane >> 4;
  const int s = lane & 15;
  const int node = blockIdx.x*16 + wave*4 + g;
  if (node >= n) return;

  int e = rowptr[node];
  const int e1 = rowptr[node+1];
  const int fb = s << 3;

  float acc[8] = {0.f,0.f,0.f,0.f,0.f,0.f,0.f,0.f};

  for (; e + 8 <= e1; e += 8){
    unsigned u0 = ec[e],   u1 = ec[e+1], u2 = ec[e+2], u3 = ec[e+3];
    unsigned u4 = ec[e+4], u5 = ec[e+5], u6 = ec[e+6], u7 = ec[e+7];
    uint2 p0 = *(const uint2*)(V8 + (((size_t)(u0 & 0x1FFFF)) << 7) + fb);
    uint2 p1 = *(const uint2*)(V8 + (((size_t)(u1 & 0x1FFFF)) << 7) + fb);
    uint2 p2 = *(const uint2*)(V8 + (((size_t)(u2 & 0x1FFFF)) << 7) + fb);
    uint2 p3 = *(const uint2*)(V8 + (((size_t)(u3 & 0x1FFFF)) << 7) + fb);
    uint2 p4 = *(const uint2*)(V8 + (((size_t)(u4 & 0x1FFFF)) << 7) + fb);
    uint2 p5 = *(const uint2*)(V8 + (((size_t)(u5 & 0x1FFFF)) << 7) + fb);
    uint2 p6 = *(const uint2*)(V8 + (((size_t)(u6 & 0x1FFFF)) << 7) + fb);
    uint2 p7 = *(const uint2*)(V8 + (((size_t)(u7 & 0x1FFFF)) << 7) + fb);
    float w0 = edgeWneg(u0), w1 = edgeWneg(u1), w2 = edgeWneg(u2), w3 = edgeWneg(u3);
    float w4 = edgeWneg(u4), w5 = edgeWneg(u5), w6 = edgeWneg(u6), w7 = edgeWneg(u7);
    acc4_fp8(acc,   p0.x, w0); acc4_fp8(acc+4, p0.y, w0);
    acc4_fp8(acc,   p1.x, w1); acc4_fp8(acc+4, p1.y, w1);
    acc4_fp8(acc,   p2.x, w2); acc4_fp8(acc+4, p2.y, w2);
    acc4_fp8(acc,   p3.x, w3); acc4_fp8(acc+4, p3.y, w3);
    acc4_fp8(acc,   p4.x, w4); acc4_fp8(acc+4, p4.y, w4);
    acc4_fp8(acc,   p5.x, w5); acc4_fp8(acc+4, p5.y, w5);
    acc4_fp8(acc,   p6.x, w6); acc4_fp8(acc+4, p6.y, w6);
    acc4_fp8(acc,   p7.x, w7); acc4_fp8(acc+4, p7.y, w7);
  }
  for (; e + 4 <= e1; e += 4){
    unsigned u0 = ec[e], u1 = ec[e+1], u2 = ec[e+2], u3 = ec[e+3];
    uint2 p0 = *(const uint2*)(V8 + (((size_t)(u0 & 0x1FFFF)) << 7) + fb);
    uint2 p1 = *(const uint2*)(V8 + (((size_t)(u1 & 0x1FFFF)) << 7) + fb);
    uint2 p2 = *(const uint2*)(V8 + (((size_t)(u2 & 0x1FFFF)) << 7) + fb);
    uint2 p3 = *(const uint2*)(V8 + (((size_t)(u3 & 0x1FFFF)) << 7) + fb);
    float w0 = edgeWneg(u0), w1 = edgeWneg(u1), w2 = edgeWneg(u2), w3 = edgeWneg(u3);
    acc4_fp8(acc,   p0.x, w0); acc4_fp8(acc+4, p0.y, w0);
    acc4_fp8(acc,   p1.x, w1); acc4_fp8(acc+4, p1.y, w1);
    acc4_fp8(acc,   p2.x, w2); acc4_fp8(acc+4, p2.y, w2);
    acc4_fp8(acc,   p3.x, w3); acc4_fp8(acc+4, p3.y, w3);
  }
  for (; e < e1; ++e){
    unsigned u = ec[e];
    uint2 p = *(const uint2*)(V8 + (((size_t)(u & 0x1FFFF)) << 7) + fb);
    float w = edgeWneg(u);
    acc4_fp8(acc, p.x, w); acc4_fp8(acc+4, p.y, w);
  }

  float r[8];
  #pragma unroll
  for (int i = 0; i < 8; ++i) r[i] = alpha*acc[i];
  if (sub8){
    uint2 sv = *(const uint2*)(sub8 + (((size_t)node) << 7) + fb);
    float sd[8];
    dec4_fp8(sd,     sv.x);
    dec4_fp8(sd + 4, sv.y);
    #pragma unroll
    for (int i = 0; i < 8; ++i) r[i] -= sd[i];
  }
  uint2 o8;
  o8.x = cvt2fp8(r[0], r[1]) | (cvt2fp8(r[2], r[3]) << 16);
  o8.y = cvt2fp8(r[4], r[5]) | (cvt2fp8(r[6], r[7]) << 16);
  *(uint2*)(out8 + (((size_t)node) << 7) + fb) = o8;
}

// ---------------- launch ----------------

extern "C" void kernel_launch(void* const* d_in, const int* in_sizes, int n_in,
                              void* d_out, int out_size, void* d_ws, size_t ws_size,
                              hipStream_t stream)
{
  const float* x   = (const float*)d_in[0];
  const int*   ei  = (const int*)d_in[1];
  const float* ew  = (const float*)d_in[2];
  const float* W1  = (const float*)d_in[3];
  const float* b1  = (const float*)d_in[4];
  const float* c1W = (const float*)d_in[5];
  const float* c1b = (const float*)d_in[6];
  const float* c2W = (const float*)d_in[7];
  const float* c2b = (const float*)d_in[8];
  const float* W2  = (const float*)d_in[9];
  const float* b2  = (const float*)d_in[10];
  float* out = (float*)d_out;

  const int n = NN, e = NE;
  const int* row = ei;
  const int* col = ei + e;

  char* ws = (char*)d_ws;
  size_t off = 0;
  auto carve = [&](size_t bytes)->void*{
    void* p = ws + off;
    off += (bytes + 255) & ~(size_t)255;
    return p;
  };
  uint8_t* q8a = (uint8_t*)carve((size_t)n*128);     // h0 fp8
  uint8_t* B8  = (uint8_t*)carve((size_t)n*128);     // Tx1 fp8
  uint8_t* C8  = (uint8_t*)carve((size_t)n*128);     // Tx2 fp8
  uint8_t* D8  = (uint8_t*)carve((size_t)n*128);     // h1 fp8 (aliases temp)
  float*  dinv = (float*)carve((size_t)n*4);
  int*    rowptr = (int*)carve((size_t)(n+1)*4);
  unsigned* ec = (unsigned*)carve((size_t)e*4);
  int*    bincnt = (int*)carve((size_t)NBIN*4);
  int*    binptr = (int*)carve((size_t)(NBIN+1)*4);
  int*    blockbase = (int*)carve((size_t)NBB*NBIN*4);   // 1.22MB
  bf16_t*  Wt1  = (bf16_t*)carve(2*128*128*2);
  uint8_t* W8c1 = (uint8_t*)carve(3*128*128);
  uint8_t* W8c2 = (uint8_t*)carve(3*128*128);
  // temp edge buffer (12.8MB) aliases D8: temp lives [binB(gemm1_fused), binC];
  // D8 first written by conv1's k_gemm8 (after binC).
  int2* temp = (int2*)D8;
  (void)ws_size; (void)in_sizes; (void)n_in; (void)out_size;

  const int NB_S = (n + 15)/16;     // 6250

  hipMemsetAsync(bincnt, 0, (size_t)NBIN*4, stream);
  // binA histogram + Wt1 pack
  k_binA_tw<<<NBB + NB_TW1,256,0,stream>>>(row, bincnt, blockbase, W1, Wt1);
  k_scanbins<<<1,256,0,stream>>>(bincnt, binptr, rowptr);
  // fused: h0 = relu(x@W1+b1) -> q8a  AND  binB scatter  AND  conv-weight fp8 pack
  k_gemm1_fused<<<NB_G + NBB + NB_TW8,256,0,stream>>>(
      x, Wt1, b1, q8a, n, row, col, ew, binptr, blockbase, temp, c1W, c2W, W8c1, W8c2);
  k_binC<<<NBIN,256,0,stream>>>(temp, binptr, ec, rowptr, dinv, n);

  // conv1: Tx1 = Lx(h0) -> B8 (normalizes ec in-flight) ; Tx2 = 2*Lx(Tx1) - h0 -> C8
  k_spmm8n<<<NB_S,256,0,stream>>>(rowptr, ec, dinv, q8a, B8, n);
  k_spmm8<<<NB_S,256,0,stream>>>(rowptr, ec, B8, q8a, 2.f, C8, n);
  // h1 = relu([h0|Tx1|Tx2] @ Wc1 + b) -> D8 (fp8)
  k_gemm8<<<NB_G,256,0,stream>>>(q8a, B8, C8, W8c1, c1b, D8, nullptr, nullptr, nullptr, n);
  // conv2
  k_spmm8<<<NB_S,256,0,stream>>>(rowptr, ec, D8, nullptr, 1.f, B8, n);
  k_spmm8<<<NB_S,256,0,stream>>>(rowptr, ec, B8, D8, 2.f, C8, n);
  // h2 GEMM + fused head -> out (softmax probabilities)
  k_gemm8<<<NB_G,256,0,stream>>>(D8, B8, C8, W8c2, c2b, nullptr, W2, b2, out, n);
}

// Round 21
// 292.592 us; speedup vs baseline: 1.4855x; 1.0090x over previous
//
#include <hip/hip_runtime.h>
#include <hip/hip_bf16.h>
#include <stdint.h>

typedef __bf16 bf16_t;
typedef __bf16 bf16x8 __attribute__((ext_vector_type(8)));
typedef float f32x4 __attribute__((ext_vector_type(4)));
typedef float f32x2 __attribute__((ext_vector_type(2)));
typedef float floatv4 __attribute__((ext_vector_type(4)));

// async 16B global->LDS DMA
static __device__ __forceinline__ void gload16(const void* g, void* l){
  __builtin_amdgcn_global_load_lds((const __attribute__((address_space(1))) void*)g,
                                   (__attribute__((address_space(3))) void*)l, 16, 0, 0);
}
// fp8 e4m3 (OCP) HW conversions
static __device__ __forceinline__ void acc4_fp8(float* a, unsigned w, float wt){
  f32x2 lo, hi;
  unsigned wh = w >> 16;
  asm("v_cvt_pk_f32_fp8 %0, %1" : "=v"(lo) : "v"(w));
  asm("v_cvt_pk_f32_fp8 %0, %1" : "=v"(hi) : "v"(wh));
  a[0] += wt*lo[0]; a[1] += wt*lo[1]; a[2] += wt*hi[0]; a[3] += wt*hi[1];
}
static __device__ __forceinline__ unsigned cvt2fp8(float a, float b){
  unsigned r;
  asm("v_cvt_pk_fp8_f32 %0, %1, %2" : "=v"(r) : "v"(a), "v"(b));
  return r & 0xffffu;
}
static __device__ __forceinline__ uint8_t cvt1fp8(float a){
  unsigned r;
  asm("v_cvt_pk_fp8_f32 %0, %1, %1" : "=v"(r) : "v"(a));
  return (uint8_t)r;
}
// packed edge: bits[16:0]=col, bits[31:17]=weight f32 bits[30:16] (sign implicit)
static __device__ __forceinline__ unsigned packEdge(int col, float w_pos){
  unsigned b = __float_as_uint(w_pos) + 0x8000u;
  return ((b >> 16) << 17) | (unsigned)col;
}
static __device__ __forceinline__ float edgeWpos(unsigned u){
  return __uint_as_float((u >> 17) << 16);
}
static __device__ __forceinline__ float edgeWneg(unsigned u){
  return __uint_as_float(0x80000000u | ((u >> 17) << 16));
}

constexpr int NN = 100000;
constexpr int NE = 1600000;
constexpr int NB_G  = (NN + 127)/128;    // 782
constexpr int NBIN = (NN + 127)/128;     // 782
constexpr int EPB  = 4096;
constexpr int NBB  = (NE + EPB - 1)/EPB; // 391
constexpr int MAXBE = 3072;
constexpr int NB_TW8 = (2*3*128*128)/256; // 384 conv-weight pack blocks
constexpr int NB_TW1 = (2*128*128)/256;   // 128 Wt1 pack blocks

// ---------------- binA + Wt1 pack (fused) ----------------
__global__ __launch_bounds__(256) void k_binA_tw(const int* __restrict__ row,
                                                 int* __restrict__ bincnt,
                                                 int* __restrict__ blockbase,
                                                 const float* __restrict__ W1,
                                                 bf16_t* __restrict__ Wt1){
  __shared__ int h[NBIN];
  const int tid = threadIdx.x;
  if (blockIdx.x >= NBB){             // --- Wt1 bf16 [chunk][col][k] pack ---
    int idx = (blockIdx.x - NBB)*256 + tid;   // 0..32767
    int c = idx >> 14, r = (idx >> 7) & 127, j = idx & 127;
    Wt1[(c << 14) + (j << 7) + r] = (bf16_t)W1[idx];
    return;
  }
  for (int b = tid; b < NBIN; b += 256) h[b] = 0;
  __syncthreads();
  int base = blockIdx.x * EPB;
  for (int k = 0; k < EPB; k += 256){
    int i = base + k + tid;
    if (i < NE) atomicAdd(&h[row[i] >> 7], 1);
  }
  __syncthreads();
  for (int b = tid; b < NBIN; b += 256){
    int c = h[b];
    blockbase[blockIdx.x * NBIN + b] = c ? atomicAdd(&bincnt[b], c) : 0;
  }
}

__global__ __launch_bounds__(256) void k_scanbins(const int* __restrict__ bincnt,
                                                  int* __restrict__ binptr,
                                                  int* __restrict__ rowptr){
  __shared__ int s[256];
  int t = threadIdx.x;
  int b0 = t*4;
  int c[4]; int tot = 0;
  #pragma unroll
  for (int j = 0; j < 4; ++j){
    int b = b0 + j;
    c[j] = (b < NBIN) ? bincnt[b] : 0;
    tot += c[j];
  }
  s[t] = tot;
  __syncthreads();
  for (int off = 1; off < 256; off <<= 1){
    int v = (t >= off) ? s[t - off] : 0;
    __syncthreads();
    s[t] += v;
    __syncthreads();
  }
  int ex = s[t] - tot;
  #pragma unroll
  for (int j = 0; j < 4; ++j){
    int b = b0 + j;
    if (b < NBIN) binptr[b] = ex;
    ex += c[j];
  }
  if (t == 255){ binptr[NBIN] = ex; rowptr[NN] = ex; }
}

__global__ __launch_bounds__(256) void k_binC(const int2* __restrict__ temp,
                                              const int* __restrict__ binptr,
                                              unsigned* __restrict__ ec,
                                              int* __restrict__ rowptr,
                                              float* __restrict__ dinv, int n){
  __shared__ int2 sbuf[MAXBE];
  __shared__ int cnt[128];
  __shared__ int scan[128];
  __shared__ int estart[128];
  const int b = blockIdx.x;
  const int e0 = binptr[b];
  int nb = binptr[b+1] - e0; if (nb > MAXBE) nb = MAXBE;
  const int t = threadIdx.x;
  if (t < 128) cnt[t] = 0;
  __syncthreads();
  for (int k = t; k < nb; k += 256)
    atomicAdd(&cnt[(temp[e0+k].x >> 17) & 127], 1);
  __syncthreads();
  if (t < 128) scan[t] = cnt[t];
  __syncthreads();
  for (int off = 1; off < 128; off <<= 1){
    int v = (t < 128 && t >= off) ? scan[t - off] : 0;
    __syncthreads();
    if (t < 128) scan[t] += v;
    __syncthreads();
  }
  if (t < 128){ estart[t] = scan[t] - cnt[t]; cnt[t] = 0; }
  __syncthreads();
  for (int k = t; k < nb; k += 256){
    int2 q = temp[e0+k];
    int rl = (q.x >> 17) & 127;
    int rank = atomicAdd(&cnt[rl], 1);
    sbuf[estart[rl] + rank] = q;
  }
  __syncthreads();
  for (int k = t; k < nb; k += 256){
    int2 q = sbuf[k];
    ec[e0 + k] = packEdge(q.x & 0x1FFFF, __int_as_float(q.y));
  }
  if (t < 128){
    int gid = b*128 + t;
    if (gid < n){
      rowptr[gid] = e0 + estart[t];
      float s = 0.f;
      int s0 = estart[t], c = cnt[t];
      for (int j = 0; j < c; ++j) s += __int_as_float(sbuf[s0+j].y);
      dinv[gid] = (s > 0.f) ? rsqrtf(s) : 0.f;
    }
  }
}

// ---------------- FUSED: gemm1 (782) + binB coalesced (391) + W8 packs (384) ------
// W8 packs apply the Chebyshev re-association: chunk0 = W0-W2, chunk1 = W1,
// chunk2 = 2*W2 (so spmm passes 2/4 are pure gathers, no sub input).
// binB counting-sorts its 4096 edges in LDS and writes temp in per-bin RUNS
// (coalesced ~40B) instead of 1.6M scattered 8B sectors.
__global__ __launch_bounds__(256) void k_gemm1_fused(
    const float* __restrict__ x, const bf16_t* __restrict__ Wt, const float* __restrict__ bias,
    uint8_t* __restrict__ out8, int M,
    const int* __restrict__ row, const int* __restrict__ col, const float* __restrict__ w,
    const int* __restrict__ binptr, const int* __restrict__ blockbase, int2* __restrict__ temp,
    const float* __restrict__ c1W, const float* __restrict__ c2W,
    uint8_t* __restrict__ W8c1, uint8_t* __restrict__ W8c2)
{
  __shared__ char smem[40964];
  const int tid = threadIdx.x;

  if (blockIdx.x >= NB_G + NBB){                 // --- conv-weight fp8 pack ---
    int base = (blockIdx.x - NB_G - NBB)*256 + tid;   // 0..98303
    int m = base / 49152;
    int local = base - m*49152;
    const float* src = m ? c2W : c1W;
    uint8_t* dst = m ? W8c2 : W8c1;
    int c = local >> 14, r = (local >> 7) & 127, j = local & 127;
    float v = src[local];
    if (c == 0) v -= src[2*16384 + local];   // W0 - W2
    if (c == 2) v *= 2.f;                    // 2*W2
    dst[(c << 14) + (j << 7) + r] = cvt1fp8(v);
    return;
  }
  if (blockIdx.x >= NB_G){                       // --- binB: LDS counting sort ---
    int2* stage = (int2*)smem;                    // 4096 * 8B = 32768
    int*  base_ = (int*)(smem + 32768);           // NBIN+1
    int*  rank_ = (int*)(smem + 35904);           // NBIN
    int*  saux  = (int*)(smem + 39040);           // 256
    const int bb = blockIdx.x - NB_G;
    const int ebase = bb * EPB;
    for (int b = tid; b < NBIN; b += 256){ base_[b] = 0; rank_[b] = 0; }
    __syncthreads();
    for (int k = 0; k < EPB; k += 256){
      int i = ebase + k + tid;
      if (i < NE) atomicAdd(&base_[row[i] >> 7], 1);
    }
    __syncthreads();
    // exclusive scan over NBIN bins (4 per thread)
    int b0 = tid*4;
    int c[4]; int tot = 0;
    #pragma unroll
    for (int j = 0; j < 4; ++j){
      int b = b0 + j;
      c[j] = (b < NBIN) ? base_[b] : 0;
      tot += c[j];
    }
    saux[tid] = tot;
    __syncthreads();
    for (int off = 1; off < 256; off <<= 1){
      int v = (tid >= off) ? saux[tid - off] : 0;
      __syncthreads();
      saux[tid] += v;
      __syncthreads();
    }
    int ex = saux[tid] - tot;
    #pragma unroll
    for (int j = 0; j < 4; ++j){
      int b = b0 + j;
      if (b < NBIN) base_[b] = ex;
      ex += c[j];
    }
    if (tid == 255) base_[NBIN] = ex;
    __syncthreads();
    // rank-scatter into staging
    for (int k = 0; k < EPB; k += 256){
      int i = ebase + k + tid;
      if (i < NE){
        int r = row[i];
        int b = r >> 7;
        int rk = atomicAdd(&rank_[b], 1);
        stage[base_[b] + rk] = make_int2(col[i] | ((r & 127) << 17), __float_as_int(w[i]));
      }
    }
    __syncthreads();
    // write per-bin runs (coalesced-ish consecutive stores)
    for (int b = tid; b < NBIN; b += 256){
      int s0 = base_[b];
      int cnt = base_[b+1] - s0;
      if (cnt){
        int dst = binptr[b] + blockbase[bb * NBIN + b];
        for (int r = 0; r < cnt; ++r) temp[dst + r] = stage[s0 + r];
      }
    }
    return;
  }

  // --- gemm1: BM=128, async dbuf, fp8-only output ---
  uint8_t (*lds)[16384] = (uint8_t(*)[16384])smem;
  const int wave = tid >> 6, lane = tid & 63;
  const int wm = wave >> 1, wn = wave & 1;
  const int l15 = lane & 15, lq = lane >> 4;
  const int blockRow = blockIdx.x * 128;
  const int strow = tid >> 3;
  const int scell = tid & 7;

  f32x4 acc[4][4];
  #pragma unroll
  for (int a = 0; a < 4; ++a)
    #pragma unroll
    for (int b = 0; b < 4; ++b) acc[a][b] = f32x4{0.f,0.f,0.f,0.f};

  #pragma unroll
  for (int j = 0; j < 4; ++j){
    int r = j*32 + strow;
    int gr = blockRow + r; if (gr > M-1) gr = M-1;
    gload16((const char*)x + (size_t)gr*1024 + ((scell ^ (r&7)) << 4),
            &lds[0][j*4096 + tid*16]);
  }

  #pragma unroll
  for (int s = 0; s < 8; ++s){
    if (s < 7){
      #pragma unroll
      for (int j = 0; j < 4; ++j){
        int r = j*32 + strow;
        int gr = blockRow + r; if (gr > M-1) gr = M-1;
        gload16((const char*)x + (size_t)gr*1024 + (s+1)*128 + ((scell ^ (r&7)) << 4),
                &lds[(s+1)&1][j*4096 + tid*16]);
      }
    }
    __syncthreads();
    const uint8_t* buf = lds[s&1];
    bf16x8 af[4], bfr[4];
    #pragma unroll
    for (int fm = 0; fm < 4; ++fm){
      int r = wm*64 + fm*16 + l15;
      floatv4 v0 = *(const floatv4*)(buf + r*128 + (((lq*2    ) ^ (r&7)) << 4));
      floatv4 v1 = *(const floatv4*)(buf + r*128 + (((lq*2 + 1) ^ (r&7)) << 4));
      bf16x8 t;
      t[0]=(bf16_t)v0[0]; t[1]=(bf16_t)v0[1]; t[2]=(bf16_t)v0[2]; t[3]=(bf16_t)v0[3];
      t[4]=(bf16_t)v1[0]; t[5]=(bf16_t)v1[1]; t[6]=(bf16_t)v1[2]; t[7]=(bf16_t)v1[3];
      af[fm] = t;
    }
    #pragma unroll
    for (int fn = 0; fn < 4; ++fn)
      bfr[fn] = *(const bf16x8*)(Wt + ((size_t)(((s>>2) << 7) + wn*64 + fn*16 + l15) << 7) + (s&3)*32 + lq*8);
    #pragma unroll
    for (int fm = 0; fm < 4; ++fm)
      #pragma unroll
      for (int fn = 0; fn < 4; ++fn)
        acc[fm][fn] = __builtin_amdgcn_mfma_f32_16x16x32_bf16(af[fm], bfr[fn], acc[fm][fn], 0, 0, 0);
    __syncthreads();
  }
  #pragma unroll
  for (int fm = 0; fm < 4; ++fm){
    #pragma unroll
    for (int j = 0; j < 4; ++j){
      int growo = blockRow + wm*64 + fm*16 + lq*4 + j;
      if (growo < M){
        #pragma unroll
        for (int fn = 0; fn < 4; ++fn){
          int c = wn*64 + fn*16 + l15;
          float v = fmaxf(acc[fm][fn][j] + bias[c], 0.f);
          out8[((size_t)growo << 7) + c] = cvt1fp8(v);
        }
      }
    }
  }
}

// ---------------- conv GEMM fp8 (+ optional fused head, shfl reduce) --------------
__global__ __launch_bounds__(256) void k_gemm8(
    const uint8_t* __restrict__ a0, const uint8_t* __restrict__ a1, const uint8_t* __restrict__ a2,
    const uint8_t* __restrict__ Wt8, const float* __restrict__ bias,
    uint8_t* __restrict__ out8,
    const float* __restrict__ W2h, const float* __restrict__ b2h, float* __restrict__ outh,
    int M)
{
  __shared__ uint8_t lds[2][8192];
  __shared__ float logits[128][2][2];
  const int tid = threadIdx.x;
  const int wave = tid >> 6, lane = tid & 63;
  const int wm = wave >> 1, wn = wave & 1;
  const int l15 = lane & 15, lq = lane >> 4;
  const int blockRow = blockIdx.x * 128;

  f32x4 acc[4][4];
  #pragma unroll
  for (int a = 0; a < 4; ++a)
    #pragma unroll
    for (int b = 0; b < 4; ++b) acc[a][b] = f32x4{0.f,0.f,0.f,0.f};

  #pragma unroll
  for (int j = 0; j < 2; ++j){
    int flat = j*256 + tid;
    int r = flat >> 2, cell = flat & 3;
    int gr = blockRow + r; if (gr > M-1) gr = M-1;
    gload16(a0 + (size_t)gr*128 + ((cell ^ ((r>>1)&3)) << 4), &lds[0][flat << 4]);
  }

  #pragma unroll
  for (int s = 0; s < 6; ++s){
    if (s < 5){
      const int sn = s + 1;
      const uint8_t* srcn = (sn>>1) == 0 ? a0 : ((sn>>1) == 1 ? a1 : a2);
      #pragma unroll
      for (int j = 0; j < 2; ++j){
        int flat = j*256 + tid;
        int r = flat >> 2, cell = flat & 3;
        int gr = blockRow + r; if (gr > M-1) gr = M-1;
        gload16(srcn + (size_t)gr*128 + (sn&1)*64 + ((cell ^ ((r>>1)&3)) << 4),
                &lds[sn&1][flat << 4]);
      }
    }
    __syncthreads();
    const uint8_t* buf = lds[s&1];
    #pragma unroll
    for (int kk32 = 0; kk32 < 2; ++kk32){
      long af[4], bfr[4];
      #pragma unroll
      for (int fm = 0; fm < 4; ++fm){
        int r = wm*64 + fm*16 + l15;
        int cell = kk32*2 + (lq >> 1);
        af[fm] = *(const long*)(buf + r*64 + ((cell ^ ((r>>1)&3)) << 4) + (lq & 1)*8);
      }
      #pragma unroll
      for (int fn = 0; fn < 4; ++fn)
        bfr[fn] = *(const long*)(Wt8 + ((size_t)(((s>>1) << 7) + wn*64 + fn*16 + l15) << 7)
                                 + (s&1)*64 + kk32*32 + lq*8);
      #pragma unroll
      for (int fm = 0; fm < 4; ++fm)
        #pragma unroll
        for (int fn = 0; fn < 4; ++fn)
          acc[fm][fn] = __builtin_amdgcn_mfma_f32_16x16x32_fp8_fp8(af[fm], bfr[fn], acc[fm][fn], 0, 0, 0);
    }
    __syncthreads();
  }

  if (outh){
    float w2l[8];
    #pragma unroll
    for (int fn = 0; fn < 4; ++fn){
      int c = wn*64 + fn*16 + l15;
      w2l[fn*2]   = W2h[c*2];
      w2l[fn*2+1] = W2h[c*2+1];
    }
    #pragma unroll
    for (int fm = 0; fm < 4; ++fm){
      #pragma unroll
      for (int j = 0; j < 4; ++j){
        int r = wm*64 + fm*16 + lq*4 + j;
        float p0 = 0.f, p1 = 0.f;
        #pragma unroll
        for (int fn = 0; fn < 4; ++fn){
          float v = fmaxf(acc[fm][fn][j] + bias[wn*64 + fn*16 + l15], 0.f);
          p0 += v*w2l[fn*2];
          p1 += v*w2l[fn*2+1];
        }
        #pragma unroll
        for (int m = 1; m < 16; m <<= 1){
          p0 += __shfl_xor(p0, m, 64);
          p1 += __shfl_xor(p1, m, 64);
        }
        if (l15 == 0){
          logits[r][wn][0] = p0;
          logits[r][wn][1] = p1;
        }
      }
    }
    __syncthreads();
    if (tid < 128){
      int node = blockRow + tid;
      if (node < M){
        float l0 = logits[tid][0][0] + logits[tid][1][0] + b2h[0];
        float l1 = logits[tid][0][1] + logits[tid][1][1] + b2h[1];
        float mx = fmaxf(l0, l1);
        float e0 = __expf(l0 - mx), e1 = __expf(l1 - mx);
        float inv = 1.f / (e0 + e1);
        *(float2*)(outh + (size_t)node*2) = make_float2(e0*inv, e1*inv);
      }
    }
  } else {
    #pragma unroll
    for (int fm = 0; fm < 4; ++fm){
      #pragma unroll
      for (int j = 0; j < 4; ++j){
        int growo = blockRow + wm*64 + fm*16 + lq*4 + j;
        if (growo < M){
          #pragma unroll
          for (int fn = 0; fn < 4; ++fn){
            int c = wn*64 + fn*16 + l15;
            float v = fmaxf(acc[fm][fn][j] + bias[c], 0.f);
            out8[((size_t)growo << 7) + c] = cvt1fp8(v);
          }
        }
      }
    }
  }
}

// ---------------- SpMM fp8 + on-the-fly normalization (conv1 pass 1) --------------
__global__ __launch_bounds__(256) void k_spmm8n(
    const int* __restrict__ rowptr, unsigned* __restrict__ ec,
    const float* __restrict__ dinv,
    const uint8_t* __restrict__ V8, uint8_t* __restrict__ out8, int n)
{
  const int lane = threadIdx.x & 63;
  const int wave = threadIdx.x >> 6;
  const int g = lane >> 4;
  const int s = lane & 15;
  const int node = blockIdx.x*16 + wave*4 + g;
  if (node >= n) return;

  int e = rowptr[node];
  const int e1 = rowptr[node+1];
  const int fb = s << 3;
  const float dr = dinv[node];

  float acc[8] = {0.f,0.f,0.f,0.f,0.f,0.f,0.f,0.f};

  for (; e + 4 <= e1; e += 4){
    unsigned u0 = ec[e], u1 = ec[e+1], u2 = ec[e+2], u3 = ec[e+3];
    int c0 = u0 & 0x1FFFF, c1 = u1 & 0x1FFFF, c2 = u2 & 0x1FFFF, c3 = u3 & 0x1FFFF;
    uint2 p0 = *(const uint2*)(V8 + (((size_t)c0) << 7) + fb);
    uint2 p1 = *(const uint2*)(V8 + (((size_t)c1) << 7) + fb);
    uint2 p2 = *(const uint2*)(V8 + (((size_t)c2) << 7) + fb);
    uint2 p3 = *(const uint2*)(V8 + (((size_t)c3) << 7) + fb);
    float wn0 = dr * edgeWpos(u0) * dinv[c0];
    float wn1 = dr * edgeWpos(u1) * dinv[c1];
    float wn2 = dr * edgeWpos(u2) * dinv[c2];
    float wn3 = dr * edgeWpos(u3) * dinv[c3];
    if (s == 0){
      ec[e]   = packEdge(c0, wn0);
      ec[e+1] = packEdge(c1, wn1);
      ec[e+2] = packEdge(c2, wn2);
      ec[e+3] = packEdge(c3, wn3);
    }
    acc4_fp8(acc, p0.x, -wn0); acc4_fp8(acc+4, p0.y, -wn0);
    acc4_fp8(acc, p1.x, -wn1); acc4_fp8(acc+4, p1.y, -wn1);
    acc4_fp8(acc, p2.x, -wn2); acc4_fp8(acc+4, p2.y, -wn2);
    acc4_fp8(acc, p3.x, -wn3); acc4_fp8(acc+4, p3.y, -wn3);
  }
  for (; e < e1; ++e){
    unsigned u = ec[e];
    int c = u & 0x1FFFF;
    uint2 p = *(const uint2*)(V8 + (((size_t)c) << 7) + fb);
    float wn = dr * edgeWpos(u) * dinv[c];
    if (s == 0) ec[e] = packEdge(c, wn);
    acc4_fp8(acc, p.x, -wn); acc4_fp8(acc+4, p.y, -wn);
  }

  uint2 o8;
  o8.x = cvt2fp8(acc[0], acc[1]) | (cvt2fp8(acc[2], acc[3]) << 16);
  o8.y = cvt2fp8(acc[4], acc[5]) | (cvt2fp8(acc[6], acc[7]) << 16);
  *(uint2*)(out8 + (((size_t)node) << 7) + fb) = o8;
}

// ---------------- SpMM fp8: pure gather (no sub — Chebyshev re-associated) --------
__global__ __launch_bounds__(256) void k_spmm8(
    const int* __restrict__ rowptr, const unsigned* __restrict__ ec,
    const uint8_t* __restrict__ V8, uint8_t* __restrict__ out8, int n)
{
  const int lane = threadIdx.x & 63;
  const int wave = threadIdx.x >> 6;
  const int g = lane >> 4;
  const int s = lane & 15;
  const int node = blockIdx.x*16 + wave*4 + g;
  if (node >= n) return;

  int e = rowptr[node];
  const int e1 = rowptr[node+1];
  const int fb = s << 3;

  float acc[8] = {0.f,0.f,0.f,0.f,0.f,0.f,0.f,0.f};

  for (; e + 8 <= e1; e += 8){
    unsigned u0 = ec[e],   u1 = ec[e+1], u2 = ec[e+2], u3 = ec[e+3];
    unsigned u4 = ec[e+4], u5 = ec[e+5], u6 = ec[e+6], u7 = ec[e+7];
    uint2 p0 = *(const uint2*)(V8 + (((size_t)(u0 & 0x1FFFF)) << 7) + fb);
    uint2 p1 = *(const uint2*)(V8 + (((size_t)(u1 & 0x1FFFF)) << 7) + fb);
    uint2 p2 = *(const uint2*)(V8 + (((size_t)(u2 & 0x1FFFF)) << 7) + fb);
    uint2 p3 = *(const uint2*)(V8 + (((size_t)(u3 & 0x1FFFF)) << 7) + fb);
    uint2 p4 = *(const uint2*)(V8 + (((size_t)(u4 & 0x1FFFF)) << 7) + fb);
    uint2 p5 = *(const uint2*)(V8 + (((size_t)(u5 & 0x1FFFF)) << 7) + fb);
    uint2 p6 = *(const uint2*)(V8 + (((size_t)(u6 & 0x1FFFF)) << 7) + fb);
    uint2 p7 = *(const uint2*)(V8 + (((size_t)(u7 & 0x1FFFF)) << 7) + fb);
    float w0 = edgeWneg(u0), w1 = edgeWneg(u1), w2 = edgeWneg(u2), w3 = edgeWneg(u3);
    float w4 = edgeWneg(u4), w5 = edgeWneg(u5), w6 = edgeWneg(u6), w7 = edgeWneg(u7);
    acc4_fp8(acc,   p0.x, w0); acc4_fp8(acc+4, p0.y, w0);
    acc4_fp8(acc,   p1.x, w1); acc4_fp8(acc+4, p1.y, w1);
    acc4_fp8(acc,   p2.x, w2); acc4_fp8(acc+4, p2.y, w2);
    acc4_fp8(acc,   p3.x, w3); acc4_fp8(acc+4, p3.y, w3);
    acc4_fp8(acc,   p4.x, w4); acc4_fp8(acc+4, p4.y, w4);
    acc4_fp8(acc,   p5.x, w5); acc4_fp8(acc+4, p5.y, w5);
    acc4_fp8(acc,   p6.x, w6); acc4_fp8(acc+4, p6.y, w6);
    acc4_fp8(acc,   p7.x, w7); acc4_fp8(acc+4, p7.y, w7);
  }
  for (; e + 4 <= e1; e += 4){
    unsigned u0 = ec[e], u1 = ec[e+1], u2 = ec[e+2], u3 = ec[e+3];
    uint2 p0 = *(const uint2*)(V8 + (((size_t)(u0 & 0x1FFFF)) << 7) + fb);
    uint2 p1 = *(const uint2*)(V8 + (((size_t)(u1 & 0x1FFFF)) << 7) + fb);
    uint2 p2 = *(const uint2*)(V8 + (((size_t)(u2 & 0x1FFFF)) << 7) + fb);
    uint2 p3 = *(const uint2*)(V8 + (((size_t)(u3 & 0x1FFFF)) << 7) + fb);
    float w0 = edgeWneg(u0), w1 = edgeWneg(u1), w2 = edgeWneg(u2), w3 = edgeWneg(u3);
    acc4_fp8(acc,   p0.x, w0); acc4_fp8(acc+4, p0.y, w0);
    acc4_fp8(acc,   p1.x, w1); acc4_fp8(acc+4, p1.y, w1);
    acc4_fp8(acc,   p2.x, w2); acc4_fp8(acc+4, p2.y, w2);
    acc4_fp8(acc,   p3.x, w3); acc4_fp8(acc+4, p3.y, w3);
  }
  for (; e < e1; ++e){
    unsigned u = ec[e];
    uint2 p = *(const uint2*)(V8 + (((size_t)(u & 0x1FFFF)) << 7) + fb);
    float w = edgeWneg(u);
    acc4_fp8(acc, p.x, w); acc4_fp8(acc+4, p.y, w);
  }

  uint2 o8;
  o8.x = cvt2fp8(acc[0], acc[1]) | (cvt2fp8(acc[2], acc[3]) << 16);
  o8.y = cvt2fp8(acc[4], acc[5]) | (cvt2fp8(acc[6], acc[7]) << 16);
  *(uint2*)(out8 + (((size_t)node) << 7) + fb) = o8;
}

// ---------------- launch ----------------

extern "C" void kernel_launch(void* const* d_in, const int* in_sizes, int n_in,
                              void* d_out, int out_size, void* d_ws, size_t ws_size,
                              hipStream_t stream)
{
  const float* x   = (const float*)d_in[0];
  const int*   ei  = (const int*)d_in[1];
  const float* ew  = (const float*)d_in[2];
  const float* W1  = (const float*)d_in[3];
  const float* b1  = (const float*)d_in[4];
  const float* c1W = (const float*)d_in[5];
  const float* c1b = (const float*)d_in[6];
  const float* c2W = (const float*)d_in[7];
  const float* c2b = (const float*)d_in[8];
  const float* W2  = (const float*)d_in[9];
  const float* b2  = (const float*)d_in[10];
  float* out = (float*)d_out;

  const int n = NN, e = NE;
  const int* row = ei;
  const int* col = ei + e;

  char* ws = (char*)d_ws;
  size_t off = 0;
  auto carve = [&](size_t bytes)->void*{
    void* p = ws + off;
    off += (bytes + 255) & ~(size_t)255;
    return p;
  };
  uint8_t* q8a = (uint8_t*)carve((size_t)n*128);     // h0 fp8
  uint8_t* B8  = (uint8_t*)carve((size_t)n*128);     // Tx1 / L(h1) fp8
  uint8_t* C8  = (uint8_t*)carve((size_t)n*128);     // L(Tx1) fp8
  uint8_t* D8  = (uint8_t*)carve((size_t)n*128);     // h1 fp8 (aliases temp)
  float*  dinv = (float*)carve((size_t)n*4);
  int*    rowptr = (int*)carve((size_t)(n+1)*4);
  unsigned* ec = (unsigned*)carve((size_t)e*4);
  int*    bincnt = (int*)carve((size_t)NBIN*4);
  int*    binptr = (int*)carve((size_t)(NBIN+1)*4);
  int*    blockbase = (int*)carve((size_t)NBB*NBIN*4);   // 1.22MB
  bf16_t*  Wt1  = (bf16_t*)carve(2*128*128*2);
  uint8_t* W8c1 = (uint8_t*)carve(3*128*128);
  uint8_t* W8c2 = (uint8_t*)carve(3*128*128);
  // temp edge buffer (12.8MB) aliases D8: temp lives [binB(gemm1_fused), binC];
  // D8 first written by conv1's k_gemm8 (after binC).
  int2* temp = (int2*)D8;
  (void)ws_size; (void)in_sizes; (void)n_in; (void)out_size;

  const int NB_S = (n + 15)/16;     // 6250

  hipMemsetAsync(bincnt, 0, (size_t)NBIN*4, stream);
  // binA histogram + Wt1 pack
  k_binA_tw<<<NBB + NB_TW1,256,0,stream>>>(row, bincnt, blockbase, W1, Wt1);
  k_scanbins<<<1,256,0,stream>>>(bincnt, binptr, rowptr);
  // fused: h0 = relu(x@W1+b1) -> q8a  AND  coalesced binB  AND  W8 packs (re-assoc)
  k_gemm1_fused<<<NB_G + NBB + NB_TW8,256,0,stream>>>(
      x, Wt1, b1, q8a, n, row, col, ew, binptr, blockbase, temp, c1W, c2W, W8c1, W8c2);
  k_binC<<<NBIN,256,0,stream>>>(temp, binptr, ec, rowptr, dinv, n);

  // conv1: Tx1 = L(h0) -> B8 (normalizes ec in-flight) ; then L(Tx1) -> C8
  k_spmm8n<<<NB_S,256,0,stream>>>(rowptr, ec, dinv, q8a, B8, n);
  k_spmm8<<<NB_S,256,0,stream>>>(rowptr, ec, B8, C8, n);
  // h1 = relu(h0@(W0-W2) + Tx1@W1 + L(Tx1)@(2W2) + b) -> D8 (fp8)
  k_gemm8<<<NB_G,256,0,stream>>>(q8a, B8, C8, W8c1, c1b, D8, nullptr, nullptr, nullptr, n);
  // conv2
  k_spmm8<<<NB_S,256,0,stream>>>(rowptr, ec, D8, B8, n);
  k_spmm8<<<NB_S,256,0,stream>>>(rowptr, ec, B8, C8, n);
  // h2 GEMM (re-assoc weights) + fused head -> out (softmax probabilities)
  k_gemm8<<<NB_G,256,0,stream>>>(D8, B8, C8, W8c2, c2b, nullptr, W2, b2, out, n);
}